// Round 6
// baseline (575.373 us; speedup 1.0000x reference)
//
#include <hip/hip_runtime.h>

#define T_TOK 4096
#define H_DIM 1024
#define I_DIM 2048
#define E_NUM 16
#define K_TOP 4
#define MAX_MT 80                   // max 256-row M-tiles: sum ceil(c_e/256) <= 80
#define PAD_PAIRS (MAX_MT * 256)    // 20480
#define RW_Q 4104                   // padded quarter stride (words) for router rw LDS

typedef __attribute__((ext_vector_type(8))) short s16x8;
typedef __attribute__((ext_vector_type(8))) __bf16 bf16x8;
typedef __attribute__((ext_vector_type(4))) float f32x4;
typedef __attribute__((ext_vector_type(4))) unsigned short u16x4;
typedef __attribute__((ext_vector_type(8))) unsigned short u16x8;

#define DSR(dst, addr, off) \
  asm volatile("ds_read_b128 %0, %1 offset:" #off : "=v"(dst) : "v"(addr))
#define SBAR asm volatile("s_barrier" ::: "memory")
#define WAITV8 asm volatile("s_waitcnt vmcnt(8)" ::: "memory")
#define WAITV4 asm volatile("s_waitcnt vmcnt(4)" ::: "memory")
#define WAITV0 asm volatile("s_waitcnt vmcnt(0)" ::: "memory")
#define WAITLGKM0 asm volatile("s_waitcnt lgkmcnt(0)" ::: "memory")

__device__ __forceinline__ unsigned short f2bf(float f) {
  unsigned u = __float_as_uint(f);
  u += 0x7fffu + ((u >> 16) & 1u);  // round-to-nearest-even
  return (unsigned short)(u >> 16);
}

__device__ __forceinline__ f32x4 mfma_bf16(s16x8 a, s16x8 b, f32x4 c) {
  return __builtin_amdgcn_mfma_f32_16x16x32_bf16(
      __builtin_bit_cast(bf16x8, a), __builtin_bit_cast(bf16x8, b), c, 0, 0, 0);
}

__device__ __forceinline__ void gld16(const void* g, void* l) {
  __builtin_amdgcn_global_load_lds(
      (const __attribute__((address_space(1))) unsigned int*)g,
      (__attribute__((address_space(3))) unsigned int*)l, 16, 0, 0);
}

// ---------------- x -> bf16 (vectorized elementwise) --------------------------
__global__ __launch_bounds__(256) void cvt_kernel(const float* __restrict__ x,
                                                  unsigned short* __restrict__ xb) {
  size_t i = ((size_t)blockIdx.x * 256 + threadIdx.x) * 8;
  f32x4 a = *(const f32x4*)(x + i);
  f32x4 b = *(const f32x4*)(x + i + 4);
  u16x8 o;
  o[0] = f2bf(a[0]); o[1] = f2bf(a[1]); o[2] = f2bf(a[2]); o[3] = f2bf(a[3]);
  o[4] = f2bf(b[0]); o[5] = f2bf(b[1]); o[6] = f2bf(b[2]); o[7] = f2bf(b[3]);
  *(u16x8*)(xb + i) = o;
}

// ---------------- router: lane = (expert, quarter), rw in padded LDS ----------
__global__ __launch_bounds__(256) void router_kernel(
    const float* __restrict__ x, const float* __restrict__ rw,
    const float* __restrict__ rb, int* __restrict__ topi,
    float* __restrict__ topw, int* __restrict__ counts) {
  __shared__ float rws[4 * RW_Q];
  const int tid = threadIdx.x;
  for (int idx = tid * 4; idx < H_DIM * E_NUM; idx += 256 * 4) {
    f32x4 v = *(const f32x4*)(rw + idx);
    int h = idx >> 4, e0 = idx & 15;
    *(f32x4*)&rws[(h >> 8) * RW_Q + (h & 255) * 16 + e0] = v;
  }
  __syncthreads();
  const int w = tid >> 6, l = tid & 63;
  const int e = l & 15, q = l >> 4;
  const float rbe = rb[e];
  const float* ldsb = &rws[q * RW_Q + e];
#pragma unroll
  for (int i = 0; i < 4; ++i) {
    const int t = blockIdx.x * 16 + w * 4 + i;
    const float* xr = x + (size_t)t * H_DIM + (q << 8);
    float acc = 0.f;
#pragma unroll 8
    for (int hh = 0; hh < 256; hh += 4) {
      f32x4 xv = *(const f32x4*)(xr + hh);
      acc += xv[0] * ldsb[(hh + 0) * 16];
      acc += xv[1] * ldsb[(hh + 1) * 16];
      acc += xv[2] * ldsb[(hh + 2) * 16];
      acc += xv[3] * ldsb[(hh + 3) * 16];
    }
    acc += __shfl_xor(acc, 16);
    acc += __shfl_xor(acc, 32);
    float logit = acc + rbe;
    float m = logit;
    m = fmaxf(m, __shfl_xor(m, 1));
    m = fmaxf(m, __shfl_xor(m, 2));
    m = fmaxf(m, __shfl_xor(m, 4));
    m = fmaxf(m, __shfl_xor(m, 8));
    float ex = expf(logit - m);
    int rank = 0;
    const int b16 = l & 48;
#pragma unroll
    for (int j = 0; j < 16; ++j) {
      float vj = __shfl(ex, b16 + j);
      rank += (vj > ex) || (vj == ex && j < e);
    }
    float sel = (rank < K_TOP) ? ex : 0.f;
    float subs = sel;
    subs += __shfl_xor(subs, 1);
    subs += __shfl_xor(subs, 2);
    subs += __shfl_xor(subs, 4);
    subs += __shfl_xor(subs, 8);
    if (q == 0 && rank < K_TOP) {
      topi[t * K_TOP + rank] = e;
      topw[t * K_TOP + rank] = ex / subs;
      atomicAdd(&counts[e], 1);
    }
  }
}

// ---------------- scan: padded offsets (256) + static tile map ----------------
__global__ void scan_kernel(const int* __restrict__ counts, int* padBase,
                            int* tileExpert, int* tileStart, int* nTiles,
                            int* cursor) {
  if (threadIdx.x != 0 || blockIdx.x != 0) return;
  int base = 0, nt = 0;
  for (int e = 0; e < E_NUM; ++e) {
    padBase[e] = base;
    cursor[e] = 0;
    int tc = (counts[e] + 255) >> 8;
    for (int i = 0; i < tc; ++i) {
      tileExpert[nt] = e;
      tileStart[nt] = base + (i << 8);
      ++nt;
    }
    base += tc << 8;
  }
  nTiles[0] = nt;
}

// ---------------- scatter pairs into per-expert sorted order ------------------
__global__ __launch_bounds__(256) void scatter_kernel(
    const int* __restrict__ topi, const float* __restrict__ topw,
    const int* __restrict__ padBase, int* __restrict__ cursor,
    int* __restrict__ pairTok, float* __restrict__ pairW) {
  int t = blockIdx.x * 256 + threadIdx.x;
  if (t >= T_TOK) return;
#pragma unroll
  for (int k = 0; k < K_TOP; ++k) {
    int e = topi[t * K_TOP + k];
    int pos = atomicAdd(&cursor[e], 1);
    int idx = padBase[e] + pos;
    pairTok[idx] = t;
    pairW[idx] = topw[t * K_TOP + k];
  }
}

// ---------------- transpose f32 [R][C] -> bf16 [C][R] per expert (z) ----------
__global__ __launch_bounds__(256) void transpose_kernel(
    const float* __restrict__ src, unsigned short* __restrict__ dst, int R,
    int C) {
  size_t es = (size_t)R * C;
  src += es * blockIdx.z;
  dst += es * blockIdx.z;
  int r0 = blockIdx.y * 64, c0 = blockIdx.x * 64;
  __shared__ float tle[64][65];
  int rr = threadIdx.x >> 4, cc = (threadIdx.x & 15) * 4;
#pragma unroll
  for (int i = 0; i < 4; ++i) {
    f32x4 v = *(const f32x4*)(src + (size_t)(r0 + rr + 16 * i) * C + c0 + cc);
    tle[rr + 16 * i][cc + 0] = v[0];
    tle[rr + 16 * i][cc + 1] = v[1];
    tle[rr + 16 * i][cc + 2] = v[2];
    tle[rr + 16 * i][cc + 3] = v[3];
  }
  __syncthreads();
#pragma unroll
  for (int i = 0; i < 4; ++i) {
    int oc = c0 + rr + 16 * i;
    u16x4 o;
    o[0] = f2bf(tle[cc + 0][rr + 16 * i]);
    o[1] = f2bf(tle[cc + 1][rr + 16 * i]);
    o[2] = f2bf(tle[cc + 2][rr + 16 * i]);
    o[3] = f2bf(tle[cc + 3][rr + 16 * i]);
    *(u16x4*)(dst + (size_t)oc * R + r0 + cc) = o;
  }
}

// ========== 256x256 tile, BK=32, 8 waves, 4-slot LDS, counted vmcnt(8) ========
// LDS: A [4 slots][256 rows][64 B] = 64 KB at 0; B same at 65536. Slot = t&3.
// Stage: linear dest (wave-uniform + lane*16), source chunk (l&3)^((row>>1)&3)
// pre-swizzled (round-2-verified pair, 0 conflicts). Read chunk (l>>4)^((l>>1)&3).
// Pipeline: prologue issues tiles 0-2; tile t issues tile t+3 (A in phase 0,
// B in phase 1); loop-bottom wait vmcnt(8) (= 2 tiles in flight), ramp V4/V0.

// Per-tile body shared by both gemms (two phases, 16 MFMA each).
#define GEMM_TILE_BODY(NT_)                                                    \
  for (int t = 0; t < (NT_); ++t) {                                            \
    const unsigned so = (unsigned)((t & 3) * 16384);                           \
    const unsigned aS = aRd + so, bS = bRd + so;                               \
    const int tau = t + 3;                                                     \
    s16x8 av[4], bv[4];                                                        \
    DSR(bv[0], bS, 0); DSR(bv[1], bS, 1024);                                   \
    DSR(bv[2], bS, 2048); DSR(bv[3], bS, 3072);                                \
    DSR(av[0], aS, 0); DSR(av[1], aS, 1024);                                   \
    DSR(av[2], aS, 2048); DSR(av[3], aS, 3072);                                \
    if (tau < (NT_)) {                                                         \
      char* d = dstA + (tau & 3) * 16384;                                      \
      gld16(pA0 + (size_t)tau * 64, d);                                        \
      gld16(pA1 + (size_t)tau * 64, d + 8192);                                 \
    }                                                                          \
    SBAR; WAITLGKM0; __builtin_amdgcn_sched_barrier(0);                        \
    __builtin_amdgcn_s_setprio(1);                                             \
    _Pragma("unroll") for (int m = 0; m < 4; ++m)                              \
        _Pragma("unroll") for (int n = 0; n < 4; ++n)                          \
            acc[m][n] = mfma_bf16(av[m], bv[n], acc[m][n]);                    \
    __builtin_amdgcn_s_setprio(0);                                             \
    SBAR;                                                                      \
    DSR(av[0], aS, 4096); DSR(av[1], aS, 5120);                                \
    DSR(av[2], aS, 6144); DSR(av[3], aS, 7168);                                \
    if (tau < (NT_)) {                                                         \
      char* d = dstB + (tau & 3) * 16384;                                      \
      gld16(pB0 + (size_t)tau * 64, d);                                        \
      gld16(pB1 + (size_t)tau * 64, d + 8192);                                 \
    }                                                                          \
    SBAR; WAITLGKM0; __builtin_amdgcn_sched_barrier(0);                        \
    __builtin_amdgcn_s_setprio(1);                                             \
    _Pragma("unroll") for (int m = 0; m < 4; ++m)                              \
        _Pragma("unroll") for (int n = 0; n < 4; ++n)                          \
            acc[4 + m][n] = mfma_bf16(av[m], bv[n], acc[4 + m][n]);            \
    __builtin_amdgcn_s_setprio(0);                                             \
    if (t < (NT_)-3) { WAITV8; }                                               \
    else if (t == (NT_)-3) { WAITV4; }                                         \
    else if (t == (NT_)-2) { WAITV0; }                                         \
    if (t < (NT_)-1) SBAR;                                                     \
  }

#define GEMM_PROLOGUE                                                          \
  _Pragma("unroll") for (int tau = 0; tau < 3; ++tau) {                        \
    gld16(pA0 + tau * 64, dstA + tau * 16384);                                 \
    gld16(pA1 + tau * 64, dstA + tau * 16384 + 8192);                          \
    gld16(pB0 + tau * 64, dstB + tau * 16384);                                 \
    gld16(pB1 + tau * 64, dstB + tau * 16384 + 8192);                          \
  }                                                                            \
  WAITV8; SBAR;

// ---------------- grouped GEMM1: hmid = gelu(x[pairs] @ w1 + b1) --------------
__global__ __launch_bounds__(512, 1) void gemm1_kernel(
    const unsigned short* __restrict__ xb, const unsigned short* __restrict__ w1t,
    const float* __restrict__ b1, unsigned short* __restrict__ hmid,
    const int* __restrict__ pairTok, const int* __restrict__ tileExpert,
    const int* __restrict__ tileStart, const int* __restrict__ nTiles) {
  __shared__ char LDS[131072];
  const int bid = blockIdx.x;
  const int tx = bid & 7, ty = bid >> 3;  // N-tiles fastest: balanced XCD spread
  if (ty >= nTiles[0]) return;
  const int e = tileExpert[ty], tsp = tileStart[ty], n0 = tx * 256;
  const int tid = threadIdx.x, w = tid >> 6, l = tid & 63;
  const int wm = w >> 2, wn = w & 3;
  // staging sources
  const int srow = tid >> 2;  // 0..127
  const int srcChunk = (tid & 3) ^ ((tid >> 3) & 3);
  int tokA0 = pairTok[tsp + srow];       if (tokA0 < 0) tokA0 = 0;
  int tokA1 = pairTok[tsp + 128 + srow]; if (tokA1 < 0) tokA1 = 0;
  const char* pA0 = (const char*)xb + (size_t)tokA0 * 2048 + srcChunk * 16;
  const char* pA1 = (const char*)xb + (size_t)tokA1 * 2048 + srcChunk * 16;
  const unsigned short* wbv = w1t + (size_t)e * I_DIM * H_DIM;
  const char* pB0 = (const char*)wbv + (size_t)(n0 + srow) * 2048 + srcChunk * 16;
  const char* pB1 = (const char*)wbv + (size_t)(n0 + 128 + srow) * 2048 + srcChunk * 16;
  char* dstA = LDS + w * 1024;
  char* dstB = LDS + 65536 + w * 1024;
  // read bases
  const unsigned ldsb = (unsigned)(uintptr_t)&LDS[0];
  const unsigned rswz = (unsigned)(((l >> 4) ^ ((l >> 1) & 3)) * 16);
  const unsigned aRd = ldsb + (unsigned)((wm * 128 + (l & 15)) * 64) + rswz;
  const unsigned bRd = ldsb + 65536u + (unsigned)((wn * 64 + (l & 15)) * 64) + rswz;

  f32x4 acc[8][4];
#pragma unroll
  for (int m = 0; m < 8; ++m)
#pragma unroll
    for (int n = 0; n < 4; ++n) acc[m][n] = f32x4{0.f, 0.f, 0.f, 0.f};

  GEMM_PROLOGUE
  GEMM_TILE_BODY(32)  // K = 1024

  const float* b1e = b1 + (size_t)e * I_DIM;
  const int qrow = (l >> 4) * 4;
#pragma unroll
  for (int m = 0; m < 8; ++m) {
    const int mrow = tsp + wm * 128 + m * 16 + qrow;
#pragma unroll
    for (int n = 0; n < 4; ++n) {
      const int col = n0 + wn * 64 + n * 16 + (l & 15);
      const float bb = b1e[col];
      f32x4 v = acc[m][n];
#pragma unroll
      for (int j = 0; j < 4; ++j) {
        float xv = v[j] + bb;
        float ge = 0.5f * xv * (1.f + erff(xv * 0.7071067811865476f));
        hmid[(size_t)(mrow + j) * I_DIM + col] = f2bf(ge);
      }
    }
  }
}

// ---------------- grouped GEMM2: out += ((hmid @ w2) + b2) * pairW ------------
__global__ __launch_bounds__(512, 1) void gemm2_kernel(
    const unsigned short* __restrict__ hmid,
    const unsigned short* __restrict__ w2t, const float* __restrict__ b2,
    float* __restrict__ out, const int* __restrict__ pairTok,
    const float* __restrict__ pairW, const int* __restrict__ tileExpert,
    const int* __restrict__ tileStart, const int* __restrict__ nTiles) {
  __shared__ char LDS[131072];
  const int bid = blockIdx.x;
  const int tx = bid & 3, ty = bid >> 2;
  if (ty >= nTiles[0]) return;
  const int e = tileExpert[ty], tsp = tileStart[ty], n0 = tx * 256;
  const int tid = threadIdx.x, w = tid >> 6, l = tid & 63;
  const int wm = w >> 2, wn = w & 3;
  const int srow = tid >> 2;
  const int srcChunk = (tid & 3) ^ ((tid >> 3) & 3);
  const char* pA0 = (const char*)hmid + (size_t)(tsp + srow) * 4096 + srcChunk * 16;
  const char* pA1 = (const char*)hmid + (size_t)(tsp + 128 + srow) * 4096 + srcChunk * 16;
  const unsigned short* wbv = w2t + (size_t)e * H_DIM * I_DIM;
  const char* pB0 = (const char*)wbv + (size_t)(n0 + srow) * 4096 + srcChunk * 16;
  const char* pB1 = (const char*)wbv + (size_t)(n0 + 128 + srow) * 4096 + srcChunk * 16;
  char* dstA = LDS + w * 1024;
  char* dstB = LDS + 65536 + w * 1024;
  const unsigned ldsb = (unsigned)(uintptr_t)&LDS[0];
  const unsigned rswz = (unsigned)(((l >> 4) ^ ((l >> 1) & 3)) * 16);
  const unsigned aRd = ldsb + (unsigned)((wm * 128 + (l & 15)) * 64) + rswz;
  const unsigned bRd = ldsb + 65536u + (unsigned)((wn * 64 + (l & 15)) * 64) + rswz;

  f32x4 acc[8][4];
#pragma unroll
  for (int m = 0; m < 8; ++m)
#pragma unroll
    for (int n = 0; n < 4; ++n) acc[m][n] = f32x4{0.f, 0.f, 0.f, 0.f};

  GEMM_PROLOGUE
  GEMM_TILE_BODY(64)  // K = 2048

  const float* b2e = b2 + (size_t)e * H_DIM;
  const int qrow = (l >> 4) * 4;
#pragma unroll
  for (int m = 0; m < 8; ++m) {
    const int prow = tsp + wm * 128 + m * 16 + qrow;
#pragma unroll
    for (int j = 0; j < 4; ++j) {
      const int p = prow + j;
      const int tok = pairTok[p];
      if (tok < 0) continue;
      const float pw = pairW[p];
      float* orow = out + (size_t)tok * H_DIM;
#pragma unroll
      for (int n = 0; n < 4; ++n) {
        const int col = n0 + wn * 64 + n * 16 + (l & 15);
        float val = (acc[m][n][j] + b2e[col]) * pw;
        atomicAdd(orow + col, val);
      }
    }
  }
}

// ------------------------------------------------------------------------------
extern "C" void kernel_launch(void* const* d_in, const int* in_sizes, int n_in,
                              void* d_out, int out_size, void* d_ws,
                              size_t ws_size, hipStream_t stream) {
  const float* x = (const float*)d_in[0];
  const float* rw = (const float*)d_in[1];
  const float* rb = (const float*)d_in[2];
  const float* w1 = (const float*)d_in[3];
  const float* b1 = (const float*)d_in[4];
  const float* w2 = (const float*)d_in[5];
  const float* b2 = (const float*)d_in[6];
  float* out = (float*)d_out;
  char* ws = (char*)d_ws;

  size_t off = 0;
  unsigned short* xb = (unsigned short*)(ws + off);
  off += (size_t)T_TOK * H_DIM * 2;
  unsigned short* wT = (unsigned short*)(ws + off);
  off += (size_t)E_NUM * H_DIM * I_DIM * 2;  // shared by w1T then w2T
  unsigned short* hmid = (unsigned short*)(ws + off);
  off += (size_t)PAD_PAIRS * I_DIM * 2;
  int* topi = (int*)(ws + off);      off += (size_t)T_TOK * K_TOP * 4;
  float* topw = (float*)(ws + off);  off += (size_t)T_TOK * K_TOP * 4;
  int* pairTok = (int*)(ws + off);   off += (size_t)PAD_PAIRS * 4;
  float* pairW = (float*)(ws + off); off += (size_t)PAD_PAIRS * 4;
  int* counts = (int*)(ws + off);    off += 64;
  int* cursor = (int*)(ws + off);    off += 64;
  int* padBase = (int*)(ws + off);   off += 64;
  int* tileExpert = (int*)(ws + off); off += MAX_MT * 4;
  int* tileStart = (int*)(ws + off);  off += MAX_MT * 4;
  int* nTiles = (int*)(ws + off);     off += 64;

  if (ws_size < off) return;  // diagnostic: output stays 0

  hipMemsetAsync(counts, 0, 64, stream);
  hipMemsetAsync(pairTok, 0xFF, (size_t)PAD_PAIRS * 4, stream);
  hipMemsetAsync(out, 0, (size_t)T_TOK * H_DIM * 4, stream);

  cvt_kernel<<<T_TOK * H_DIM / (256 * 8), 256, 0, stream>>>(x, xb);
  router_kernel<<<T_TOK / 16, 256, 0, stream>>>(x, rw, rb, topi, topw, counts);
  scan_kernel<<<1, 64, 0, stream>>>(counts, padBase, tileExpert, tileStart,
                                    nTiles, cursor);
  scatter_kernel<<<T_TOK / 256, 256, 0, stream>>>(topi, topw, padBase, cursor,
                                                  pairTok, pairW);
  transpose_kernel<<<dim3(I_DIM / 64, H_DIM / 64, E_NUM), 256, 0, stream>>>(
      w1, wT, H_DIM, I_DIM);
  gemm1_kernel<<<8 * MAX_MT, 512, 0, stream>>>(
      xb, wT, b1, hmid, pairTok, tileExpert, tileStart, nTiles);
  transpose_kernel<<<dim3(H_DIM / 64, I_DIM / 64, E_NUM), 256, 0, stream>>>(
      w2, wT, I_DIM, H_DIM);
  gemm2_kernel<<<4 * MAX_MT, 512, 0, stream>>>(
      hmid, wT, b2, out, pairTok, pairW, tileExpert, tileStart, nTiles);
}

// Round 7
// 432.352 us; speedup vs baseline: 1.3308x; 1.3308x over previous
//
#include <hip/hip_runtime.h>

#define T_TOK 4096
#define H_DIM 1024
#define I_DIM 2048
#define E_NUM 16
#define K_TOP 4
#define BM 128
#define BK 32
#define MAX_TILES 144
#define PAD_PAIRS (MAX_TILES * BM)  // 18432
#define RW_Q 4104                   // padded quarter stride (words) for router rw LDS

typedef __attribute__((ext_vector_type(8))) short s16x8;
typedef __attribute__((ext_vector_type(4))) float f32x4;
typedef __attribute__((ext_vector_type(4))) unsigned short u16x4;
typedef __attribute__((ext_vector_type(8))) unsigned short u16x8;

__device__ __forceinline__ unsigned short f2bf(float f) {
  unsigned u = __float_as_uint(f);
  u += 0x7fffu + ((u >> 16) & 1u);  // round-to-nearest-even
  return (unsigned short)(u >> 16);
}

// asm MFMA: measured best across r2(194us) vs r5-builtin(204us).
__device__ __forceinline__ void mfma_bf16(const s16x8& a, const s16x8& b, f32x4& c) {
  asm("v_mfma_f32_16x16x32_bf16 %0, %1, %2, %0" : "+v"(c) : "v"(a), "v"(b));
}

__device__ __forceinline__ void gld16(const void* g, void* l) {
  __builtin_amdgcn_global_load_lds(
      (const __attribute__((address_space(1))) unsigned int*)g,
      (__attribute__((address_space(3))) unsigned int*)l, 16, 0, 0);
}

// ---------------- x -> bf16 (vectorized elementwise) --------------------------
__global__ __launch_bounds__(256) void cvt_kernel(const float* __restrict__ x,
                                                  unsigned short* __restrict__ xb) {
  size_t i = ((size_t)blockIdx.x * 256 + threadIdx.x) * 8;
  f32x4 a = *(const f32x4*)(x + i);
  f32x4 b = *(const f32x4*)(x + i + 4);
  u16x8 o;
  o[0] = f2bf(a[0]); o[1] = f2bf(a[1]); o[2] = f2bf(a[2]); o[3] = f2bf(a[3]);
  o[4] = f2bf(b[0]); o[5] = f2bf(b[1]); o[6] = f2bf(b[2]); o[7] = f2bf(b[3]);
  *(u16x8*)(xb + i) = o;
}

// ---------------- router: lane = (expert, quarter), rw in padded LDS ----------
__global__ __launch_bounds__(256) void router_kernel(
    const float* __restrict__ x, const float* __restrict__ rw,
    const float* __restrict__ rb, int* __restrict__ topi,
    float* __restrict__ topw, int* __restrict__ counts) {
  __shared__ float rws[4 * RW_Q];
  const int tid = threadIdx.x;
  for (int idx = tid * 4; idx < H_DIM * E_NUM; idx += 256 * 4) {
    f32x4 v = *(const f32x4*)(rw + idx);
    int h = idx >> 4, e0 = idx & 15;
    *(f32x4*)&rws[(h >> 8) * RW_Q + (h & 255) * 16 + e0] = v;
  }
  __syncthreads();
  const int w = tid >> 6, l = tid & 63;
  const int e = l & 15, q = l >> 4;
  const float rbe = rb[e];
  const float* ldsb = &rws[q * RW_Q + e];
#pragma unroll
  for (int i = 0; i < 4; ++i) {
    const int t = blockIdx.x * 16 + w * 4 + i;
    const float* xr = x + (size_t)t * H_DIM + (q << 8);
    float acc = 0.f;
#pragma unroll 8
    for (int hh = 0; hh < 256; hh += 4) {
      f32x4 xv = *(const f32x4*)(xr + hh);
      acc += xv[0] * ldsb[(hh + 0) * 16];
      acc += xv[1] * ldsb[(hh + 1) * 16];
      acc += xv[2] * ldsb[(hh + 2) * 16];
      acc += xv[3] * ldsb[(hh + 3) * 16];
    }
    acc += __shfl_xor(acc, 16);
    acc += __shfl_xor(acc, 32);
    float logit = acc + rbe;
    float m = logit;
    m = fmaxf(m, __shfl_xor(m, 1));
    m = fmaxf(m, __shfl_xor(m, 2));
    m = fmaxf(m, __shfl_xor(m, 4));
    m = fmaxf(m, __shfl_xor(m, 8));
    float ex = expf(logit - m);
    int rank = 0;
    const int b16 = l & 48;
#pragma unroll
    for (int j = 0; j < 16; ++j) {
      float vj = __shfl(ex, b16 + j);
      rank += (vj > ex) || (vj == ex && j < e);
    }
    float sel = (rank < K_TOP) ? ex : 0.f;
    float subs = sel;
    subs += __shfl_xor(subs, 1);
    subs += __shfl_xor(subs, 2);
    subs += __shfl_xor(subs, 4);
    subs += __shfl_xor(subs, 8);
    if (q == 0 && rank < K_TOP) {
      topi[t * K_TOP + rank] = e;
      topw[t * K_TOP + rank] = ex / subs;
      atomicAdd(&counts[e], 1);
    }
  }
}

// ---------------- scan: padded offsets + static tile map -----------------------
__global__ void scan_kernel(const int* __restrict__ counts, int* padBase,
                            int* tileExpert, int* tileStart, int* nTiles,
                            int* cursor) {
  if (threadIdx.x != 0 || blockIdx.x != 0) return;
  int base = 0, nt = 0;
  for (int e = 0; e < E_NUM; ++e) {
    padBase[e] = base;
    cursor[e] = 0;
    int tc = (counts[e] + BM - 1) >> 7;
    for (int i = 0; i < tc; ++i) {
      tileExpert[nt] = e;
      tileStart[nt] = base + (i << 7);
      ++nt;
    }
    base += tc << 7;
  }
  nTiles[0] = nt;
}

// ---------------- scatter pairs into per-expert sorted order ------------------
__global__ __launch_bounds__(256) void scatter_kernel(
    const int* __restrict__ topi, const float* __restrict__ topw,
    const int* __restrict__ padBase, int* __restrict__ cursor,
    int* __restrict__ pairTok, float* __restrict__ pairW,
    int* __restrict__ pairPos) {
  int t = blockIdx.x * 256 + threadIdx.x;
  if (t >= T_TOK) return;
#pragma unroll
  for (int k = 0; k < K_TOP; ++k) {
    int e = topi[t * K_TOP + k];
    int pos = atomicAdd(&cursor[e], 1);
    int idx = padBase[e] + pos;
    pairTok[idx] = t;
    pairW[idx] = topw[t * K_TOP + k];
    pairPos[t * K_TOP + k] = idx;
  }
}

// ---------------- transpose f32 [R][C] -> bf16 [C][R] per expert (z) ----------
__global__ __launch_bounds__(256) void transpose_kernel(
    const float* __restrict__ src, unsigned short* __restrict__ dst, int R,
    int C) {
  size_t es = (size_t)R * C;
  src += es * blockIdx.z;
  dst += es * blockIdx.z;
  int r0 = blockIdx.y * 64, c0 = blockIdx.x * 64;
  __shared__ float tle[64][65];
  int rr = threadIdx.x >> 4, cc = (threadIdx.x & 15) * 4;
#pragma unroll
  for (int i = 0; i < 4; ++i) {
    f32x4 v = *(const f32x4*)(src + (size_t)(r0 + rr + 16 * i) * C + c0 + cc);
    tle[rr + 16 * i][cc + 0] = v[0];
    tle[rr + 16 * i][cc + 1] = v[1];
    tle[rr + 16 * i][cc + 2] = v[2];
    tle[rr + 16 * i][cc + 3] = v[3];
  }
  __syncthreads();
#pragma unroll
  for (int i = 0; i < 4; ++i) {
    int oc = c0 + rr + 16 * i;
    u16x4 o;
    o[0] = f2bf(tle[cc + 0][rr + 16 * i]);
    o[1] = f2bf(tle[cc + 1][rr + 16 * i]);
    o[2] = f2bf(tle[cc + 2][rr + 16 * i]);
    o[3] = f2bf(tle[cc + 3][rr + 16 * i]);
    *(u16x4*)(dst + (size_t)oc * R + r0 + cc) = o;
  }
}

// ---------------- grouped GEMM1: hmid = gelu(x[pairs] @ w1 + b1) --------------
// r2-verified structure: gld16 staging, syncthreads dbuf, asm MFMA, XOR swizzle
// (measured 0 conflicts), XCD-chunked grid (measured FETCH 94MB).
__global__ __launch_bounds__(256, 4) void gemm1_kernel(
    const unsigned short* __restrict__ xb, const unsigned short* __restrict__ w1t,
    const float* __restrict__ b1, unsigned short* __restrict__ hmid,
    const int* __restrict__ pairTok, const int* __restrict__ tileExpert,
    const int* __restrict__ tileStart, const int* __restrict__ nTiles) {
  const int bid = blockIdx.x;
  const int lin = (bid & 7) * ((16 * MAX_TILES) >> 3) + (bid >> 3);  // XCD chunk
  const int tx = lin & 15, ty = lin >> 4;
  if (ty >= nTiles[0]) return;
  const int e = tileExpert[ty];
  const int tsp = tileStart[ty];
  const int n0 = tx * 128;
  __shared__ unsigned short As[2][BM * BK];
  __shared__ unsigned short Bs[2][BM * BK];
  const int tid = threadIdx.x, w = tid >> 6, l = tid & 63;
  const int rbase = w * 16 + (l >> 2);
  const int segp = (l & 3) ^ ((l >> 3) & 3);  // swizzled source chunk
  int tok0 = pairTok[tsp + rbase];
  if (tok0 < 0) tok0 = 0;
  int tok1 = pairTok[tsp + rbase + 64];
  if (tok1 < 0) tok1 = 0;
  const char* gA0 = (const char*)(xb + (size_t)tok0 * H_DIM) + segp * 16;
  const char* gA1 = (const char*)(xb + (size_t)tok1 * H_DIM) + segp * 16;
  const unsigned short* wbase = w1t + (size_t)e * I_DIM * H_DIM;
  const char* gB0 = (const char*)(wbase + (size_t)(n0 + rbase) * H_DIM) + segp * 16;
  const char* gB1 = (const char*)(wbase + (size_t)(n0 + rbase + 64) * H_DIM) + segp * 16;

  f32x4 acc[4][4];
#pragma unroll
  for (int m = 0; m < 4; ++m)
#pragma unroll
    for (int n = 0; n < 4; ++n) acc[m][n] = f32x4{0.f, 0.f, 0.f, 0.f};

  const int wr = w >> 1, wc = w & 1, lrow = l & 15, g = l >> 4;
  const int gs = g ^ ((l >> 1) & 3);  // swizzled read chunk
  const int NK = H_DIM / BK;  // 32

  gld16(gA0, &As[0][w * 512]);
  gld16(gA1, &As[0][2048 + w * 512]);
  gld16(gB0, &Bs[0][w * 512]);
  gld16(gB1, &Bs[0][2048 + w * 512]);

  for (int kt = 0; kt < NK; ++kt) {
    __syncthreads();
    if (kt + 1 < NK) {
      const int kb = (kt + 1) * 64;
      const int nb = (kt + 1) & 1;
      gld16(gA0 + kb, &As[nb][w * 512]);
      gld16(gA1 + kb, &As[nb][2048 + w * 512]);
      gld16(gB0 + kb, &Bs[nb][w * 512]);
      gld16(gB1 + kb, &Bs[nb][2048 + w * 512]);
    }
    const int cb = kt & 1;
    const s16x8* Ap = (const s16x8*)As[cb];
    const s16x8* Bp = (const s16x8*)Bs[cb];
    s16x8 av[4], bv[4];
#pragma unroll
    for (int m = 0; m < 4; ++m) av[m] = Ap[(wr * 64 + m * 16 + lrow) * 4 + gs];
#pragma unroll
    for (int n = 0; n < 4; ++n) bv[n] = Bp[(wc * 64 + n * 16 + lrow) * 4 + gs];
#pragma unroll
    for (int m = 0; m < 4; ++m)
#pragma unroll
      for (int n = 0; n < 4; ++n) mfma_bf16(av[m], bv[n], acc[m][n]);
  }

  const float* b1e = b1 + (size_t)e * I_DIM;
#pragma unroll
  for (int m = 0; m < 4; ++m) {
    const int rw0 = wr * 64 + m * 16 + g * 4;
#pragma unroll
    for (int n = 0; n < 4; ++n) {
      const int col = n0 + wc * 64 + n * 16 + lrow;
      const float bb = b1e[col];
      f32x4 v = acc[m][n];
#pragma unroll
      for (int j = 0; j < 4; ++j) {
        const int p = tsp + rw0 + j;
        float xv = v[j] + bb;
        // tanh-form GeLU (max |err| ~3e-4 vs exact erf; one transcendental)
        float y = 0.7978845608028654f * (xv + 0.044715f * xv * xv * xv);
        float ey = __expf(2.f * y);
        float th = 1.f - 2.f / (ey + 1.f);
        float ge = 0.5f * xv * (1.f + th);
        hmid[(size_t)p * I_DIM + col] = f2bf(ge);
      }
    }
  }
}

// ---------------- grouped GEMM2 -----------------------------------------------
// usePairOut=1: store raw per-pair results bf16 (combine kernel applies b2, pw).
// usePairOut=0: legacy atomic path (fallback when ws is too small).
__global__ __launch_bounds__(256, 4) void gemm2_kernel(
    const unsigned short* __restrict__ hmid,
    const unsigned short* __restrict__ w2t, const float* __restrict__ b2,
    float* __restrict__ out, unsigned short* __restrict__ pairOut,
    const int* __restrict__ pairTok, const float* __restrict__ pairW,
    const int* __restrict__ tileExpert, const int* __restrict__ tileStart,
    const int* __restrict__ nTiles, int usePairOut) {
  const int bid = blockIdx.x;
  const int lin = (bid & 7) * ((8 * MAX_TILES) >> 3) + (bid >> 3);  // XCD chunk
  const int tx = lin & 7, ty = lin >> 3;
  if (ty >= nTiles[0]) return;
  const int e = tileExpert[ty];
  const int tsp = tileStart[ty];
  const int n0 = tx * 128;
  __shared__ unsigned short As[2][BM * BK];
  __shared__ unsigned short Bs[2][BM * BK];
  const int tid = threadIdx.x, w = tid >> 6, l = tid & 63;
  const int rbase = w * 16 + (l >> 2);
  const int segp = (l & 3) ^ ((l >> 3) & 3);
  const char* gA0 = (const char*)(hmid + (size_t)(tsp + rbase) * I_DIM) + segp * 16;
  const char* gA1 = (const char*)(hmid + (size_t)(tsp + rbase + 64) * I_DIM) + segp * 16;
  const unsigned short* wbase = w2t + (size_t)e * H_DIM * I_DIM;
  const char* gB0 = (const char*)(wbase + (size_t)(n0 + rbase) * I_DIM) + segp * 16;
  const char* gB1 = (const char*)(wbase + (size_t)(n0 + rbase + 64) * I_DIM) + segp * 16;

  f32x4 acc[4][4];
#pragma unroll
  for (int m = 0; m < 4; ++m)
#pragma unroll
    for (int n = 0; n < 4; ++n) acc[m][n] = f32x4{0.f, 0.f, 0.f, 0.f};

  const int wr = w >> 1, wc = w & 1, lrow = l & 15, g = l >> 4;
  const int gs = g ^ ((l >> 1) & 3);
  const int NK = I_DIM / BK;  // 64

  gld16(gA0, &As[0][w * 512]);
  gld16(gA1, &As[0][2048 + w * 512]);
  gld16(gB0, &Bs[0][w * 512]);
  gld16(gB1, &Bs[0][2048 + w * 512]);

  for (int kt = 0; kt < NK; ++kt) {
    __syncthreads();
    if (kt + 1 < NK) {
      const int kb = (kt + 1) * 64;
      const int nb = (kt + 1) & 1;
      gld16(gA0 + kb, &As[nb][w * 512]);
      gld16(gA1 + kb, &As[nb][2048 + w * 512]);
      gld16(gB0 + kb, &Bs[nb][w * 512]);
      gld16(gB1 + kb, &Bs[nb][2048 + w * 512]);
    }
    const int cb = kt & 1;
    const s16x8* Ap = (const s16x8*)As[cb];
    const s16x8* Bp = (const s16x8*)Bs[cb];
    s16x8 av[4], bv[4];
#pragma unroll
    for (int m = 0; m < 4; ++m) av[m] = Ap[(wr * 64 + m * 16 + lrow) * 4 + gs];
#pragma unroll
    for (int n = 0; n < 4; ++n) bv[n] = Bp[(wc * 64 + n * 16 + lrow) * 4 + gs];
#pragma unroll
    for (int m = 0; m < 4; ++m)
#pragma unroll
      for (int n = 0; n < 4; ++n) mfma_bf16(av[m], bv[n], acc[m][n]);
  }

  if (usePairOut) {
#pragma unroll
    for (int m = 0; m < 4; ++m) {
      const int rw0 = wr * 64 + m * 16 + g * 4;
#pragma unroll
      for (int n = 0; n < 4; ++n) {
        const int col = n0 + wc * 64 + n * 16 + lrow;
        f32x4 v = acc[m][n];
#pragma unroll
        for (int j = 0; j < 4; ++j)
          pairOut[(size_t)(tsp + rw0 + j) * H_DIM + col] = f2bf(v[j]);
      }
    }
  } else {
    const float* b2e = b2 + (size_t)e * H_DIM;
#pragma unroll
    for (int m = 0; m < 4; ++m) {
      const int rw0 = wr * 64 + m * 16 + g * 4;
#pragma unroll
      for (int j = 0; j < 4; ++j) {
        const int p = tsp + rw0 + j;
        const int tok = pairTok[p];
        if (tok < 0) continue;
        const float pw = pairW[p];
        float* orow = out + (size_t)tok * H_DIM;
#pragma unroll
        for (int n = 0; n < 4; ++n) {
          const int col = n0 + wc * 64 + n * 16 + lrow;
          float val = (acc[m][n][j] + b2e[col]) * pw;
          atomicAdd(orow + col, val);
        }
      }
    }
  }
}

// ---------------- combine: out[t] = sum_k pw_k * (pairOut[pos_k] + b2[e_k]) ---
__global__ __launch_bounds__(256) void combine_kernel(
    const unsigned short* __restrict__ pairOut, const int* __restrict__ pairPos,
    const int* __restrict__ topi, const float* __restrict__ topw,
    const float* __restrict__ b2, float* __restrict__ out) {
  const int t = blockIdx.x * 2 + (threadIdx.x >> 7);
  const int c0 = (threadIdx.x & 127) * 8;
  float o[8];
#pragma unroll
  for (int j = 0; j < 8; ++j) o[j] = 0.f;
#pragma unroll
  for (int k = 0; k < K_TOP; ++k) {
    const int e = topi[t * K_TOP + k];
    const float pw = topw[t * K_TOP + k];
    const int pos = pairPos[t * K_TOP + k];
    u16x8 v = *(const u16x8*)(pairOut + (size_t)pos * H_DIM + c0);
    const float* b2r = b2 + (size_t)e * H_DIM + c0;
#pragma unroll
    for (int j = 0; j < 8; ++j) {
      float hv = __uint_as_float((unsigned)v[j] << 16);
      o[j] += pw * (hv + b2r[j]);
    }
  }
  float* orow = out + (size_t)t * H_DIM + c0;
  *(f32x4*)orow = f32x4{o[0], o[1], o[2], o[3]};
  *(f32x4*)(orow + 4) = f32x4{o[4], o[5], o[6], o[7]};
}

// ------------------------------------------------------------------------------
extern "C" void kernel_launch(void* const* d_in, const int* in_sizes, int n_in,
                              void* d_out, int out_size, void* d_ws,
                              size_t ws_size, hipStream_t stream) {
  const float* x = (const float*)d_in[0];
  const float* rw = (const float*)d_in[1];
  const float* rb = (const float*)d_in[2];
  const float* w1 = (const float*)d_in[3];
  const float* b1 = (const float*)d_in[4];
  const float* w2 = (const float*)d_in[5];
  const float* b2 = (const float*)d_in[6];
  float* out = (float*)d_out;
  char* ws = (char*)d_ws;

  const size_t xbSz = (size_t)T_TOK * H_DIM * 2;          // 8.39 MB
  const size_t poSz = (size_t)PAD_PAIRS * H_DIM * 2;      // 37.75 MB
  const size_t wtSz = (size_t)E_NUM * H_DIM * I_DIM * 2;  // 67.11 MB
  const size_t hmSz = (size_t)PAD_PAIRS * I_DIM * 2;      // 75.50 MB
  const size_t smallSz = (size_t)T_TOK * K_TOP * 4 * 3    // topi, topw, pairPos
                         + (size_t)PAD_PAIRS * 4 * 2      // pairTok, pairW
                         + 64 * 3 + MAX_TILES * 4 * 2 + 64;
  const size_t richTotal = poSz + wtSz + hmSz + smallSz;  // xb unioned w/ pairOut
  const size_t poorTotal = xbSz + wtSz + hmSz + smallSz;
  const int rich = ws_size >= richTotal;
  if (!rich && ws_size < poorTotal) return;  // diagnostic: output stays 0

  size_t off = 0;
  unsigned short* xb = (unsigned short*)(ws + off);       // union region
  unsigned short* pairOut = (unsigned short*)(ws + off);  // (xb dead by gemm2)
  off += rich ? poSz : xbSz;
  unsigned short* wT = (unsigned short*)(ws + off);
  off += wtSz;  // shared by w1T then w2T
  unsigned short* hmid = (unsigned short*)(ws + off);
  off += hmSz;
  int* topi = (int*)(ws + off);      off += (size_t)T_TOK * K_TOP * 4;
  float* topw = (float*)(ws + off);  off += (size_t)T_TOK * K_TOP * 4;
  int* pairPos = (int*)(ws + off);   off += (size_t)T_TOK * K_TOP * 4;
  int* pairTok = (int*)(ws + off);   off += (size_t)PAD_PAIRS * 4;
  float* pairW = (float*)(ws + off); off += (size_t)PAD_PAIRS * 4;
  int* counts = (int*)(ws + off);    off += 64;
  int* cursor = (int*)(ws + off);    off += 64;
  int* padBase = (int*)(ws + off);   off += 64;
  int* tileExpert = (int*)(ws + off); off += MAX_TILES * 4;
  int* tileStart = (int*)(ws + off);  off += MAX_TILES * 4;
  int* nTiles = (int*)(ws + off);     off += 64;

  hipMemsetAsync(counts, 0, 64, stream);
  hipMemsetAsync(pairTok, 0xFF, (size_t)PAD_PAIRS * 4, stream);
  if (!rich) hipMemsetAsync(out, 0, (size_t)T_TOK * H_DIM * 4, stream);

  cvt_kernel<<<T_TOK * H_DIM / (256 * 8), 256, 0, stream>>>(x, xb);
  router_kernel<<<T_TOK / 16, 256, 0, stream>>>(x, rw, rb, topi, topw, counts);
  scan_kernel<<<1, 64, 0, stream>>>(counts, padBase, tileExpert, tileStart,
                                    nTiles, cursor);
  scatter_kernel<<<T_TOK / 256, 256, 0, stream>>>(topi, topw, padBase, cursor,
                                                  pairTok, pairW, pairPos);
  transpose_kernel<<<dim3(I_DIM / 64, H_DIM / 64, E_NUM), 256, 0, stream>>>(
      w1, wT, H_DIM, I_DIM);
  gemm1_kernel<<<16 * MAX_TILES, 256, 0, stream>>>(
      xb, wT, b1, hmid, pairTok, tileExpert, tileStart, nTiles);
  transpose_kernel<<<dim3(H_DIM / 64, I_DIM / 64, E_NUM), 256, 0, stream>>>(
      w2, wT, I_DIM, H_DIM);
  gemm2_kernel<<<8 * MAX_TILES, 256, 0, stream>>>(
      hmid, wT, b2, out, pairOut, pairTok, pairW, tileExpert, tileStart, nTiles,
      rich);
  if (rich)
    combine_kernel<<<T_TOK / 2, 256, 0, stream>>>(pairOut, pairPos, topi, topw,
                                                  b2, out);
}

// Round 8
// 420.179 us; speedup vs baseline: 1.3694x; 1.0290x over previous
//
#include <hip/hip_runtime.h>

#define T_TOK 4096
#define H_DIM 1024
#define I_DIM 2048
#define E_NUM 16
#define K_TOP 4
#define BM 128
#define BK 32
#define MAX_TILES 144
#define PAD_PAIRS (MAX_TILES * BM)  // 18432
#define RW_Q 4104                   // padded quarter stride (words) for router rw LDS

typedef __attribute__((ext_vector_type(8))) short s16x8;
typedef __attribute__((ext_vector_type(4))) float f32x4;
typedef __attribute__((ext_vector_type(4))) unsigned short u16x4;
typedef __attribute__((ext_vector_type(8))) unsigned short u16x8;

__device__ __forceinline__ unsigned short f2bf(float f) {
  unsigned u = __float_as_uint(f);
  u += 0x7fffu + ((u >> 16) & 1u);  // round-to-nearest-even
  return (unsigned short)(u >> 16);
}

// asm MFMA: measured best (r2 194us vs r5-builtin 204us).
__device__ __forceinline__ void mfma_bf16(const s16x8& a, const s16x8& b, f32x4& c) {
  asm("v_mfma_f32_16x16x32_bf16 %0, %1, %2, %0" : "+v"(c) : "v"(a), "v"(b));
}

__device__ __forceinline__ void gld16(const void* g, void* l) {
  __builtin_amdgcn_global_load_lds(
      (const __attribute__((address_space(1))) unsigned int*)g,
      (__attribute__((address_space(3))) unsigned int*)l, 16, 0, 0);
}

// Per-block redundant tile map from counts (replaces scan_kernel).
__device__ __forceinline__ int tile_map(const int* counts, int ty, int* tsp) {
  int e = -1, acc = 0, base = 0;
#pragma unroll
  for (int ee = 0; ee < E_NUM; ++ee) {
    int tc = (counts[ee] + 127) >> 7;
    if (ty >= acc && ty < acc + tc) {
      e = ee;
      *tsp = base + ((ty - acc) << 7);
    }
    acc += tc;
    base += tc << 7;
  }
  return e;
}

// ---------------- x -> bf16 (vectorized elementwise) --------------------------
__global__ __launch_bounds__(256) void cvt_kernel(const float* __restrict__ x,
                                                  unsigned short* __restrict__ xb) {
  size_t i = ((size_t)blockIdx.x * 256 + threadIdx.x) * 8;
  f32x4 a = *(const f32x4*)(x + i);
  f32x4 b = *(const f32x4*)(x + i + 4);
  u16x8 o;
  o[0] = f2bf(a[0]); o[1] = f2bf(a[1]); o[2] = f2bf(a[2]); o[3] = f2bf(a[3]);
  o[4] = f2bf(b[0]); o[5] = f2bf(b[1]); o[6] = f2bf(b[2]); o[7] = f2bf(b[3]);
  *(u16x8*)(xb + i) = o;
}

// ---------------- router: lane = (expert, quarter), rw in padded LDS ----------
__global__ __launch_bounds__(256) void router_kernel(
    const float* __restrict__ x, const float* __restrict__ rw,
    const float* __restrict__ rb, int* __restrict__ topi,
    float* __restrict__ topw, int* __restrict__ counts) {
  __shared__ float rws[4 * RW_Q];
  const int tid = threadIdx.x;
  for (int idx = tid * 4; idx < H_DIM * E_NUM; idx += 256 * 4) {
    f32x4 v = *(const f32x4*)(rw + idx);
    int h = idx >> 4, e0 = idx & 15;
    *(f32x4*)&rws[(h >> 8) * RW_Q + (h & 255) * 16 + e0] = v;
  }
  __syncthreads();
  const int w = tid >> 6, l = tid & 63;
  const int e = l & 15, q = l >> 4;
  const float rbe = rb[e];
  const float* ldsb = &rws[q * RW_Q + e];
#pragma unroll
  for (int i = 0; i < 4; ++i) {
    const int t = blockIdx.x * 16 + w * 4 + i;
    const float* xr = x + (size_t)t * H_DIM + (q << 8);
    float acc = 0.f;
#pragma unroll 8
    for (int hh = 0; hh < 256; hh += 4) {
      f32x4 xv = *(const f32x4*)(xr + hh);
      acc += xv[0] * ldsb[(hh + 0) * 16];
      acc += xv[1] * ldsb[(hh + 1) * 16];
      acc += xv[2] * ldsb[(hh + 2) * 16];
      acc += xv[3] * ldsb[(hh + 3) * 16];
    }
    acc += __shfl_xor(acc, 16);
    acc += __shfl_xor(acc, 32);
    float logit = acc + rbe;
    float m = logit;
    m = fmaxf(m, __shfl_xor(m, 1));
    m = fmaxf(m, __shfl_xor(m, 2));
    m = fmaxf(m, __shfl_xor(m, 4));
    m = fmaxf(m, __shfl_xor(m, 8));
    float ex = expf(logit - m);
    int rank = 0;
    const int b16 = l & 48;
#pragma unroll
    for (int j = 0; j < 16; ++j) {
      float vj = __shfl(ex, b16 + j);
      rank += (vj > ex) || (vj == ex && j < e);
    }
    float sel = (rank < K_TOP) ? ex : 0.f;
    float subs = sel;
    subs += __shfl_xor(subs, 1);
    subs += __shfl_xor(subs, 2);
    subs += __shfl_xor(subs, 4);
    subs += __shfl_xor(subs, 8);
    if (q == 0 && rank < K_TOP) {
      topi[t * K_TOP + rank] = e;
      topw[t * K_TOP + rank] = ex / subs;
      atomicAdd(&counts[e], 1);
    }
  }
}

// ---------------- scatter pairs into per-expert sorted order ------------------
__global__ __launch_bounds__(256) void scatter_kernel(
    const int* __restrict__ topi, const float* __restrict__ topw,
    const int* __restrict__ counts, int* __restrict__ cursor,
    int* __restrict__ pairTok, float* __restrict__ pairW,
    int* __restrict__ pairPos) {
  int padBase[E_NUM];
  int base = 0;
#pragma unroll
  for (int ee = 0; ee < E_NUM; ++ee) {
    padBase[ee] = base;
    base += ((counts[ee] + 127) >> 7) << 7;
  }
  int t = blockIdx.x * 256 + threadIdx.x;
  if (t >= T_TOK) return;
#pragma unroll
  for (int k = 0; k < K_TOP; ++k) {
    int e = topi[t * K_TOP + k];
    int pos = atomicAdd(&cursor[e], 1);
    int idx = padBase[e] + pos;
    pairTok[idx] = t;
    pairW[idx] = topw[t * K_TOP + k];
    pairPos[t * K_TOP + k] = idx;
  }
}

// ---------------- transpose f32 [R][C] -> bf16 [C][R] per expert (z) ----------
__global__ __launch_bounds__(256) void transpose_kernel(
    const float* __restrict__ src, unsigned short* __restrict__ dst, int R,
    int C) {
  size_t es = (size_t)R * C;
  src += es * blockIdx.z;
  dst += es * blockIdx.z;
  int r0 = blockIdx.y * 64, c0 = blockIdx.x * 64;
  __shared__ float tle[64][65];
  int rr = threadIdx.x >> 4, cc = (threadIdx.x & 15) * 4;
#pragma unroll
  for (int i = 0; i < 4; ++i) {
    f32x4 v = *(const f32x4*)(src + (size_t)(r0 + rr + 16 * i) * C + c0 + cc);
    tle[rr + 16 * i][cc + 0] = v[0];
    tle[rr + 16 * i][cc + 1] = v[1];
    tle[rr + 16 * i][cc + 2] = v[2];
    tle[rr + 16 * i][cc + 3] = v[3];
  }
  __syncthreads();
#pragma unroll
  for (int i = 0; i < 4; ++i) {
    int oc = c0 + rr + 16 * i;
    u16x4 o;
    o[0] = f2bf(tle[cc + 0][rr + 16 * i]);
    o[1] = f2bf(tle[cc + 1][rr + 16 * i]);
    o[2] = f2bf(tle[cc + 2][rr + 16 * i]);
    o[3] = f2bf(tle[cc + 3][rr + 16 * i]);
    *(u16x4*)(dst + (size_t)oc * R + r0 + cc) = o;
  }
}

// ---------------- grouped GEMM1: hmid = gelu(x[pairs] @ w1 + b1) --------------
__global__ __launch_bounds__(256, 4) void gemm1_kernel(
    const unsigned short* __restrict__ xb, const unsigned short* __restrict__ w1t,
    const float* __restrict__ b1, unsigned short* __restrict__ hmid,
    const int* __restrict__ pairTok, const int* __restrict__ counts) {
  const int bid = blockIdx.x;
  const int lin = (bid & 7) * 288 + (bid >> 3);  // XCD chunk (2304 blocks)
  const int tx = lin & 15, ty = lin >> 4;
  int tsp = 0;
  const int e = tile_map(counts, ty, &tsp);
  if (e < 0) return;
  const int n0 = tx * 128;
  __shared__ unsigned short As[2][BM * BK];
  __shared__ unsigned short Bs[2][BM * BK];
  const int tid = threadIdx.x, w = tid >> 6, l = tid & 63;
  const int rbase = w * 16 + (l >> 2);
  const int segp = (l & 3) ^ ((l >> 3) & 3);  // swizzled source chunk
  int tok0 = pairTok[tsp + rbase];
  if (tok0 < 0) tok0 = 0;
  int tok1 = pairTok[tsp + rbase + 64];
  if (tok1 < 0) tok1 = 0;
  const char* gA0 = (const char*)(xb + (size_t)tok0 * H_DIM) + segp * 16;
  const char* gA1 = (const char*)(xb + (size_t)tok1 * H_DIM) + segp * 16;
  const unsigned short* wbase = w1t + (size_t)e * I_DIM * H_DIM;
  const char* gB0 = (const char*)(wbase + (size_t)(n0 + rbase) * H_DIM) + segp * 16;
  const char* gB1 = (const char*)(wbase + (size_t)(n0 + rbase + 64) * H_DIM) + segp * 16;

  f32x4 acc[4][4];
#pragma unroll
  for (int m = 0; m < 4; ++m)
#pragma unroll
    for (int n = 0; n < 4; ++n) acc[m][n] = f32x4{0.f, 0.f, 0.f, 0.f};

  const int wr = w >> 1, wc = w & 1, lrow = l & 15, g = l >> 4;
  const int gs = g ^ ((l >> 1) & 3);  // swizzled read chunk
  const int NK = H_DIM / BK;  // 32

  gld16(gA0, &As[0][w * 512]);
  gld16(gA1, &As[0][2048 + w * 512]);
  gld16(gB0, &Bs[0][w * 512]);
  gld16(gB1, &Bs[0][2048 + w * 512]);

  for (int kt = 0; kt < NK; ++kt) {
    __syncthreads();
    if (kt + 1 < NK) {
      const int kb = (kt + 1) * 64;
      const int nb = (kt + 1) & 1;
      gld16(gA0 + kb, &As[nb][w * 512]);
      gld16(gA1 + kb, &As[nb][2048 + w * 512]);
      gld16(gB0 + kb, &Bs[nb][w * 512]);
      gld16(gB1 + kb, &Bs[nb][2048 + w * 512]);
    }
    const int cb = kt & 1;
    const s16x8* Ap = (const s16x8*)As[cb];
    const s16x8* Bp = (const s16x8*)Bs[cb];
    s16x8 av[4], bv[4];
#pragma unroll
    for (int m = 0; m < 4; ++m) av[m] = Ap[(wr * 64 + m * 16 + lrow) * 4 + gs];
#pragma unroll
    for (int n = 0; n < 4; ++n) bv[n] = Bp[(wc * 64 + n * 16 + lrow) * 4 + gs];
#pragma unroll
    for (int m = 0; m < 4; ++m)
#pragma unroll
      for (int n = 0; n < 4; ++n) mfma_bf16(av[m], bv[n], acc[m][n]);
  }

  const float* b1e = b1 + (size_t)e * I_DIM;
#pragma unroll
  for (int m = 0; m < 4; ++m) {
    const int rw0 = wr * 64 + m * 16 + g * 4;
#pragma unroll
    for (int n = 0; n < 4; ++n) {
      const int col = n0 + wc * 64 + n * 16 + lrow;
      const float bb = b1e[col];
      f32x4 v = acc[m][n];
#pragma unroll
      for (int j = 0; j < 4; ++j) {
        const int p = tsp + rw0 + j;
        float xv = v[j] + bb;
        float y = 0.7978845608028654f * (xv + 0.044715f * xv * xv * xv);
        float ey = __expf(2.f * y);
        float th = 1.f - 2.f / (ey + 1.f);
        float ge = 0.5f * xv * (1.f + th);
        hmid[(size_t)p * I_DIM + col] = f2bf(ge);
      }
    }
  }
}

// ---------------- grouped GEMM2 -----------------------------------------------
// mode 2: K-split x2 -> poA/poB bf16 partials (combine sums, applies b2, pw).
// mode 1: full-K -> poA only.  mode 0: legacy atomicAdd into out.
__global__ __launch_bounds__(256, 4) void gemm2_kernel(
    const unsigned short* __restrict__ hmid,
    const unsigned short* __restrict__ w2t, const float* __restrict__ b2,
    float* __restrict__ out, unsigned short* __restrict__ poA,
    unsigned short* __restrict__ poB, const int* __restrict__ pairTok,
    const float* __restrict__ pairW, const int* __restrict__ counts, int mode) {
  const int bid = blockIdx.x;
  const int nchunk = (mode == 2) ? 288 : 144;  // grid/8
  const int lin = (bid & 7) * nchunk + (bid >> 3);
  const int kh = (mode == 2) ? (lin & 1) : 0;
  const int tx = (mode == 2) ? ((lin >> 1) & 7) : (lin & 7);
  const int ty = (mode == 2) ? (lin >> 4) : (lin >> 3);
  int tsp = 0;
  const int e = tile_map(counts, ty, &tsp);
  if (e < 0) return;
  const int n0 = tx * 128;
  __shared__ unsigned short As[2][BM * BK];
  __shared__ unsigned short Bs[2][BM * BK];
  const int tid = threadIdx.x, w = tid >> 6, l = tid & 63;
  const int rbase = w * 16 + (l >> 2);
  const int segp = (l & 3) ^ ((l >> 3) & 3);
  const size_t koff = (size_t)kh * 2048;  // byte offset of K half
  const char* gA0 =
      (const char*)(hmid + (size_t)(tsp + rbase) * I_DIM) + segp * 16 + koff;
  const char* gA1 =
      (const char*)(hmid + (size_t)(tsp + rbase + 64) * I_DIM) + segp * 16 + koff;
  const unsigned short* wbase = w2t + (size_t)e * H_DIM * I_DIM;
  const char* gB0 =
      (const char*)(wbase + (size_t)(n0 + rbase) * I_DIM) + segp * 16 + koff;
  const char* gB1 =
      (const char*)(wbase + (size_t)(n0 + rbase + 64) * I_DIM) + segp * 16 + koff;

  f32x4 acc[4][4];
#pragma unroll
  for (int m = 0; m < 4; ++m)
#pragma unroll
    for (int n = 0; n < 4; ++n) acc[m][n] = f32x4{0.f, 0.f, 0.f, 0.f};

  const int wr = w >> 1, wc = w & 1, lrow = l & 15, g = l >> 4;
  const int gs = g ^ ((l >> 1) & 3);
  const int NK = (mode == 2) ? 32 : 64;

  gld16(gA0, &As[0][w * 512]);
  gld16(gA1, &As[0][2048 + w * 512]);
  gld16(gB0, &Bs[0][w * 512]);
  gld16(gB1, &Bs[0][2048 + w * 512]);

  for (int kt = 0; kt < NK; ++kt) {
    __syncthreads();
    if (kt + 1 < NK) {
      const int kb = (kt + 1) * 64;
      const int nb = (kt + 1) & 1;
      gld16(gA0 + kb, &As[nb][w * 512]);
      gld16(gA1 + kb, &As[nb][2048 + w * 512]);
      gld16(gB0 + kb, &Bs[nb][w * 512]);
      gld16(gB1 + kb, &Bs[nb][2048 + w * 512]);
    }
    const int cb = kt & 1;
    const s16x8* Ap = (const s16x8*)As[cb];
    const s16x8* Bp = (const s16x8*)Bs[cb];
    s16x8 av[4], bv[4];
#pragma unroll
    for (int m = 0; m < 4; ++m) av[m] = Ap[(wr * 64 + m * 16 + lrow) * 4 + gs];
#pragma unroll
    for (int n = 0; n < 4; ++n) bv[n] = Bp[(wc * 64 + n * 16 + lrow) * 4 + gs];
#pragma unroll
    for (int m = 0; m < 4; ++m)
#pragma unroll
      for (int n = 0; n < 4; ++n) mfma_bf16(av[m], bv[n], acc[m][n]);
  }

  if (mode >= 1) {
    unsigned short* po = (kh == 0) ? poA : poB;
#pragma unroll
    for (int m = 0; m < 4; ++m) {
      const int rw0 = wr * 64 + m * 16 + g * 4;
#pragma unroll
      for (int n = 0; n < 4; ++n) {
        const int col = n0 + wc * 64 + n * 16 + lrow;
        f32x4 v = acc[m][n];
#pragma unroll
        for (int j = 0; j < 4; ++j)
          po[(size_t)(tsp + rw0 + j) * H_DIM + col] = f2bf(v[j]);
      }
    }
  } else {
    const float* b2e = b2 + (size_t)e * H_DIM;
#pragma unroll
    for (int m = 0; m < 4; ++m) {
      const int rw0 = wr * 64 + m * 16 + g * 4;
#pragma unroll
      for (int j = 0; j < 4; ++j) {
        const int p = tsp + rw0 + j;
        const int tok = pairTok[p];
        if (tok < 0) continue;
        const float pw = pairW[p];
        float* orow = out + (size_t)tok * H_DIM;
#pragma unroll
        for (int n = 0; n < 4; ++n) {
          const int col = n0 + wc * 64 + n * 16 + lrow;
          float val = (acc[m][n][j] + b2e[col]) * pw;
          atomicAdd(orow + col, val);
        }
      }
    }
  }
}

// ---------------- combine: out[t] = sum_k pw_k * (poA[+poB] + b2[e_k]) --------
__global__ __launch_bounds__(256) void combine_kernel(
    const unsigned short* __restrict__ poA, const unsigned short* __restrict__ poB,
    const int* __restrict__ pairPos, const int* __restrict__ topi,
    const float* __restrict__ topw, const float* __restrict__ b2,
    float* __restrict__ out, int nbuf) {
  const int t = blockIdx.x * 2 + (threadIdx.x >> 7);
  const int c0 = (threadIdx.x & 127) * 8;
  float o[8];
#pragma unroll
  for (int j = 0; j < 8; ++j) o[j] = 0.f;
#pragma unroll
  for (int k = 0; k < K_TOP; ++k) {
    const int e = topi[t * K_TOP + k];
    const float pw = topw[t * K_TOP + k];
    const int pos = pairPos[t * K_TOP + k];
    u16x8 va = *(const u16x8*)(poA + (size_t)pos * H_DIM + c0);
    u16x8 vb;
    if (nbuf == 2) vb = *(const u16x8*)(poB + (size_t)pos * H_DIM + c0);
    const float* b2r = b2 + (size_t)e * H_DIM + c0;
#pragma unroll
    for (int j = 0; j < 8; ++j) {
      float hv = __uint_as_float((unsigned)va[j] << 16);
      if (nbuf == 2) hv += __uint_as_float((unsigned)vb[j] << 16);
      o[j] += pw * (hv + b2r[j]);
    }
  }
  float* orow = out + (size_t)t * H_DIM + c0;
  *(f32x4*)orow = f32x4{o[0], o[1], o[2], o[3]};
  *(f32x4*)(orow + 4) = f32x4{o[4], o[5], o[6], o[7]};
}

// ------------------------------------------------------------------------------
extern "C" void kernel_launch(void* const* d_in, const int* in_sizes, int n_in,
                              void* d_out, int out_size, void* d_ws,
                              size_t ws_size, hipStream_t stream) {
  const float* x = (const float*)d_in[0];
  const float* rw = (const float*)d_in[1];
  const float* rb = (const float*)d_in[2];
  const float* w1 = (const float*)d_in[3];
  const float* b1 = (const float*)d_in[4];
  const float* w2 = (const float*)d_in[5];
  const float* b2 = (const float*)d_in[6];
  float* out = (float*)d_out;
  char* ws = (char*)d_ws;

  const size_t xbSz = (size_t)T_TOK * H_DIM * 2;          // 8.39 MB
  const size_t poSz = (size_t)PAD_PAIRS * H_DIM * 2;      // 37.75 MB
  const size_t wtSz = (size_t)E_NUM * H_DIM * I_DIM * 2;  // 67.11 MB
  const size_t hmSz = (size_t)PAD_PAIRS * I_DIM * 2;      // 75.50 MB
  const size_t smallSz = (size_t)T_TOK * K_TOP * 4 * 3    // topi, topw, pairPos
                         + (size_t)PAD_PAIRS * 4 * 2      // pairTok, pairW
                         + 128;                           // counts+cursor
  const size_t needSplit = poSz * 2 + wtSz + hmSz + smallSz;
  const size_t needRich = poSz + wtSz + hmSz + smallSz;
  const size_t needPoor = xbSz + wtSz + hmSz + smallSz;
  int mode = 0;
  if (ws_size >= needSplit) mode = 2;
  else if (ws_size >= needRich) mode = 1;
  else if (ws_size < needPoor) return;  // diagnostic: output stays 0

  size_t off = 0;
  unsigned short* xb = (unsigned short*)(ws + off);   // union: xb / pairOut-A
  unsigned short* poA = (unsigned short*)(ws + off);  // (xb dead by gemm2)
  off += (mode >= 1) ? poSz : xbSz;
  unsigned short* poB = (unsigned short*)(ws + off);
  if (mode == 2) off += poSz;
  unsigned short* wT = (unsigned short*)(ws + off);
  off += wtSz;  // shared by w1T then w2T
  unsigned short* hmid = (unsigned short*)(ws + off);
  off += hmSz;
  int* topi = (int*)(ws + off);      off += (size_t)T_TOK * K_TOP * 4;
  float* topw = (float*)(ws + off);  off += (size_t)T_TOK * K_TOP * 4;
  int* pairPos = (int*)(ws + off);   off += (size_t)T_TOK * K_TOP * 4;
  int* pairTok = (int*)(ws + off);   off += (size_t)PAD_PAIRS * 4;
  float* pairW = (float*)(ws + off); off += (size_t)PAD_PAIRS * 4;
  int* counts = (int*)(ws + off);    off += 64;
  int* cursor = (int*)(ws + off);    off += 64;

  hipMemsetAsync(counts, 0, 128, stream);  // counts + cursor
  hipMemsetAsync(pairTok, 0xFF, (size_t)PAD_PAIRS * 4, stream);
  if (mode == 0) hipMemsetAsync(out, 0, (size_t)T_TOK * H_DIM * 4, stream);

  cvt_kernel<<<T_TOK * H_DIM / (256 * 8), 256, 0, stream>>>(x, xb);
  router_kernel<<<T_TOK / 16, 256, 0, stream>>>(x, rw, rb, topi, topw, counts);
  scatter_kernel<<<T_TOK / 256, 256, 0, stream>>>(topi, topw, counts, cursor,
                                                  pairTok, pairW, pairPos);
  transpose_kernel<<<dim3(I_DIM / 64, H_DIM / 64, E_NUM), 256, 0, stream>>>(
      w1, wT, H_DIM, I_DIM);
  gemm1_kernel<<<16 * MAX_TILES, 256, 0, stream>>>(xb, wT, b1, hmid, pairTok,
                                                   counts);
  transpose_kernel<<<dim3(H_DIM / 64, I_DIM / 64, E_NUM), 256, 0, stream>>>(
      w2, wT, I_DIM, H_DIM);
  gemm2_kernel<<<(mode == 2 ? 16 : 8) * MAX_TILES, 256, 0, stream>>>(
      hmid, wT, b2, out, poA, poB, pairTok, pairW, counts, mode);
  if (mode >= 1)
    combine_kernel<<<T_TOK / 2, 256, 0, stream>>>(poA, poB, pairPos, topi, topw,
                                                  b2, out, mode);
}

// Round 9
// 417.393 us; speedup vs baseline: 1.3785x; 1.0067x over previous
//
#include <hip/hip_runtime.h>

#define T_TOK 4096
#define H_DIM 1024
#define I_DIM 2048
#define E_NUM 16
#define K_TOP 4
#define BM 128
#define BK 32
#define MAX_TILES 144
#define PAD_PAIRS (MAX_TILES * BM)  // 18432
#define RW_Q 4104                   // padded quarter stride (words) for router rw LDS

typedef __attribute__((ext_vector_type(8))) short s16x8;
typedef __attribute__((ext_vector_type(4))) float f32x4;
typedef __attribute__((ext_vector_type(4))) unsigned short u16x4;
typedef __attribute__((ext_vector_type(8))) unsigned short u16x8;

__device__ __forceinline__ unsigned short f2bf(float f) {
  unsigned u = __float_as_uint(f);
  u += 0x7fffu + ((u >> 16) & 1u);  // round-to-nearest-even
  return (unsigned short)(u >> 16);
}

// asm MFMA: measured best (r2 194us vs r5-builtin 204us).
__device__ __forceinline__ void mfma_bf16(const s16x8& a, const s16x8& b, f32x4& c) {
  asm("v_mfma_f32_16x16x32_bf16 %0, %1, %2, %0" : "+v"(c) : "v"(a), "v"(b));
}

__device__ __forceinline__ void gld16(const void* g, void* l) {
  __builtin_amdgcn_global_load_lds(
      (const __attribute__((address_space(1))) unsigned int*)g,
      (__attribute__((address_space(3))) unsigned int*)l, 16, 0, 0);
}

// Per-block redundant tile map from counts.
__device__ __forceinline__ int tile_map(const int* counts, int ty, int* tsp) {
  int e = -1, acc = 0, base = 0;
#pragma unroll
  for (int ee = 0; ee < E_NUM; ++ee) {
    int tc = (counts[ee] + 127) >> 7;
    if (ty >= acc && ty < acc + tc) {
      e = ee;
      *tsp = base + ((ty - acc) << 7);
    }
    acc += tc;
    base += tc << 7;
  }
  return e;
}

// ---------------- router (+fused x->bf16): lane = (expert, quarter) ----------
__global__ __launch_bounds__(256) void router_kernel(
    const float* __restrict__ x, const float* __restrict__ rw,
    const float* __restrict__ rb, int* __restrict__ topi,
    float* __restrict__ topw, int* __restrict__ counts,
    unsigned short* __restrict__ xb) {
  __shared__ float rws[4 * RW_Q];
  const int tid = threadIdx.x;
  // fused cvt: this block's 16 token rows -> bf16 (16*1024/8 = 2048 chunks)
  {
    const size_t base = (size_t)blockIdx.x * 16 * H_DIM;
#pragma unroll
    for (int it = 0; it < 8; ++it) {
      size_t idx = base + ((size_t)(it * 256 + tid)) * 8;
      f32x4 a = *(const f32x4*)(x + idx);
      f32x4 b = *(const f32x4*)(x + idx + 4);
      u16x8 o;
      o[0] = f2bf(a[0]); o[1] = f2bf(a[1]); o[2] = f2bf(a[2]); o[3] = f2bf(a[3]);
      o[4] = f2bf(b[0]); o[5] = f2bf(b[1]); o[6] = f2bf(b[2]); o[7] = f2bf(b[3]);
      *(u16x8*)(xb + idx) = o;
    }
  }
  for (int idx = tid * 4; idx < H_DIM * E_NUM; idx += 256 * 4) {
    f32x4 v = *(const f32x4*)(rw + idx);
    int h = idx >> 4, e0 = idx & 15;
    *(f32x4*)&rws[(h >> 8) * RW_Q + (h & 255) * 16 + e0] = v;
  }
  __syncthreads();
  const int w = tid >> 6, l = tid & 63;
  const int e = l & 15, q = l >> 4;
  const float rbe = rb[e];
  const float* ldsb = &rws[q * RW_Q + e];
#pragma unroll
  for (int i = 0; i < 4; ++i) {
    const int t = blockIdx.x * 16 + w * 4 + i;
    const float* xr = x + (size_t)t * H_DIM + (q << 8);
    float acc = 0.f;
#pragma unroll 8
    for (int hh = 0; hh < 256; hh += 4) {
      f32x4 xv = *(const f32x4*)(xr + hh);
      acc += xv[0] * ldsb[(hh + 0) * 16];
      acc += xv[1] * ldsb[(hh + 1) * 16];
      acc += xv[2] * ldsb[(hh + 2) * 16];
      acc += xv[3] * ldsb[(hh + 3) * 16];
    }
    acc += __shfl_xor(acc, 16);
    acc += __shfl_xor(acc, 32);
    float logit = acc + rbe;
    float m = logit;
    m = fmaxf(m, __shfl_xor(m, 1));
    m = fmaxf(m, __shfl_xor(m, 2));
    m = fmaxf(m, __shfl_xor(m, 4));
    m = fmaxf(m, __shfl_xor(m, 8));
    float ex = expf(logit - m);
    int rank = 0;
    const int b16 = l & 48;
#pragma unroll
    for (int j = 0; j < 16; ++j) {
      float vj = __shfl(ex, b16 + j);
      rank += (vj > ex) || (vj == ex && j < e);
    }
    float sel = (rank < K_TOP) ? ex : 0.f;
    float subs = sel;
    subs += __shfl_xor(subs, 1);
    subs += __shfl_xor(subs, 2);
    subs += __shfl_xor(subs, 4);
    subs += __shfl_xor(subs, 8);
    if (q == 0 && rank < K_TOP) {
      topi[t * K_TOP + rank] = e;
      topw[t * K_TOP + rank] = ex / subs;
      atomicAdd(&counts[e], 1);
    }
  }
}

// ---------------- scatter pairs into per-expert sorted order ------------------
__global__ __launch_bounds__(256) void scatter_kernel(
    const int* __restrict__ topi, const float* __restrict__ topw,
    const int* __restrict__ counts, int* __restrict__ cursor,
    int* __restrict__ pairTok, float* __restrict__ pairW,
    int* __restrict__ pairPos) {
  int padBase[E_NUM];
  int base = 0;
#pragma unroll
  for (int ee = 0; ee < E_NUM; ++ee) {
    padBase[ee] = base;
    base += ((counts[ee] + 127) >> 7) << 7;
  }
  int t = blockIdx.x * 256 + threadIdx.x;
  if (t >= T_TOK) return;
#pragma unroll
  for (int k = 0; k < K_TOP; ++k) {
    int e = topi[t * K_TOP + k];
    int pos = atomicAdd(&cursor[e], 1);
    int idx = padBase[e] + pos;
    pairTok[idx] = t;
    pairW[idx] = topw[t * K_TOP + k];
    pairPos[t * K_TOP + k] = idx;
  }
}

// ---------------- transpose tile body -----------------------------------------
__device__ __forceinline__ void transpose_tile(const float* __restrict__ src,
                                               unsigned short* __restrict__ dst,
                                               int R, int C, int tx, int ty) {
  int r0 = ty * 64, c0 = tx * 64;
  __shared__ float tle[64][65];
  int rr = threadIdx.x >> 4, cc = (threadIdx.x & 15) * 4;
#pragma unroll
  for (int i = 0; i < 4; ++i) {
    f32x4 v = *(const f32x4*)(src + (size_t)(r0 + rr + 16 * i) * C + c0 + cc);
    tle[rr + 16 * i][cc + 0] = v[0];
    tle[rr + 16 * i][cc + 1] = v[1];
    tle[rr + 16 * i][cc + 2] = v[2];
    tle[rr + 16 * i][cc + 3] = v[3];
  }
  __syncthreads();
#pragma unroll
  for (int i = 0; i < 4; ++i) {
    int oc = c0 + rr + 16 * i;
    u16x4 o;
    o[0] = f2bf(tle[cc + 0][rr + 16 * i]);
    o[1] = f2bf(tle[cc + 1][rr + 16 * i]);
    o[2] = f2bf(tle[cc + 2][rr + 16 * i]);
    o[3] = f2bf(tle[cc + 3][rr + 16 * i]);
    *(u16x4*)(dst + (size_t)oc * R + r0 + cc) = o;
  }
}

// legacy per-matrix transpose (fallback modes <3)
__global__ __launch_bounds__(256) void transpose_kernel(
    const float* __restrict__ src, unsigned short* __restrict__ dst, int R,
    int C) {
  size_t es = (size_t)R * C;
  transpose_tile(src + es * blockIdx.z, dst + es * blockIdx.z, R, C,
                 blockIdx.x, blockIdx.y);
}

// combined: w1 (16x[1024][2048]) and w2 (16x[2048][1024]) in one launch
__global__ __launch_bounds__(256) void transpose2_kernel(
    const float* __restrict__ w1, const float* __restrict__ w2,
    unsigned short* __restrict__ wT1, unsigned short* __restrict__ wT2) {
  const int bid = blockIdx.x;          // 0..16383
  const size_t es = (size_t)H_DIM * I_DIM;
  if (bid < 8192) {                    // w1: per expert 512 tiles (32x x 16y)
    const int e = bid >> 9, tb = bid & 511;
    transpose_tile(w1 + es * e, wT1 + es * e, H_DIM, I_DIM, tb & 31, tb >> 5);
  } else {                             // w2: per expert 512 tiles (16x x 32y)
    const int eb = bid - 8192;
    const int e = eb >> 9, tb = eb & 511;
    transpose_tile(w2 + es * e, wT2 + es * e, I_DIM, H_DIM, tb & 15, tb >> 4);
  }
}

// ---------------- grouped GEMM1: hmid = gelu(x[pairs] @ w1 + b1) --------------
__global__ __launch_bounds__(256, 4) void gemm1_kernel(
    const unsigned short* __restrict__ xb, const unsigned short* __restrict__ w1t,
    const float* __restrict__ b1, unsigned short* __restrict__ hmid,
    const int* __restrict__ pairTok, const int* __restrict__ counts) {
  const int bid = blockIdx.x;
  const int lin = (bid & 7) * 288 + (bid >> 3);  // XCD chunk (2304 blocks)
  const int tx = lin & 15, ty = lin >> 4;
  int tsp = 0;
  const int e = tile_map(counts, ty, &tsp);
  if (e < 0) return;
  const int n0 = tx * 128;
  __shared__ unsigned short As[2][BM * BK];
  __shared__ unsigned short Bs[2][BM * BK];
  const int tid = threadIdx.x, w = tid >> 6, l = tid & 63;
  const int rbase = w * 16 + (l >> 2);
  const int segp = (l & 3) ^ ((l >> 3) & 3);  // swizzled source chunk
  int tok0 = pairTok[tsp + rbase];
  if (tok0 < 0) tok0 = 0;
  int tok1 = pairTok[tsp + rbase + 64];
  if (tok1 < 0) tok1 = 0;
  const char* gA0 = (const char*)(xb + (size_t)tok0 * H_DIM) + segp * 16;
  const char* gA1 = (const char*)(xb + (size_t)tok1 * H_DIM) + segp * 16;
  const unsigned short* wbase = w1t + (size_t)e * I_DIM * H_DIM;
  const char* gB0 = (const char*)(wbase + (size_t)(n0 + rbase) * H_DIM) + segp * 16;
  const char* gB1 = (const char*)(wbase + (size_t)(n0 + rbase + 64) * H_DIM) + segp * 16;

  f32x4 acc[4][4];
#pragma unroll
  for (int m = 0; m < 4; ++m)
#pragma unroll
    for (int n = 0; n < 4; ++n) acc[m][n] = f32x4{0.f, 0.f, 0.f, 0.f};

  const int wr = w >> 1, wc = w & 1, lrow = l & 15, g = l >> 4;
  const int gs = g ^ ((l >> 1) & 3);  // swizzled read chunk
  const int NK = H_DIM / BK;  // 32

  gld16(gA0, &As[0][w * 512]);
  gld16(gA1, &As[0][2048 + w * 512]);
  gld16(gB0, &Bs[0][w * 512]);
  gld16(gB1, &Bs[0][2048 + w * 512]);

  for (int kt = 0; kt < NK; ++kt) {
    __syncthreads();
    if (kt + 1 < NK) {
      const int kb = (kt + 1) * 64;
      const int nb = (kt + 1) & 1;
      gld16(gA0 + kb, &As[nb][w * 512]);
      gld16(gA1 + kb, &As[nb][2048 + w * 512]);
      gld16(gB0 + kb, &Bs[nb][w * 512]);
      gld16(gB1 + kb, &Bs[nb][2048 + w * 512]);
    }
    const int cb = kt & 1;
    const s16x8* Ap = (const s16x8*)As[cb];
    const s16x8* Bp = (const s16x8*)Bs[cb];
    s16x8 av[4], bv[4];
#pragma unroll
    for (int m = 0; m < 4; ++m) av[m] = Ap[(wr * 64 + m * 16 + lrow) * 4 + gs];
#pragma unroll
    for (int n = 0; n < 4; ++n) bv[n] = Bp[(wc * 64 + n * 16 + lrow) * 4 + gs];
#pragma unroll
    for (int m = 0; m < 4; ++m)
#pragma unroll
      for (int n = 0; n < 4; ++n) mfma_bf16(av[m], bv[n], acc[m][n]);
  }

  const float* b1e = b1 + (size_t)e * I_DIM;
#pragma unroll
  for (int m = 0; m < 4; ++m) {
    const int rw0 = wr * 64 + m * 16 + g * 4;
#pragma unroll
    for (int n = 0; n < 4; ++n) {
      const int col = n0 + wc * 64 + n * 16 + lrow;
      const float bb = b1e[col];
      f32x4 v = acc[m][n];
#pragma unroll
      for (int j = 0; j < 4; ++j) {
        const int p = tsp + rw0 + j;
        float xv = v[j] + bb;
        float y = 0.7978845608028654f * (xv + 0.044715f * xv * xv * xv);
        float ey = __expf(2.f * y);
        float th = 1.f - 2.f / (ey + 1.f);
        float ge = 0.5f * xv * (1.f + th);
        hmid[(size_t)p * I_DIM + col] = f2bf(ge);
      }
    }
  }
}

// ---------------- grouped GEMM2 -----------------------------------------------
// mode 2: K-split x2 -> poA/poB bf16 partials. mode 1: full-K -> poA.
// mode 0: legacy atomicAdd into out.
__global__ __launch_bounds__(256, 4) void gemm2_kernel(
    const unsigned short* __restrict__ hmid,
    const unsigned short* __restrict__ w2t, const float* __restrict__ b2,
    float* __restrict__ out, unsigned short* __restrict__ poA,
    unsigned short* __restrict__ poB, const int* __restrict__ pairTok,
    const float* __restrict__ pairW, const int* __restrict__ counts, int mode) {
  const int bid = blockIdx.x;
  const int nchunk = (mode == 2) ? 288 : 144;  // grid/8
  const int lin = (bid & 7) * nchunk + (bid >> 3);
  const int kh = (mode == 2) ? (lin & 1) : 0;
  const int tx = (mode == 2) ? ((lin >> 1) & 7) : (lin & 7);
  const int ty = (mode == 2) ? (lin >> 4) : (lin >> 3);
  int tsp = 0;
  const int e = tile_map(counts, ty, &tsp);
  if (e < 0) return;
  const int n0 = tx * 128;
  __shared__ unsigned short As[2][BM * BK];
  __shared__ unsigned short Bs[2][BM * BK];
  const int tid = threadIdx.x, w = tid >> 6, l = tid & 63;
  const int rbase = w * 16 + (l >> 2);
  const int segp = (l & 3) ^ ((l >> 3) & 3);
  const size_t koff = (size_t)kh * 2048;  // byte offset of K half
  const char* gA0 =
      (const char*)(hmid + (size_t)(tsp + rbase) * I_DIM) + segp * 16 + koff;
  const char* gA1 =
      (const char*)(hmid + (size_t)(tsp + rbase + 64) * I_DIM) + segp * 16 + koff;
  const unsigned short* wbase = w2t + (size_t)e * H_DIM * I_DIM;
  const char* gB0 =
      (const char*)(wbase + (size_t)(n0 + rbase) * I_DIM) + segp * 16 + koff;
  const char* gB1 =
      (const char*)(wbase + (size_t)(n0 + rbase + 64) * I_DIM) + segp * 16 + koff;

  f32x4 acc[4][4];
#pragma unroll
  for (int m = 0; m < 4; ++m)
#pragma unroll
    for (int n = 0; n < 4; ++n) acc[m][n] = f32x4{0.f, 0.f, 0.f, 0.f};

  const int wr = w >> 1, wc = w & 1, lrow = l & 15, g = l >> 4;
  const int gs = g ^ ((l >> 1) & 3);
  const int NK = (mode == 2) ? 32 : 64;

  gld16(gA0, &As[0][w * 512]);
  gld16(gA1, &As[0][2048 + w * 512]);
  gld16(gB0, &Bs[0][w * 512]);
  gld16(gB1, &Bs[0][2048 + w * 512]);

  for (int kt = 0; kt < NK; ++kt) {
    __syncthreads();
    if (kt + 1 < NK) {
      const int kb = (kt + 1) * 64;
      const int nb = (kt + 1) & 1;
      gld16(gA0 + kb, &As[nb][w * 512]);
      gld16(gA1 + kb, &As[nb][2048 + w * 512]);
      gld16(gB0 + kb, &Bs[nb][w * 512]);
      gld16(gB1 + kb, &Bs[nb][2048 + w * 512]);
    }
    const int cb = kt & 1;
    const s16x8* Ap = (const s16x8*)As[cb];
    const s16x8* Bp = (const s16x8*)Bs[cb];
    s16x8 av[4], bv[4];
#pragma unroll
    for (int m = 0; m < 4; ++m) av[m] = Ap[(wr * 64 + m * 16 + lrow) * 4 + gs];
#pragma unroll
    for (int n = 0; n < 4; ++n) bv[n] = Bp[(wc * 64 + n * 16 + lrow) * 4 + gs];
#pragma unroll
    for (int m = 0; m < 4; ++m)
#pragma unroll
      for (int n = 0; n < 4; ++n) mfma_bf16(av[m], bv[n], acc[m][n]);
  }

  if (mode >= 1) {
    unsigned short* po = (kh == 0) ? poA : poB;
#pragma unroll
    for (int m = 0; m < 4; ++m) {
      const int rw0 = wr * 64 + m * 16 + g * 4;
#pragma unroll
      for (int n = 0; n < 4; ++n) {
        const int col = n0 + wc * 64 + n * 16 + lrow;
        f32x4 v = acc[m][n];
#pragma unroll
        for (int j = 0; j < 4; ++j)
          po[(size_t)(tsp + rw0 + j) * H_DIM + col] = f2bf(v[j]);
      }
    }
  } else {
    const float* b2e = b2 + (size_t)e * H_DIM;
#pragma unroll
    for (int m = 0; m < 4; ++m) {
      const int rw0 = wr * 64 + m * 16 + g * 4;
#pragma unroll
      for (int j = 0; j < 4; ++j) {
        const int p = tsp + rw0 + j;
        const int tok = pairTok[p];
        if (tok < 0) continue;
        const float pw = pairW[p];
        float* orow = out + (size_t)tok * H_DIM;
#pragma unroll
        for (int n = 0; n < 4; ++n) {
          const int col = n0 + wc * 64 + n * 16 + lrow;
          float val = (acc[m][n][j] + b2e[col]) * pw;
          atomicAdd(orow + col, val);
        }
      }
    }
  }
}

// ---------------- combine: out[t] = sum_k pw_k * (poA[+poB] + b2[e_k]) --------
__global__ __launch_bounds__(256) void combine_kernel(
    const unsigned short* __restrict__ poA, const unsigned short* __restrict__ poB,
    const int* __restrict__ pairPos, const int* __restrict__ topi,
    const float* __restrict__ topw, const float* __restrict__ b2,
    float* __restrict__ out, int nbuf) {
  const int t = blockIdx.x * 2 + (threadIdx.x >> 7);
  const int c0 = (threadIdx.x & 127) * 8;
  float o[8];
#pragma unroll
  for (int j = 0; j < 8; ++j) o[j] = 0.f;
#pragma unroll
  for (int k = 0; k < K_TOP; ++k) {
    const int e = topi[t * K_TOP + k];
    const float pw = topw[t * K_TOP + k];
    const int pos = pairPos[t * K_TOP + k];
    u16x8 va = *(const u16x8*)(poA + (size_t)pos * H_DIM + c0);
    u16x8 vb;
    if (nbuf == 2) vb = *(const u16x8*)(poB + (size_t)pos * H_DIM + c0);
    const float* b2r = b2 + (size_t)e * H_DIM + c0;
#pragma unroll
    for (int j = 0; j < 8; ++j) {
      float hv = __uint_as_float((unsigned)va[j] << 16);
      if (nbuf == 2) hv += __uint_as_float((unsigned)vb[j] << 16);
      o[j] += pw * (hv + b2r[j]);
    }
  }
  float* orow = out + (size_t)t * H_DIM + c0;
  *(f32x4*)orow = f32x4{o[0], o[1], o[2], o[3]};
  *(f32x4*)(orow + 4) = f32x4{o[4], o[5], o[6], o[7]};
}

// ------------------------------------------------------------------------------
extern "C" void kernel_launch(void* const* d_in, const int* in_sizes, int n_in,
                              void* d_out, int out_size, void* d_ws,
                              size_t ws_size, hipStream_t stream) {
  const float* x = (const float*)d_in[0];
  const float* rw = (const float*)d_in[1];
  const float* rb = (const float*)d_in[2];
  const float* w1 = (const float*)d_in[3];
  const float* b1 = (const float*)d_in[4];
  const float* w2 = (const float*)d_in[5];
  const float* b2 = (const float*)d_in[6];
  float* out = (float*)d_out;
  char* ws = (char*)d_ws;

  const size_t xbSz = (size_t)T_TOK * H_DIM * 2;          // 8.39 MB
  const size_t poSz = (size_t)PAD_PAIRS * H_DIM * 2;      // 37.75 MB
  const size_t wtSz = (size_t)E_NUM * H_DIM * I_DIM * 2;  // 67.11 MB
  const size_t hmSz = (size_t)PAD_PAIRS * I_DIM * 2;      // 75.50 MB
  const size_t smallSz = (size_t)T_TOK * K_TOP * 4 * 3    // topi, topw, pairPos
                         + (size_t)PAD_PAIRS * 4 * 2      // pairTok, pairW
                         + 128;                           // counts+cursor
  const size_t need3 = poSz * 2 + wtSz * 2 + hmSz + smallSz;  // ~293.7 MB
  const size_t need2 = poSz * 2 + wtSz + hmSz + smallSz;      // ~226.6 MB
  const size_t need1 = poSz + wtSz + hmSz + smallSz;
  const size_t need0 = xbSz + wtSz + hmSz + smallSz;
  int mode;
  if (ws_size >= need3) mode = 3;
  else if (ws_size >= need2) mode = 2;
  else if (ws_size >= need1) mode = 1;
  else if (ws_size >= need0) mode = 0;
  else return;  // diagnostic: output stays 0

  size_t off = 0;
  unsigned short* xb = (unsigned short*)(ws + off);   // union: xb / pairOut-A
  unsigned short* poA = (unsigned short*)(ws + off);  // (xb dead by gemm2)
  off += (mode >= 1) ? poSz : xbSz;
  unsigned short* poB = (unsigned short*)(ws + off);
  if (mode >= 2) off += poSz;
  unsigned short* wT1 = (unsigned short*)(ws + off);
  off += wtSz;
  unsigned short* wT2 = wT1;  // modes <3: sequential reuse
  if (mode == 3) { wT2 = (unsigned short*)(ws + off); off += wtSz; }
  unsigned short* hmid = (unsigned short*)(ws + off);
  off += hmSz;
  int* topi = (int*)(ws + off);      off += (size_t)T_TOK * K_TOP * 4;
  float* topw = (float*)(ws + off);  off += (size_t)T_TOK * K_TOP * 4;
  int* pairPos = (int*)(ws + off);   off += (size_t)T_TOK * K_TOP * 4;
  int* pairTok = (int*)(ws + off);   off += (size_t)PAD_PAIRS * 4;
  float* pairW = (float*)(ws + off); off += (size_t)PAD_PAIRS * 4;
  int* counts = (int*)(ws + off);    off += 64;
  int* cursor = (int*)(ws + off);    off += 64;

  const int gmode = (mode >= 2) ? 2 : mode;  // gemm2/combine capability level

  hipMemsetAsync(counts, 0, 128, stream);  // counts + cursor
  hipMemsetAsync(pairTok, 0xFF, (size_t)PAD_PAIRS * 4, stream);
  if (gmode == 0) hipMemsetAsync(out, 0, (size_t)T_TOK * H_DIM * 4, stream);

  router_kernel<<<T_TOK / 16, 256, 0, stream>>>(x, rw, rb, topi, topw, counts,
                                                xb);
  scatter_kernel<<<T_TOK / 256, 256, 0, stream>>>(topi, topw, counts, cursor,
                                                  pairTok, pairW, pairPos);
  if (mode == 3) {
    transpose2_kernel<<<16384, 256, 0, stream>>>(w1, w2, wT1, wT2);
    gemm1_kernel<<<16 * MAX_TILES, 256, 0, stream>>>(xb, wT1, b1, hmid, pairTok,
                                                     counts);
  } else {
    transpose_kernel<<<dim3(I_DIM / 64, H_DIM / 64, E_NUM), 256, 0, stream>>>(
        w1, wT1, H_DIM, I_DIM);
    gemm1_kernel<<<16 * MAX_TILES, 256, 0, stream>>>(xb, wT1, b1, hmid, pairTok,
                                                     counts);
    transpose_kernel<<<dim3(H_DIM / 64, I_DIM / 64, E_NUM), 256, 0, stream>>>(
        w2, wT2, I_DIM, H_DIM);
  }
  gemm2_kernel<<<(gmode == 2 ? 16 : 8) * MAX_TILES, 256, 0, stream>>>(
      hmid, wT2, b2, out, poA, poB, pairTok, pairW, counts, gmode);
  if (gmode >= 1)
    combine_kernel<<<T_TOK / 2, 256, 0, stream>>>(poA, poB, pairPos, topi, topw,
                                                  b2, out, gmode);
}

// Round 10
// 412.541 us; speedup vs baseline: 1.3947x; 1.0118x over previous
//
#include <hip/hip_runtime.h>

#define T_TOK 4096
#define H_DIM 1024
#define I_DIM 2048
#define E_NUM 16
#define K_TOP 4
#define BM 128
#define BK 32
#define MAX_TILES 144
#define PAD_PAIRS (MAX_TILES * BM)  // 18432
#define RW_Q 4104                   // padded quarter stride (words) for router rw LDS

typedef __attribute__((ext_vector_type(8))) short s16x8;
typedef __attribute__((ext_vector_type(4))) float f32x4;
typedef __attribute__((ext_vector_type(4))) unsigned short u16x4;
typedef __attribute__((ext_vector_type(8))) unsigned short u16x8;

#define DSR(dst, addr, off) \
  asm volatile("ds_read_b128 %0, %1 offset:" #off : "=v"(dst) : "v"(addr))

__device__ __forceinline__ unsigned short f2bf(float f) {
  unsigned u = __float_as_uint(f);
  u += 0x7fffu + ((u >> 16) & 1u);  // round-to-nearest-even
  return (unsigned short)(u >> 16);
}

// asm MFMA: measured best (r2 194us vs r5-builtin 204us).
__device__ __forceinline__ void mfma_bf16(const s16x8& a, const s16x8& b, f32x4& c) {
  asm("v_mfma_f32_16x16x32_bf16 %0, %1, %2, %0" : "+v"(c) : "v"(a), "v"(b));
}

__device__ __forceinline__ void gld16(const void* g, void* l) {
  __builtin_amdgcn_global_load_lds(
      (const __attribute__((address_space(1))) unsigned int*)g,
      (__attribute__((address_space(3))) unsigned int*)l, 16, 0, 0);
}

// Per-block redundant tile map from counts.
__device__ __forceinline__ int tile_map(const int* counts, int ty, int* tsp) {
  int e = -1, acc = 0, base = 0;
#pragma unroll
  for (int ee = 0; ee < E_NUM; ++ee) {
    int tc = (counts[ee] + 127) >> 7;
    if (ty >= acc && ty < acc + tc) {
      e = ee;
      *tsp = base + ((ty - acc) << 7);
    }
    acc += tc;
    base += tc << 7;
  }
  return e;
}

// ---------------- router (+fused x->bf16): lane = (expert, quarter) ----------
__global__ __launch_bounds__(256) void router_kernel(
    const float* __restrict__ x, const float* __restrict__ rw,
    const float* __restrict__ rb, int* __restrict__ topi,
    float* __restrict__ topw, int* __restrict__ counts,
    unsigned short* __restrict__ xb) {
  __shared__ float rws[4 * RW_Q];
  const int tid = threadIdx.x;
  {
    const size_t base = (size_t)blockIdx.x * 16 * H_DIM;
#pragma unroll
    for (int it = 0; it < 8; ++it) {
      size_t idx = base + ((size_t)(it * 256 + tid)) * 8;
      f32x4 a = *(const f32x4*)(x + idx);
      f32x4 b = *(const f32x4*)(x + idx + 4);
      u16x8 o;
      o[0] = f2bf(a[0]); o[1] = f2bf(a[1]); o[2] = f2bf(a[2]); o[3] = f2bf(a[3]);
      o[4] = f2bf(b[0]); o[5] = f2bf(b[1]); o[6] = f2bf(b[2]); o[7] = f2bf(b[3]);
      *(u16x8*)(xb + idx) = o;
    }
  }
  for (int idx = tid * 4; idx < H_DIM * E_NUM; idx += 256 * 4) {
    f32x4 v = *(const f32x4*)(rw + idx);
    int h = idx >> 4, e0 = idx & 15;
    *(f32x4*)&rws[(h >> 8) * RW_Q + (h & 255) * 16 + e0] = v;
  }
  __syncthreads();
  const int w = tid >> 6, l = tid & 63;
  const int e = l & 15, q = l >> 4;
  const float rbe = rb[e];
  const float* ldsb = &rws[q * RW_Q + e];
#pragma unroll
  for (int i = 0; i < 4; ++i) {
    const int t = blockIdx.x * 16 + w * 4 + i;
    const float* xr = x + (size_t)t * H_DIM + (q << 8);
    float acc = 0.f;
#pragma unroll 8
    for (int hh = 0; hh < 256; hh += 4) {
      f32x4 xv = *(const f32x4*)(xr + hh);
      acc += xv[0] * ldsb[(hh + 0) * 16];
      acc += xv[1] * ldsb[(hh + 1) * 16];
      acc += xv[2] * ldsb[(hh + 2) * 16];
      acc += xv[3] * ldsb[(hh + 3) * 16];
    }
    acc += __shfl_xor(acc, 16);
    acc += __shfl_xor(acc, 32);
    float logit = acc + rbe;
    float m = logit;
    m = fmaxf(m, __shfl_xor(m, 1));
    m = fmaxf(m, __shfl_xor(m, 2));
    m = fmaxf(m, __shfl_xor(m, 4));
    m = fmaxf(m, __shfl_xor(m, 8));
    float ex = expf(logit - m);
    int rank = 0;
    const int b16 = l & 48;
#pragma unroll
    for (int j = 0; j < 16; ++j) {
      float vj = __shfl(ex, b16 + j);
      rank += (vj > ex) || (vj == ex && j < e);
    }
    float sel = (rank < K_TOP) ? ex : 0.f;
    float subs = sel;
    subs += __shfl_xor(subs, 1);
    subs += __shfl_xor(subs, 2);
    subs += __shfl_xor(subs, 4);
    subs += __shfl_xor(subs, 8);
    if (q == 0 && rank < K_TOP) {
      topi[t * K_TOP + rank] = e;
      topw[t * K_TOP + rank] = ex / subs;
      atomicAdd(&counts[e], 1);
    }
  }
}

// ---------------- scatter + padding clear -------------------------------------
__global__ __launch_bounds__(256) void scatter_kernel(
    const int* __restrict__ topi, const float* __restrict__ topw,
    const int* __restrict__ counts, int* __restrict__ cursor,
    int* __restrict__ pairTok, float* __restrict__ pairW,
    int* __restrict__ pairPos) {
  int padBase[E_NUM];
  int base = 0;
#pragma unroll
  for (int ee = 0; ee < E_NUM; ++ee) {
    padBase[ee] = base;
    base += ((counts[ee] + 127) >> 7) << 7;
  }
  const int t = blockIdx.x * 256 + threadIdx.x;  // 0..4095, always < T_TOK
#pragma unroll
  for (int k = 0; k < K_TOP; ++k) {
    int e = topi[t * K_TOP + k];
    int pos = atomicAdd(&cursor[e], 1);
    int idx = padBase[e] + pos;
    pairTok[idx] = t;
    pairW[idx] = topw[t * K_TOP + k];
    pairPos[t * K_TOP + k] = idx;
  }
  // clear never-claimed padding slots (replaces the pairTok memset dispatch);
  // disjoint from claimed range [padBase, padBase+counts) -> race-free.
#pragma unroll
  for (int ee = 0; ee < E_NUM; ++ee) {
    int c = counts[ee];
    int padded = ((c + 127) >> 7) << 7;
    int o = c + t;
    if (o < padded) pairTok[padBase[ee] + o] = -1;
  }
}

// ---------------- transpose tile body -----------------------------------------
__device__ __forceinline__ void transpose_tile(const float* __restrict__ src,
                                               unsigned short* __restrict__ dst,
                                               int R, int C, int tx, int ty) {
  int r0 = ty * 64, c0 = tx * 64;
  __shared__ float tle[64][65];
  int rr = threadIdx.x >> 4, cc = (threadIdx.x & 15) * 4;
#pragma unroll
  for (int i = 0; i < 4; ++i) {
    f32x4 v = *(const f32x4*)(src + (size_t)(r0 + rr + 16 * i) * C + c0 + cc);
    tle[rr + 16 * i][cc + 0] = v[0];
    tle[rr + 16 * i][cc + 1] = v[1];
    tle[rr + 16 * i][cc + 2] = v[2];
    tle[rr + 16 * i][cc + 3] = v[3];
  }
  __syncthreads();
#pragma unroll
  for (int i = 0; i < 4; ++i) {
    int oc = c0 + rr + 16 * i;
    u16x4 o;
    o[0] = f2bf(tle[cc + 0][rr + 16 * i]);
    o[1] = f2bf(tle[cc + 1][rr + 16 * i]);
    o[2] = f2bf(tle[cc + 2][rr + 16 * i]);
    o[3] = f2bf(tle[cc + 3][rr + 16 * i]);
    *(u16x4*)(dst + (size_t)oc * R + r0 + cc) = o;
  }
}

__global__ __launch_bounds__(256) void transpose_kernel(
    const float* __restrict__ src, unsigned short* __restrict__ dst, int R,
    int C) {
  size_t es = (size_t)R * C;
  transpose_tile(src + es * blockIdx.z, dst + es * blockIdx.z, R, C,
                 blockIdx.x, blockIdx.y);
}

__global__ __launch_bounds__(256) void transpose2_kernel(
    const float* __restrict__ w1, const float* __restrict__ w2,
    unsigned short* __restrict__ wT1, unsigned short* __restrict__ wT2) {
  const int bid = blockIdx.x;  // 0..16383
  const size_t es = (size_t)H_DIM * I_DIM;
  if (bid < 8192) {
    const int e = bid >> 9, tb = bid & 511;
    transpose_tile(w1 + es * e, wT1 + es * e, H_DIM, I_DIM, tb & 31, tb >> 5);
  } else {
    const int eb = bid - 8192;
    const int e = eb >> 9, tb = eb & 511;
    transpose_tile(w2 + es * e, wT2 + es * e, I_DIM, H_DIM, tb & 15, tb >> 4);
  }
}

// ---------------- grouped GEMM1 (UNCHANGED r9 control) ------------------------
__global__ __launch_bounds__(256, 4) void gemm1_kernel(
    const unsigned short* __restrict__ xb, const unsigned short* __restrict__ w1t,
    const float* __restrict__ b1, unsigned short* __restrict__ hmid,
    const int* __restrict__ pairTok, const int* __restrict__ counts) {
  const int bid = blockIdx.x;
  const int lin = (bid & 7) * 288 + (bid >> 3);  // XCD chunk (2304 blocks)
  const int tx = lin & 15, ty = lin >> 4;
  int tsp = 0;
  const int e = tile_map(counts, ty, &tsp);
  if (e < 0) return;
  const int n0 = tx * 128;
  __shared__ unsigned short As[2][BM * BK];
  __shared__ unsigned short Bs[2][BM * BK];
  const int tid = threadIdx.x, w = tid >> 6, l = tid & 63;
  const int rbase = w * 16 + (l >> 2);
  const int segp = (l & 3) ^ ((l >> 3) & 3);
  int tok0 = pairTok[tsp + rbase];
  if (tok0 < 0) tok0 = 0;
  int tok1 = pairTok[tsp + rbase + 64];
  if (tok1 < 0) tok1 = 0;
  const char* gA0 = (const char*)(xb + (size_t)tok0 * H_DIM) + segp * 16;
  const char* gA1 = (const char*)(xb + (size_t)tok1 * H_DIM) + segp * 16;
  const unsigned short* wbase = w1t + (size_t)e * I_DIM * H_DIM;
  const char* gB0 = (const char*)(wbase + (size_t)(n0 + rbase) * H_DIM) + segp * 16;
  const char* gB1 = (const char*)(wbase + (size_t)(n0 + rbase + 64) * H_DIM) + segp * 16;

  f32x4 acc[4][4];
#pragma unroll
  for (int m = 0; m < 4; ++m)
#pragma unroll
    for (int n = 0; n < 4; ++n) acc[m][n] = f32x4{0.f, 0.f, 0.f, 0.f};

  const int wr = w >> 1, wc = w & 1, lrow = l & 15, g = l >> 4;
  const int gs = g ^ ((l >> 1) & 3);
  const int NK = H_DIM / BK;  // 32

  gld16(gA0, &As[0][w * 512]);
  gld16(gA1, &As[0][2048 + w * 512]);
  gld16(gB0, &Bs[0][w * 512]);
  gld16(gB1, &Bs[0][2048 + w * 512]);

  for (int kt = 0; kt < NK; ++kt) {
    __syncthreads();
    if (kt + 1 < NK) {
      const int kb = (kt + 1) * 64;
      const int nb = (kt + 1) & 1;
      gld16(gA0 + kb, &As[nb][w * 512]);
      gld16(gA1 + kb, &As[nb][2048 + w * 512]);
      gld16(gB0 + kb, &Bs[nb][w * 512]);
      gld16(gB1 + kb, &Bs[nb][2048 + w * 512]);
    }
    const int cb = kt & 1;
    const s16x8* Ap = (const s16x8*)As[cb];
    const s16x8* Bp = (const s16x8*)Bs[cb];
    s16x8 av[4], bv[4];
#pragma unroll
    for (int m = 0; m < 4; ++m) av[m] = Ap[(wr * 64 + m * 16 + lrow) * 4 + gs];
#pragma unroll
    for (int n = 0; n < 4; ++n) bv[n] = Bp[(wc * 64 + n * 16 + lrow) * 4 + gs];
#pragma unroll
    for (int m = 0; m < 4; ++m)
#pragma unroll
      for (int n = 0; n < 4; ++n) mfma_bf16(av[m], bv[n], acc[m][n]);
  }

  const float* b1e = b1 + (size_t)e * I_DIM;
#pragma unroll
  for (int m = 0; m < 4; ++m) {
    const int rw0 = wr * 64 + m * 16 + g * 4;
#pragma unroll
    for (int n = 0; n < 4; ++n) {
      const int col = n0 + wc * 64 + n * 16 + lrow;
      const float bb = b1e[col];
      f32x4 v = acc[m][n];
#pragma unroll
      for (int j = 0; j < 4; ++j) {
        const int p = tsp + rw0 + j;
        float xv = v[j] + bb;
        float y = 0.7978845608028654f * (xv + 0.044715f * xv * xv * xv);
        float ey = __expf(2.f * y);
        float th = 1.f - 2.f / (ey + 1.f);
        float ge = 0.5f * xv * (1.f + th);
        hmid[(size_t)p * I_DIM + col] = f2bf(ge);
      }
    }
  }
}

// ---------------- grouped GEMM2: counted-vmcnt 3-slot pipeline (T4 test) ------
// Identical tile/swizzle/XCD/K-split/epilogue to r9; ONLY the K-loop schedule
// changed: 3 LDS slots, prefetch distance 2, s_waitcnt vmcnt(4) steady state,
// raw s_barrier (1/iter), asm ds_read_b128 + lgkmcnt(0) + sched_barrier(0).
__global__ __launch_bounds__(256, 3) void gemm2_kernel(
    const unsigned short* __restrict__ hmid,
    const unsigned short* __restrict__ w2t, const float* __restrict__ b2,
    float* __restrict__ out, unsigned short* __restrict__ poA,
    unsigned short* __restrict__ poB, const int* __restrict__ pairTok,
    const float* __restrict__ pairW, const int* __restrict__ counts, int mode) {
  __shared__ char LDS[49152];  // A: 3x8KB @0, B: 3x8KB @24576
  const int bid = blockIdx.x;
  const int nchunk = (mode == 2) ? 288 : 144;
  const int lin = (bid & 7) * nchunk + (bid >> 3);
  const int kh = (mode == 2) ? (lin & 1) : 0;
  const int tx = (mode == 2) ? ((lin >> 1) & 7) : (lin & 7);
  const int ty = (mode == 2) ? (lin >> 4) : (lin >> 3);
  int tsp = 0;
  const int e = tile_map(counts, ty, &tsp);
  if (e < 0) return;
  const int n0 = tx * 128;
  const int tid = threadIdx.x, w = tid >> 6, l = tid & 63;
  const int rbase = w * 16 + (l >> 2);
  const int segp = (l & 3) ^ ((l >> 3) & 3);
  const size_t koff = (size_t)kh * 2048;
  const char* gA0 =
      (const char*)(hmid + (size_t)(tsp + rbase) * I_DIM) + segp * 16 + koff;
  const char* gA1 =
      (const char*)(hmid + (size_t)(tsp + rbase + 64) * I_DIM) + segp * 16 + koff;
  const unsigned short* wbase = w2t + (size_t)e * H_DIM * I_DIM;
  const char* gB0 =
      (const char*)(wbase + (size_t)(n0 + rbase) * I_DIM) + segp * 16 + koff;
  const char* gB1 =
      (const char*)(wbase + (size_t)(n0 + rbase + 64) * I_DIM) + segp * 16 + koff;

  f32x4 acc[4][4];
#pragma unroll
  for (int m = 0; m < 4; ++m)
#pragma unroll
    for (int n = 0; n < 4; ++n) acc[m][n] = f32x4{0.f, 0.f, 0.f, 0.f};

  const int wr = w >> 1, wc = w & 1, lrow = l & 15, g = l >> 4;
  const int gs = g ^ ((l >> 1) & 3);
  const int NK = (mode == 2) ? 32 : 64;

  char* dA = LDS + w * 1024;           // wave's A stage dest within a slot
  char* dB = LDS + 24576 + w * 1024;
  const unsigned ldsb = (unsigned)(uintptr_t)&LDS[0];
  const unsigned aRd = ldsb + (unsigned)((wr * 64 + lrow) * 64 + gs * 16);
  const unsigned bRd = ldsb + 24576u + (unsigned)((wc * 64 + lrow) * 64 + gs * 16);

  // exact vmcnt accounting: drain setup loads first
  asm volatile("s_waitcnt vmcnt(0)" ::: "memory");
  // prologue: stage tiles 0 (slot0) and 1 (slot1); 4 loads each, FIFO order
  gld16(gA0, dA);        gld16(gA1, dA + 4096);
  gld16(gB0, dB);        gld16(gB1, dB + 4096);
  gld16(gA0 + 64, dA + 8192);  gld16(gA1 + 64, dA + 8192 + 4096);
  gld16(gB0 + 64, dB + 8192);  gld16(gB1 + 64, dB + 8192 + 4096);

  int srd = 0, sst = 2;
  for (int t = 0; t < NK; ++t) {
    if (t + 1 < NK)
      asm volatile("s_waitcnt vmcnt(4)" ::: "memory");  // tile t landed
    else
      asm volatile("s_waitcnt vmcnt(0)" ::: "memory");
    asm volatile("s_barrier" ::: "memory");  // all waves' tile-t data visible
    const int tau = t + 2;
    if (tau < NK) {  // stage tile t+2 into slot (t+2)%3 (== slot of t-1, safe)
      const size_t kb = (size_t)tau * 64;
      char* da = dA + sst * 8192;
      char* db = dB + sst * 8192;
      gld16(gA0 + kb, da);  gld16(gA1 + kb, da + 4096);
      gld16(gB0 + kb, db);  gld16(gB1 + kb, db + 4096);
    }
    const unsigned so = (unsigned)(srd * 8192);
    const unsigned aS = aRd + so, bS = bRd + so;
    s16x8 av[4], bv[4];
    DSR(bv[0], bS, 0);    DSR(bv[1], bS, 1024);
    DSR(bv[2], bS, 2048); DSR(bv[3], bS, 3072);
    DSR(av[0], aS, 0);    DSR(av[1], aS, 1024);
    DSR(av[2], aS, 2048); DSR(av[3], aS, 3072);
    asm volatile("s_waitcnt lgkmcnt(0)" ::: "memory");
    __builtin_amdgcn_sched_barrier(0);  // rule 18: pin MFMA after lgkmcnt
    __builtin_amdgcn_s_setprio(1);
#pragma unroll
    for (int m = 0; m < 4; ++m)
#pragma unroll
      for (int n = 0; n < 4; ++n) mfma_bf16(av[m], bv[n], acc[m][n]);
    __builtin_amdgcn_s_setprio(0);
    srd = (srd == 2) ? 0 : srd + 1;
    sst = (sst == 2) ? 0 : sst + 1;
  }
  __builtin_amdgcn_sched_barrier(0);

  if (mode >= 1) {
    unsigned short* po = (kh == 0) ? poA : poB;
#pragma unroll
    for (int m = 0; m < 4; ++m) {
      const int rw0 = wr * 64 + m * 16 + g * 4;
#pragma unroll
      for (int n = 0; n < 4; ++n) {
        const int col = n0 + wc * 64 + n * 16 + lrow;
        f32x4 v = acc[m][n];
#pragma unroll
        for (int j = 0; j < 4; ++j)
          po[(size_t)(tsp + rw0 + j) * H_DIM + col] = f2bf(v[j]);
      }
    }
  } else {
    const float* b2e = b2 + (size_t)e * H_DIM;
#pragma unroll
    for (int m = 0; m < 4; ++m) {
      const int rw0 = wr * 64 + m * 16 + g * 4;
#pragma unroll
      for (int j = 0; j < 4; ++j) {
        const int p = tsp + rw0 + j;
        const int tok = pairTok[p];
        if (tok < 0) continue;
        const float pw = pairW[p];
        float* orow = out + (size_t)tok * H_DIM;
#pragma unroll
        for (int n = 0; n < 4; ++n) {
          const int col = n0 + wc * 64 + n * 16 + lrow;
          float val = (acc[m][n][j] + b2e[col]) * pw;
          atomicAdd(orow + col, val);
        }
      }
    }
  }
}

// ---------------- combine: out[t] = sum_k pw_k * (poA[+poB] + b2[e_k]) --------
__global__ __launch_bounds__(256) void combine_kernel(
    const unsigned short* __restrict__ poA, const unsigned short* __restrict__ poB,
    const int* __restrict__ pairPos, const int* __restrict__ topi,
    const float* __restrict__ topw, const float* __restrict__ b2,
    float* __restrict__ out, int nbuf) {
  const int t = blockIdx.x * 2 + (threadIdx.x >> 7);
  const int c0 = (threadIdx.x & 127) * 8;
  float o[8];
#pragma unroll
  for (int j = 0; j < 8; ++j) o[j] = 0.f;
#pragma unroll
  for (int k = 0; k < K_TOP; ++k) {
    const int e = topi[t * K_TOP + k];
    const float pw = topw[t * K_TOP + k];
    const int pos = pairPos[t * K_TOP + k];
    u16x8 va = *(const u16x8*)(poA + (size_t)pos * H_DIM + c0);
    u16x8 vb;
    if (nbuf == 2) vb = *(const u16x8*)(poB + (size_t)pos * H_DIM + c0);
    const float* b2r = b2 + (size_t)e * H_DIM + c0;
#pragma unroll
    for (int j = 0; j < 8; ++j) {
      float hv = __uint_as_float((unsigned)va[j] << 16);
      if (nbuf == 2) hv += __uint_as_float((unsigned)vb[j] << 16);
      o[j] += pw * (hv + b2r[j]);
    }
  }
  float* orow = out + (size_t)t * H_DIM + c0;
  *(f32x4*)orow = f32x4{o[0], o[1], o[2], o[3]};
  *(f32x4*)(orow + 4) = f32x4{o[4], o[5], o[6], o[7]};
}

// ------------------------------------------------------------------------------
extern "C" void kernel_launch(void* const* d_in, const int* in_sizes, int n_in,
                              void* d_out, int out_size, void* d_ws,
                              size_t ws_size, hipStream_t stream) {
  const float* x = (const float*)d_in[0];
  const float* rw = (const float*)d_in[1];
  const float* rb = (const float*)d_in[2];
  const float* w1 = (const float*)d_in[3];
  const float* b1 = (const float*)d_in[4];
  const float* w2 = (const float*)d_in[5];
  const float* b2 = (const float*)d_in[6];
  float* out = (float*)d_out;
  char* ws = (char*)d_ws;

  const size_t xbSz = (size_t)T_TOK * H_DIM * 2;
  const size_t poSz = (size_t)PAD_PAIRS * H_DIM * 2;
  const size_t wtSz = (size_t)E_NUM * H_DIM * I_DIM * 2;
  const size_t hmSz = (size_t)PAD_PAIRS * I_DIM * 2;
  const size_t smallSz = (size_t)T_TOK * K_TOP * 4 * 3
                         + (size_t)PAD_PAIRS * 4 * 2 + 128;
  const size_t need3 = poSz * 2 + wtSz * 2 + hmSz + smallSz;
  const size_t need2 = poSz * 2 + wtSz + hmSz + smallSz;
  const size_t need1 = poSz + wtSz + hmSz + smallSz;
  const size_t need0 = xbSz + wtSz + hmSz + smallSz;
  int mode;
  if (ws_size >= need3) mode = 3;
  else if (ws_size >= need2) mode = 2;
  else if (ws_size >= need1) mode = 1;
  else if (ws_size >= need0) mode = 0;
  else return;

  size_t off = 0;
  unsigned short* xb = (unsigned short*)(ws + off);
  unsigned short* poA = (unsigned short*)(ws + off);  // xb dead by gemm2
  off += (mode >= 1) ? poSz : xbSz;
  unsigned short* poB = (unsigned short*)(ws + off);
  if (mode >= 2) off += poSz;
  unsigned short* wT1 = (unsigned short*)(ws + off);
  off += wtSz;
  unsigned short* wT2 = wT1;
  if (mode == 3) { wT2 = (unsigned short*)(ws + off); off += wtSz; }
  unsigned short* hmid = (unsigned short*)(ws + off);
  off += hmSz;
  int* topi = (int*)(ws + off);      off += (size_t)T_TOK * K_TOP * 4;
  float* topw = (float*)(ws + off);  off += (size_t)T_TOK * K_TOP * 4;
  int* pairPos = (int*)(ws + off);   off += (size_t)T_TOK * K_TOP * 4;
  int* pairTok = (int*)(ws + off);   off += (size_t)PAD_PAIRS * 4;
  float* pairW = (float*)(ws + off); off += (size_t)PAD_PAIRS * 4;
  int* counts = (int*)(ws + off);    off += 64;
  int* cursor = (int*)(ws + off);    off += 64;

  const int gmode = (mode >= 2) ? 2 : mode;

  hipMemsetAsync(counts, 0, 128, stream);  // counts + cursor
  if (gmode == 0) hipMemsetAsync(out, 0, (size_t)T_TOK * H_DIM * 4, stream);

  router_kernel<<<T_TOK / 16, 256, 0, stream>>>(x, rw, rb, topi, topw, counts,
                                                xb);
  scatter_kernel<<<T_TOK / 256, 256, 0, stream>>>(topi, topw, counts, cursor,
                                                  pairTok, pairW, pairPos);
  if (mode == 3) {
    transpose2_kernel<<<16384, 256, 0, stream>>>(w1, w2, wT1, wT2);
    gemm1_kernel<<<16 * MAX_TILES, 256, 0, stream>>>(xb, wT1, b1, hmid, pairTok,
                                                     counts);
  } else {
    transpose_kernel<<<dim3(I_DIM / 64, H_DIM / 64, E_NUM), 256, 0, stream>>>(
        w1, wT1, H_DIM, I_DIM);
    gemm1_kernel<<<16 * MAX_TILES, 256, 0, stream>>>(xb, wT1, b1, hmid, pairTok,
                                                     counts);
    transpose_kernel<<<dim3(H_DIM / 64, I_DIM / 64, E_NUM), 256, 0, stream>>>(
        w2, wT2, I_DIM, H_DIM);
  }
  gemm2_kernel<<<(gmode == 2 ? 16 : 8) * MAX_TILES, 256, 0, stream>>>(
      hmid, wT2, b2, out, poA, poB, pairTok, pairW, counts, gmode);
  if (gmode >= 1)
    combine_kernel<<<T_TOK / 2, 256, 0, stream>>>(poA, poB, pairPos, topi, topw,
                                                  b2, out, gmode);
}

// Round 11
// 412.489 us; speedup vs baseline: 1.3949x; 1.0001x over previous
//
#include <hip/hip_runtime.h>

#define T_TOK 4096
#define H_DIM 1024
#define I_DIM 2048
#define E_NUM 16
#define K_TOP 4
#define BM 128
#define BK 32
#define MAX_TILES 144
#define PAD_PAIRS (MAX_TILES * BM)  // 18432

typedef __attribute__((ext_vector_type(8))) short s16x8;
typedef __attribute__((ext_vector_type(4))) float f32x4;
typedef __attribute__((ext_vector_type(4))) unsigned short u16x4;
typedef __attribute__((ext_vector_type(8))) unsigned short u16x8;

#define DSR(dst, addr, off) \
  asm volatile("ds_read_b128 %0, %1 offset:" #off : "=v"(dst) : "v"(addr))

__device__ __forceinline__ unsigned short f2bf(float f) {
  unsigned u = __float_as_uint(f);
  u += 0x7fffu + ((u >> 16) & 1u);  // round-to-nearest-even
  return (unsigned short)(u >> 16);
}

__device__ __forceinline__ void mfma_bf16(const s16x8& a, const s16x8& b, f32x4& c) {
  asm("v_mfma_f32_16x16x32_bf16 %0, %1, %2, %0" : "+v"(c) : "v"(a), "v"(b));
}

__device__ __forceinline__ void gld16(const void* g, void* l) {
  __builtin_amdgcn_global_load_lds(
      (const __attribute__((address_space(1))) unsigned int*)g,
      (__attribute__((address_space(3))) unsigned int*)l, 16, 0, 0);
}

__device__ __forceinline__ int tile_map(const int* counts, int ty, int* tsp) {
  int e = -1, acc = 0, base = 0;
#pragma unroll
  for (int ee = 0; ee < E_NUM; ++ee) {
    int tc = (counts[ee] + 127) >> 7;
    if (ty >= acc && ty < acc + tc) {
      e = ee;
      *tsp = base + ((ty - acc) << 7);
    }
    acc += tc;
    base += tc << 7;
  }
  return e;
}

// ---------------- transpose tile body (own 16.6KB shared) ---------------------
__device__ __forceinline__ void transpose_tile(const float* __restrict__ src,
                                               unsigned short* __restrict__ dst,
                                               int R, int C, int tx, int ty) {
  int r0 = ty * 64, c0 = tx * 64;
  __shared__ float tle[64][65];
  int rr = threadIdx.x >> 4, cc = (threadIdx.x & 15) * 4;
#pragma unroll
  for (int i = 0; i < 4; ++i) {
    f32x4 v = *(const f32x4*)(src + (size_t)(r0 + rr + 16 * i) * C + c0 + cc);
    tle[rr + 16 * i][cc + 0] = v[0];
    tle[rr + 16 * i][cc + 1] = v[1];
    tle[rr + 16 * i][cc + 2] = v[2];
    tle[rr + 16 * i][cc + 3] = v[3];
  }
  __syncthreads();
#pragma unroll
  for (int i = 0; i < 4; ++i) {
    int oc = c0 + rr + 16 * i;
    u16x4 o;
    o[0] = f2bf(tle[cc + 0][rr + 16 * i]);
    o[1] = f2bf(tle[cc + 1][rr + 16 * i]);
    o[2] = f2bf(tle[cc + 2][rr + 16 * i]);
    o[3] = f2bf(tle[cc + 3][rr + 16 * i]);
    *(u16x4*)(dst + (size_t)oc * R + r0 + cc) = o;
  }
}

// ---------------- router device body (no LDS: rw read direct, L1-resident) ----
__device__ __forceinline__ void router_body(
    int rbid, const float* __restrict__ x, const float* __restrict__ rw,
    const float* __restrict__ rb, int* __restrict__ topi,
    float* __restrict__ topw, int* __restrict__ counts,
    unsigned short* __restrict__ xb) {
  const int tid = threadIdx.x;
  {  // fused x -> bf16 for this block's 16 token rows
    const size_t base = (size_t)rbid * 16 * H_DIM;
#pragma unroll
    for (int it = 0; it < 8; ++it) {
      size_t idx = base + ((size_t)(it * 256 + tid)) * 8;
      f32x4 a = *(const f32x4*)(x + idx);
      f32x4 b = *(const f32x4*)(x + idx + 4);
      u16x8 o;
      o[0] = f2bf(a[0]); o[1] = f2bf(a[1]); o[2] = f2bf(a[2]); o[3] = f2bf(a[3]);
      o[4] = f2bf(b[0]); o[5] = f2bf(b[1]); o[6] = f2bf(b[2]); o[7] = f2bf(b[3]);
      *(u16x8*)(xb + idx) = o;
    }
  }
  const int w = tid >> 6, l = tid & 63;
  const int e = l & 15, q = l >> 4;
  const float rbe = rb[e];
  const float* rq = rw + ((size_t)q * 256) * E_NUM + e;  // lane's expert column
#pragma unroll
  for (int i = 0; i < 4; ++i) {
    const int t = rbid * 16 + w * 4 + i;
    const float* xr = x + (size_t)t * H_DIM + (q << 8);
    float acc = 0.f;
#pragma unroll 8
    for (int hh = 0; hh < 256; hh += 4) {
      f32x4 xv = *(const f32x4*)(xr + hh);
      acc += xv[0] * rq[(hh + 0) * 16];
      acc += xv[1] * rq[(hh + 1) * 16];
      acc += xv[2] * rq[(hh + 2) * 16];
      acc += xv[3] * rq[(hh + 3) * 16];
    }
    acc += __shfl_xor(acc, 16);
    acc += __shfl_xor(acc, 32);
    float logit = acc + rbe;
    float m = logit;
    m = fmaxf(m, __shfl_xor(m, 1));
    m = fmaxf(m, __shfl_xor(m, 2));
    m = fmaxf(m, __shfl_xor(m, 4));
    m = fmaxf(m, __shfl_xor(m, 8));
    float ex = expf(logit - m);
    int rank = 0;
    const int b16 = l & 48;
#pragma unroll
    for (int j = 0; j < 16; ++j) {
      float vj = __shfl(ex, b16 + j);
      rank += (vj > ex) || (vj == ex && j < e);
    }
    float sel = (rank < K_TOP) ? ex : 0.f;
    float subs = sel;
    subs += __shfl_xor(subs, 1);
    subs += __shfl_xor(subs, 2);
    subs += __shfl_xor(subs, 4);
    subs += __shfl_xor(subs, 8);
    if (q == 0 && rank < K_TOP) {
      topi[t * K_TOP + rank] = e;
      topw[t * K_TOP + rank] = ex / subs;
      atomicAdd(&counts[e], 1);
    }
  }
}

// ---------------- fused1: transpose(w1) [0,8192) || router [8192,8448) --------
__global__ __launch_bounds__(256) void fused1_kernel(
    const float* __restrict__ x, const float* __restrict__ rw,
    const float* __restrict__ rb, int* __restrict__ topi,
    float* __restrict__ topw, int* __restrict__ counts,
    unsigned short* __restrict__ xb, const float* __restrict__ w1,
    unsigned short* __restrict__ wT1) {
  const int bid = blockIdx.x;
  if (bid < 8192) {
    const size_t es = (size_t)H_DIM * I_DIM;
    const int e = bid >> 9, tb = bid & 511;
    transpose_tile(w1 + es * e, wT1 + es * e, H_DIM, I_DIM, tb & 31, tb >> 5);
  } else {
    router_body(bid - 8192, x, rw, rb, topi, topw, counts, xb);
  }
}

// legacy standalone transpose (fallback path)
__global__ __launch_bounds__(256) void transpose_kernel(
    const float* __restrict__ src, unsigned short* __restrict__ dst, int R,
    int C) {
  size_t es = (size_t)R * C;
  transpose_tile(src + es * blockIdx.z, dst + es * blockIdx.z, R, C,
                 blockIdx.x, blockIdx.y);
}

// ---------------- scatter + padding clear -------------------------------------
__global__ __launch_bounds__(256) void scatter_kernel(
    const int* __restrict__ topi, const float* __restrict__ topw,
    const int* __restrict__ counts, int* __restrict__ cursor,
    int* __restrict__ pairTok, float* __restrict__ pairW,
    int* __restrict__ pairPos) {
  int padBase[E_NUM];
  int base = 0;
#pragma unroll
  for (int ee = 0; ee < E_NUM; ++ee) {
    padBase[ee] = base;
    base += ((counts[ee] + 127) >> 7) << 7;
  }
  const int t = blockIdx.x * 256 + threadIdx.x;
#pragma unroll
  for (int k = 0; k < K_TOP; ++k) {
    int e = topi[t * K_TOP + k];
    int pos = atomicAdd(&cursor[e], 1);
    int idx = padBase[e] + pos;
    pairTok[idx] = t;
    pairW[idx] = topw[t * K_TOP + k];
    pairPos[t * K_TOP + k] = idx;
  }
#pragma unroll
  for (int ee = 0; ee < E_NUM; ++ee) {
    int c = counts[ee];
    int padded = ((c + 127) >> 7) << 7;
    int o = c + t;
    if (o < padded) pairTok[padBase[ee] + o] = -1;  // disjoint: race-free
  }
}

// ---------------- gemm1 device body (r9 2-phase, unchanged logic) -------------
__device__ __forceinline__ void gemm1_body(
    int bid, const unsigned short* __restrict__ xb,
    const unsigned short* __restrict__ w1t, const float* __restrict__ b1,
    unsigned short* __restrict__ hmid, const int* __restrict__ pairTok,
    const int* __restrict__ counts) {
  const int lin = (bid & 7) * 288 + (bid >> 3);  // XCD chunk (2304 blocks)
  const int tx = lin & 15, ty = lin >> 4;
  int tsp = 0;
  const int e = tile_map(counts, ty, &tsp);
  if (e < 0) return;
  const int n0 = tx * 128;
  __shared__ unsigned short As[2][BM * BK];
  __shared__ unsigned short Bs[2][BM * BK];
  const int tid = threadIdx.x, w = tid >> 6, l = tid & 63;
  const int rbase = w * 16 + (l >> 2);
  const int segp = (l & 3) ^ ((l >> 3) & 3);
  int tok0 = pairTok[tsp + rbase];
  if (tok0 < 0) tok0 = 0;
  int tok1 = pairTok[tsp + rbase + 64];
  if (tok1 < 0) tok1 = 0;
  const char* gA0 = (const char*)(xb + (size_t)tok0 * H_DIM) + segp * 16;
  const char* gA1 = (const char*)(xb + (size_t)tok1 * H_DIM) + segp * 16;
  const unsigned short* wbase = w1t + (size_t)e * I_DIM * H_DIM;
  const char* gB0 = (const char*)(wbase + (size_t)(n0 + rbase) * H_DIM) + segp * 16;
  const char* gB1 = (const char*)(wbase + (size_t)(n0 + rbase + 64) * H_DIM) + segp * 16;

  f32x4 acc[4][4];
#pragma unroll
  for (int m = 0; m < 4; ++m)
#pragma unroll
    for (int n = 0; n < 4; ++n) acc[m][n] = f32x4{0.f, 0.f, 0.f, 0.f};

  const int wr = w >> 1, wc = w & 1, lrow = l & 15, g = l >> 4;
  const int gs = g ^ ((l >> 1) & 3);
  const int NK = H_DIM / BK;  // 32

  gld16(gA0, &As[0][w * 512]);
  gld16(gA1, &As[0][2048 + w * 512]);
  gld16(gB0, &Bs[0][w * 512]);
  gld16(gB1, &Bs[0][2048 + w * 512]);

  for (int kt = 0; kt < NK; ++kt) {
    __syncthreads();
    if (kt + 1 < NK) {
      const int kb = (kt + 1) * 64;
      const int nb = (kt + 1) & 1;
      gld16(gA0 + kb, &As[nb][w * 512]);
      gld16(gA1 + kb, &As[nb][2048 + w * 512]);
      gld16(gB0 + kb, &Bs[nb][w * 512]);
      gld16(gB1 + kb, &Bs[nb][2048 + w * 512]);
    }
    const int cb = kt & 1;
    const s16x8* Ap = (const s16x8*)As[cb];
    const s16x8* Bp = (const s16x8*)Bs[cb];
    s16x8 av[4], bv[4];
#pragma unroll
    for (int m = 0; m < 4; ++m) av[m] = Ap[(wr * 64 + m * 16 + lrow) * 4 + gs];
#pragma unroll
    for (int n = 0; n < 4; ++n) bv[n] = Bp[(wc * 64 + n * 16 + lrow) * 4 + gs];
#pragma unroll
    for (int m = 0; m < 4; ++m)
#pragma unroll
      for (int n = 0; n < 4; ++n) mfma_bf16(av[m], bv[n], acc[m][n]);
  }

  const float* b1e = b1 + (size_t)e * I_DIM;
#pragma unroll
  for (int m = 0; m < 4; ++m) {
    const int rw0 = wr * 64 + m * 16 + g * 4;
#pragma unroll
    for (int n = 0; n < 4; ++n) {
      const int col = n0 + wc * 64 + n * 16 + lrow;
      const float bb = b1e[col];
      f32x4 v = acc[m][n];
#pragma unroll
      for (int j = 0; j < 4; ++j) {
        const int p = tsp + rw0 + j;
        float xv = v[j] + bb;
        float y = 0.7978845608028654f * (xv + 0.044715f * xv * xv * xv);
        float ey = __expf(2.f * y);
        float th = 1.f - 2.f / (ey + 1.f);
        float ge = 0.5f * xv * (1.f + th);
        hmid[(size_t)p * I_DIM + col] = f2bf(ge);
      }
    }
  }
}

// standalone gemm1 (fallback when no dual-wT buffer)
__global__ __launch_bounds__(256, 4) void gemm1_kernel(
    const unsigned short* __restrict__ xb, const unsigned short* __restrict__ w1t,
    const float* __restrict__ b1, unsigned short* __restrict__ hmid,
    const int* __restrict__ pairTok, const int* __restrict__ counts) {
  gemm1_body(blockIdx.x, xb, w1t, b1, hmid, pairTok, counts);
}

// ---------------- fused2: gemm1 [0,2304) || transpose(w2) [2304,10496) --------
__global__ __launch_bounds__(256, 3) void fused2_kernel(
    const unsigned short* __restrict__ xb, const unsigned short* __restrict__ w1t,
    const float* __restrict__ b1, unsigned short* __restrict__ hmid,
    const int* __restrict__ pairTok, const int* __restrict__ counts,
    const float* __restrict__ w2, unsigned short* __restrict__ wT2) {
  const int bid = blockIdx.x;
  if (bid < 2304) {
    gemm1_body(bid, xb, w1t, b1, hmid, pairTok, counts);
  } else {
    const int tbid = bid - 2304;
    const size_t es = (size_t)H_DIM * I_DIM;
    const int e = tbid >> 9, tb = tbid & 511;
    transpose_tile(w2 + es * e, wT2 + es * e, I_DIM, H_DIM, tb & 15, tb >> 4);
  }
}

// ---------------- grouped GEMM2: r10 counted-vmcnt 3-slot pipeline ------------
__global__ __launch_bounds__(256, 3) void gemm2_kernel(
    const unsigned short* __restrict__ hmid,
    const unsigned short* __restrict__ w2t, const float* __restrict__ b2,
    float* __restrict__ out, unsigned short* __restrict__ poA,
    unsigned short* __restrict__ poB, const int* __restrict__ pairTok,
    const float* __restrict__ pairW, const int* __restrict__ counts, int mode) {
  __shared__ char LDS[49152];  // A: 3x8KB @0, B: 3x8KB @24576
  const int bid = blockIdx.x;
  const int nchunk = (mode == 2) ? 288 : 144;
  const int lin = (bid & 7) * nchunk + (bid >> 3);
  const int kh = (mode == 2) ? (lin & 1) : 0;
  const int tx = (mode == 2) ? ((lin >> 1) & 7) : (lin & 7);
  const int ty = (mode == 2) ? (lin >> 4) : (lin >> 3);
  int tsp = 0;
  const int e = tile_map(counts, ty, &tsp);
  if (e < 0) return;
  const int n0 = tx * 128;
  const int tid = threadIdx.x, w = tid >> 6, l = tid & 63;
  const int rbase = w * 16 + (l >> 2);
  const int segp = (l & 3) ^ ((l >> 3) & 3);
  const size_t koff = (size_t)kh * 2048;
  const char* gA0 =
      (const char*)(hmid + (size_t)(tsp + rbase) * I_DIM) + segp * 16 + koff;
  const char* gA1 =
      (const char*)(hmid + (size_t)(tsp + rbase + 64) * I_DIM) + segp * 16 + koff;
  const unsigned short* wbase = w2t + (size_t)e * H_DIM * I_DIM;
  const char* gB0 =
      (const char*)(wbase + (size_t)(n0 + rbase) * I_DIM) + segp * 16 + koff;
  const char* gB1 =
      (const char*)(wbase + (size_t)(n0 + rbase + 64) * I_DIM) + segp * 16 + koff;

  f32x4 acc[4][4];
#pragma unroll
  for (int m = 0; m < 4; ++m)
#pragma unroll
    for (int n = 0; n < 4; ++n) acc[m][n] = f32x4{0.f, 0.f, 0.f, 0.f};

  const int wr = w >> 1, wc = w & 1, lrow = l & 15, g = l >> 4;
  const int gs = g ^ ((l >> 1) & 3);
  const int NK = (mode == 2) ? 32 : 64;

  char* dA = LDS + w * 1024;
  char* dB = LDS + 24576 + w * 1024;
  const unsigned ldsb = (unsigned)(uintptr_t)&LDS[0];
  const unsigned aRd = ldsb + (unsigned)((wr * 64 + lrow) * 64 + gs * 16);
  const unsigned bRd = ldsb + 24576u + (unsigned)((wc * 64 + lrow) * 64 + gs * 16);

  asm volatile("s_waitcnt vmcnt(0)" ::: "memory");
  gld16(gA0, dA);        gld16(gA1, dA + 4096);
  gld16(gB0, dB);        gld16(gB1, dB + 4096);
  gld16(gA0 + 64, dA + 8192);  gld16(gA1 + 64, dA + 8192 + 4096);
  gld16(gB0 + 64, dB + 8192);  gld16(gB1 + 64, dB + 8192 + 4096);

  int srd = 0, sst = 2;
  for (int t = 0; t < NK; ++t) {
    if (t + 1 < NK)
      asm volatile("s_waitcnt vmcnt(4)" ::: "memory");
    else
      asm volatile("s_waitcnt vmcnt(0)" ::: "memory");
    asm volatile("s_barrier" ::: "memory");
    const int tau = t + 2;
    if (tau < NK) {
      const size_t kb = (size_t)tau * 64;
      char* da = dA + sst * 8192;
      char* db = dB + sst * 8192;
      gld16(gA0 + kb, da);  gld16(gA1 + kb, da + 4096);
      gld16(gB0 + kb, db);  gld16(gB1 + kb, db + 4096);
    }
    const unsigned so = (unsigned)(srd * 8192);
    const unsigned aS = aRd + so, bS = bRd + so;
    s16x8 av[4], bv[4];
    DSR(bv[0], bS, 0);    DSR(bv[1], bS, 1024);
    DSR(bv[2], bS, 2048); DSR(bv[3], bS, 3072);
    DSR(av[0], aS, 0);    DSR(av[1], aS, 1024);
    DSR(av[2], aS, 2048); DSR(av[3], aS, 3072);
    asm volatile("s_waitcnt lgkmcnt(0)" ::: "memory");
    __builtin_amdgcn_sched_barrier(0);
    __builtin_amdgcn_s_setprio(1);
#pragma unroll
    for (int m = 0; m < 4; ++m)
#pragma unroll
      for (int n = 0; n < 4; ++n) mfma_bf16(av[m], bv[n], acc[m][n]);
    __builtin_amdgcn_s_setprio(0);
    srd = (srd == 2) ? 0 : srd + 1;
    sst = (sst == 2) ? 0 : sst + 1;
  }
  __builtin_amdgcn_sched_barrier(0);

  if (mode >= 1) {
    unsigned short* po = (kh == 0) ? poA : poB;
#pragma unroll
    for (int m = 0; m < 4; ++m) {
      const int rw0 = wr * 64 + m * 16 + g * 4;
#pragma unroll
      for (int n = 0; n < 4; ++n) {
        const int col = n0 + wc * 64 + n * 16 + lrow;
        f32x4 v = acc[m][n];
#pragma unroll
        for (int j = 0; j < 4; ++j)
          po[(size_t)(tsp + rw0 + j) * H_DIM + col] = f2bf(v[j]);
      }
    }
  } else {
    const float* b2e = b2 + (size_t)e * H_DIM;
#pragma unroll
    for (int m = 0; m < 4; ++m) {
      const int rw0 = wr * 64 + m * 16 + g * 4;
#pragma unroll
      for (int j = 0; j < 4; ++j) {
        const int p = tsp + rw0 + j;
        const int tok = pairTok[p];
        if (tok < 0) continue;
        const float pw = pairW[p];
        float* orow = out + (size_t)tok * H_DIM;
#pragma unroll
        for (int n = 0; n < 4; ++n) {
          const int col = n0 + wc * 64 + n * 16 + lrow;
          float val = (acc[m][n][j] + b2e[col]) * pw;
          atomicAdd(orow + col, val);
        }
      }
    }
  }
}

// ---------------- combine: out[t] = sum_k pw_k * (poA[+poB] + b2[e_k]) --------
__global__ __launch_bounds__(256) void combine_kernel(
    const unsigned short* __restrict__ poA, const unsigned short* __restrict__ poB,
    const int* __restrict__ pairPos, const int* __restrict__ topi,
    const float* __restrict__ topw, const float* __restrict__ b2,
    float* __restrict__ out, int nbuf) {
  const int t = blockIdx.x * 2 + (threadIdx.x >> 7);
  const int c0 = (threadIdx.x & 127) * 8;
  float o[8];
#pragma unroll
  for (int j = 0; j < 8; ++j) o[j] = 0.f;
#pragma unroll
  for (int k = 0; k < K_TOP; ++k) {
    const int e = topi[t * K_TOP + k];
    const float pw = topw[t * K_TOP + k];
    const int pos = pairPos[t * K_TOP + k];
    u16x8 va = *(const u16x8*)(poA + (size_t)pos * H_DIM + c0);
    u16x8 vb;
    if (nbuf == 2) vb = *(const u16x8*)(poB + (size_t)pos * H_DIM + c0);
    const float* b2r = b2 + (size_t)e * H_DIM + c0;
#pragma unroll
    for (int j = 0; j < 8; ++j) {
      float hv = __uint_as_float((unsigned)va[j] << 16);
      if (nbuf == 2) hv += __uint_as_float((unsigned)vb[j] << 16);
      o[j] += pw * (hv + b2r[j]);
    }
  }
  float* orow = out + (size_t)t * H_DIM + c0;
  *(f32x4*)orow = f32x4{o[0], o[1], o[2], o[3]};
  *(f32x4*)(orow + 4) = f32x4{o[4], o[5], o[6], o[7]};
}

// ------------------------------------------------------------------------------
extern "C" void kernel_launch(void* const* d_in, const int* in_sizes, int n_in,
                              void* d_out, int out_size, void* d_ws,
                              size_t ws_size, hipStream_t stream) {
  const float* x = (const float*)d_in[0];
  const float* rw = (const float*)d_in[1];
  const float* rb = (const float*)d_in[2];
  const float* w1 = (const float*)d_in[3];
  const float* b1 = (const float*)d_in[4];
  const float* w2 = (const float*)d_in[5];
  const float* b2 = (const float*)d_in[6];
  float* out = (float*)d_out;
  char* ws = (char*)d_ws;

  const size_t xbSz = (size_t)T_TOK * H_DIM * 2;          // 8.39 MB
  const size_t poSz = (size_t)PAD_PAIRS * H_DIM * 2;      // 37.75 MB
  const size_t wtSz = (size_t)E_NUM * H_DIM * I_DIM * 2;  // 67.11 MB
  const size_t hmSz = (size_t)PAD_PAIRS * I_DIM * 2;      // 75.50 MB
  const size_t smallSz = (size_t)T_TOK * K_TOP * 4 * 3
                         + (size_t)PAD_PAIRS * 4 * 2 + 128;
  // Tier priority: dual-wT (enables gemm1||tr_w2 fusion) > K-split > pairOut.
  const size_t needDualSplit = 2 * poSz + 2 * wtSz + hmSz + smallSz;  // 285.6MB
  const size_t needDual      = poSz + 2 * wtSz + hmSz + smallSz;      // 247.8MB
  const size_t needSplit     = 2 * poSz + wtSz + hmSz + smallSz;      // 218.4MB
  const size_t needPo        = poSz + wtSz + hmSz + smallSz;          // 180.7MB
  const size_t needMin       = xbSz + wtSz + hmSz + smallSz;          // 151.3MB
  int dual = 0, split = 0, po = 0;
  if (ws_size >= needDualSplit) { dual = 1; split = 1; po = 1; }
  else if (ws_size >= needDual) { dual = 1; po = 1; }
  else if (ws_size >= needSplit) { split = 1; po = 1; }
  else if (ws_size >= needPo) { po = 1; }
  else if (ws_size < needMin) return;  // diagnostic: output stays 0

  size_t off = 0;
  unsigned short* xb = (unsigned short*)(ws + off);
  unsigned short* poA = (unsigned short*)(ws + off);  // xb dead by gemm2
  off += po ? poSz : xbSz;
  unsigned short* poB = (unsigned short*)(ws + off);
  if (split) off += poSz;
  unsigned short* wT1 = (unsigned short*)(ws + off);
  off += wtSz;
  unsigned short* wT2 = wT1;
  if (dual) { wT2 = (unsigned short*)(ws + off); off += wtSz; }
  unsigned short* hmid = (unsigned short*)(ws + off);
  off += hmSz;
  int* topi = (int*)(ws + off);      off += (size_t)T_TOK * K_TOP * 4;
  float* topw = (float*)(ws + off);  off += (size_t)T_TOK * K_TOP * 4;
  int* pairPos = (int*)(ws + off);   off += (size_t)T_TOK * K_TOP * 4;
  int* pairTok = (int*)(ws + off);   off += (size_t)PAD_PAIRS * 4;
  float* pairW = (float*)(ws + off); off += (size_t)PAD_PAIRS * 4;
  int* counts = (int*)(ws + off);    off += 64;
  int* cursor = (int*)(ws + off);    off += 64;

  const int gmode = split ? 2 : (po ? 1 : 0);

  hipMemsetAsync(counts, 0, 128, stream);  // counts + cursor
  if (gmode == 0) hipMemsetAsync(out, 0, (size_t)T_TOK * H_DIM * 4, stream);

  // stage 1: transpose(w1) || router (+x->bf16) in one launch
  fused1_kernel<<<8192 + 256, 256, 0, stream>>>(x, rw, rb, topi, topw, counts,
                                                xb, w1, wT1);
  scatter_kernel<<<T_TOK / 256, 256, 0, stream>>>(topi, topw, counts, cursor,
                                                  pairTok, pairW, pairPos);
  // stage 2: gemm1 || transpose(w2) when dual buffers available
  if (dual) {
    fused2_kernel<<<2304 + 8192, 256, 0, stream>>>(xb, wT1, b1, hmid, pairTok,
                                                   counts, w2, wT2);
  } else {
    gemm1_kernel<<<16 * MAX_TILES, 256, 0, stream>>>(xb, wT1, b1, hmid, pairTok,
                                                     counts);
    transpose_kernel<<<dim3(H_DIM / 64, I_DIM / 64, E_NUM), 256, 0, stream>>>(
        w2, wT2, I_DIM, H_DIM);
  }
  gemm2_kernel<<<(gmode == 2 ? 16 : 8) * MAX_TILES, 256, 0, stream>>>(
      hmid, wT2, b2, out, poA, poB, pairTok, pairW, counts, gmode);
  if (gmode >= 1)
    combine_kernel<<<T_TOK / 2, 256, 0, stream>>>(poA, poB, pairPos, topi, topw,
                                                  b2, out, gmode);
}

// Round 12
// 377.760 us; speedup vs baseline: 1.5231x; 1.0919x over previous
//
#include <hip/hip_runtime.h>

#define T_TOK 4096
#define H_DIM 1024
#define I_DIM 2048
#define E_NUM 16
#define K_TOP 4
#define BM 128
#define BK 32
#define MAX_TILES 144
#define PAD_PAIRS (MAX_TILES * BM)  // 18432

typedef __attribute__((ext_vector_type(8))) short s16x8;
typedef __attribute__((ext_vector_type(4))) float f32x4;
typedef __attribute__((ext_vector_type(4))) unsigned short u16x4;
typedef __attribute__((ext_vector_type(8))) unsigned short u16x8;

#define DSR(dst, addr, off) \
  asm volatile("ds_read_b128 %0, %1 offset:" #off : "=v"(dst) : "v"(addr))

__device__ __forceinline__ unsigned short f2bf(float f) {
  unsigned u = __float_as_uint(f);
  u += 0x7fffu + ((u >> 16) & 1u);  // round-to-nearest-even
  return (unsigned short)(u >> 16);
}

__device__ __forceinline__ void mfma_bf16(const s16x8& a, const s16x8& b, f32x4& c) {
  asm("v_mfma_f32_16x16x32_bf16 %0, %1, %2, %0" : "+v"(c) : "v"(a), "v"(b));
}

__device__ __forceinline__ void gld16(const void* g, void* l) {
  __builtin_amdgcn_global_load_lds(
      (const __attribute__((address_space(1))) unsigned int*)g,
      (__attribute__((address_space(3))) unsigned int*)l, 16, 0, 0);
}

__device__ __forceinline__ int tile_map(const int* counts, int ty, int* tsp) {
  int e = -1, acc = 0, base = 0;
#pragma unroll
  for (int ee = 0; ee < E_NUM; ++ee) {
    int tc = (counts[ee] + 127) >> 7;
    if (ty >= acc && ty < acc + tc) {
      e = ee;
      *tsp = base + ((ty - acc) << 7);
    }
    acc += tc;
    base += tc << 7;
  }
  return e;
}

// ---------------- transpose tile body (own 16.6KB shared) ---------------------
__device__ __forceinline__ void transpose_tile(const float* __restrict__ src,
                                               unsigned short* __restrict__ dst,
                                               int R, int C, int tx, int ty) {
  int r0 = ty * 64, c0 = tx * 64;
  __shared__ float tle[64][65];
  int rr = threadIdx.x >> 4, cc = (threadIdx.x & 15) * 4;
#pragma unroll
  for (int i = 0; i < 4; ++i) {
    f32x4 v = *(const f32x4*)(src + (size_t)(r0 + rr + 16 * i) * C + c0 + cc);
    tle[rr + 16 * i][cc + 0] = v[0];
    tle[rr + 16 * i][cc + 1] = v[1];
    tle[rr + 16 * i][cc + 2] = v[2];
    tle[rr + 16 * i][cc + 3] = v[3];
  }
  __syncthreads();
#pragma unroll
  for (int i = 0; i < 4; ++i) {
    int oc = c0 + rr + 16 * i;
    u16x4 o;
    o[0] = f2bf(tle[cc + 0][rr + 16 * i]);
    o[1] = f2bf(tle[cc + 1][rr + 16 * i]);
    o[2] = f2bf(tle[cc + 2][rr + 16 * i]);
    o[3] = f2bf(tle[cc + 3][rr + 16 * i]);
    *(u16x4*)(dst + (size_t)oc * R + r0 + cc) = o;
  }
}

// ---------------- router device body (no LDS: rw read direct, L1-resident) ----
__device__ __forceinline__ void router_body(
    int rbid, const float* __restrict__ x, const float* __restrict__ rw,
    const float* __restrict__ rb, int* __restrict__ topi,
    float* __restrict__ topw, int* __restrict__ counts,
    unsigned short* __restrict__ xb) {
  const int tid = threadIdx.x;
  {  // fused x -> bf16 for this block's 16 token rows
    const size_t base = (size_t)rbid * 16 * H_DIM;
#pragma unroll
    for (int it = 0; it < 8; ++it) {
      size_t idx = base + ((size_t)(it * 256 + tid)) * 8;
      f32x4 a = *(const f32x4*)(x + idx);
      f32x4 b = *(const f32x4*)(x + idx + 4);
      u16x8 o;
      o[0] = f2bf(a[0]); o[1] = f2bf(a[1]); o[2] = f2bf(a[2]); o[3] = f2bf(a[3]);
      o[4] = f2bf(b[0]); o[5] = f2bf(b[1]); o[6] = f2bf(b[2]); o[7] = f2bf(b[3]);
      *(u16x8*)(xb + idx) = o;
    }
  }
  const int w = tid >> 6, l = tid & 63;
  const int e = l & 15, q = l >> 4;
  const float rbe = rb[e];
  const float* rq = rw + ((size_t)q * 256) * E_NUM + e;  // lane's expert column
#pragma unroll
  for (int i = 0; i < 4; ++i) {
    const int t = rbid * 16 + w * 4 + i;
    const float* xr = x + (size_t)t * H_DIM + (q << 8);
    float acc = 0.f;
#pragma unroll 8
    for (int hh = 0; hh < 256; hh += 4) {
      f32x4 xv = *(const f32x4*)(xr + hh);
      acc += xv[0] * rq[(hh + 0) * 16];
      acc += xv[1] * rq[(hh + 1) * 16];
      acc += xv[2] * rq[(hh + 2) * 16];
      acc += xv[3] * rq[(hh + 3) * 16];
    }
    acc += __shfl_xor(acc, 16);
    acc += __shfl_xor(acc, 32);
    float logit = acc + rbe;
    float m = logit;
    m = fmaxf(m, __shfl_xor(m, 1));
    m = fmaxf(m, __shfl_xor(m, 2));
    m = fmaxf(m, __shfl_xor(m, 4));
    m = fmaxf(m, __shfl_xor(m, 8));
    float ex = expf(logit - m);
    int rank = 0;
    const int b16 = l & 48;
#pragma unroll
    for (int j = 0; j < 16; ++j) {
      float vj = __shfl(ex, b16 + j);
      rank += (vj > ex) || (vj == ex && j < e);
    }
    float sel = (rank < K_TOP) ? ex : 0.f;
    float subs = sel;
    subs += __shfl_xor(subs, 1);
    subs += __shfl_xor(subs, 2);
    subs += __shfl_xor(subs, 4);
    subs += __shfl_xor(subs, 8);
    if (q == 0 && rank < K_TOP) {
      topi[t * K_TOP + rank] = e;
      topw[t * K_TOP + rank] = ex / subs;
      atomicAdd(&counts[e], 1);
    }
  }
}

// -------- fused1: router FIRST [0,256) || transpose(w1) [256,8448) ------------
// Router blocks dispatch first so their ~25us hides under the BW-bound
// transpose instead of trailing it (r11 had router last -> serialized tail).
__global__ __launch_bounds__(256) void fused1_kernel(
    const float* __restrict__ x, const float* __restrict__ rw,
    const float* __restrict__ rb, int* __restrict__ topi,
    float* __restrict__ topw, int* __restrict__ counts,
    unsigned short* __restrict__ xb, const float* __restrict__ w1,
    unsigned short* __restrict__ wT1) {
  const int bid = blockIdx.x;
  if (bid < 256) {
    router_body(bid, x, rw, rb, topi, topw, counts, xb);
  } else {
    const int tbid = bid - 256;
    const size_t es = (size_t)H_DIM * I_DIM;
    const int e = tbid >> 9, tb = tbid & 511;
    transpose_tile(w1 + es * e, wT1 + es * e, H_DIM, I_DIM, tb & 31, tb >> 5);
  }
}

// legacy standalone transpose (fallback path)
__global__ __launch_bounds__(256) void transpose_kernel(
    const float* __restrict__ src, unsigned short* __restrict__ dst, int R,
    int C) {
  size_t es = (size_t)R * C;
  transpose_tile(src + es * blockIdx.z, dst + es * blockIdx.z, R, C,
                 blockIdx.x, blockIdx.y);
}

// ---------------- scatter + padding clear -------------------------------------
__global__ __launch_bounds__(256) void scatter_kernel(
    const int* __restrict__ topi, const float* __restrict__ topw,
    const int* __restrict__ counts, int* __restrict__ cursor,
    int* __restrict__ pairTok, float* __restrict__ pairW,
    int* __restrict__ pairPos) {
  int padBase[E_NUM];
  int base = 0;
#pragma unroll
  for (int ee = 0; ee < E_NUM; ++ee) {
    padBase[ee] = base;
    base += ((counts[ee] + 127) >> 7) << 7;
  }
  const int t = blockIdx.x * 256 + threadIdx.x;
#pragma unroll
  for (int k = 0; k < K_TOP; ++k) {
    int e = topi[t * K_TOP + k];
    int pos = atomicAdd(&cursor[e], 1);
    int idx = padBase[e] + pos;
    pairTok[idx] = t;
    pairW[idx] = topw[t * K_TOP + k];
    pairPos[t * K_TOP + k] = idx;
  }
#pragma unroll
  for (int ee = 0; ee < E_NUM; ++ee) {
    int c = counts[ee];
    int padded = ((c + 127) >> 7) << 7;
    int o = c + t;
    if (o < padded) pairTok[padBase[ee] + o] = -1;  // disjoint: race-free
  }
}

// ---------------- gemm1 device body (r9 2-phase, unchanged logic) -------------
__device__ __forceinline__ void gemm1_body(
    int bid, const unsigned short* __restrict__ xb,
    const unsigned short* __restrict__ w1t, const float* __restrict__ b1,
    unsigned short* __restrict__ hmid, const int* __restrict__ pairTok,
    const int* __restrict__ counts) {
  const int lin = (bid & 7) * 288 + (bid >> 3);  // XCD chunk (2304 blocks)
  const int tx = lin & 15, ty = lin >> 4;
  int tsp = 0;
  const int e = tile_map(counts, ty, &tsp);
  if (e < 0) return;
  const int n0 = tx * 128;
  __shared__ unsigned short As[2][BM * BK];
  __shared__ unsigned short Bs[2][BM * BK];
  const int tid = threadIdx.x, w = tid >> 6, l = tid & 63;
  const int rbase = w * 16 + (l >> 2);
  const int segp = (l & 3) ^ ((l >> 3) & 3);
  int tok0 = pairTok[tsp + rbase];
  if (tok0 < 0) tok0 = 0;
  int tok1 = pairTok[tsp + rbase + 64];
  if (tok1 < 0) tok1 = 0;
  const char* gA0 = (const char*)(xb + (size_t)tok0 * H_DIM) + segp * 16;
  const char* gA1 = (const char*)(xb + (size_t)tok1 * H_DIM) + segp * 16;
  const unsigned short* wbase = w1t + (size_t)e * I_DIM * H_DIM;
  const char* gB0 = (const char*)(wbase + (size_t)(n0 + rbase) * H_DIM) + segp * 16;
  const char* gB1 = (const char*)(wbase + (size_t)(n0 + rbase + 64) * H_DIM) + segp * 16;

  f32x4 acc[4][4];
#pragma unroll
  for (int m = 0; m < 4; ++m)
#pragma unroll
    for (int n = 0; n < 4; ++n) acc[m][n] = f32x4{0.f, 0.f, 0.f, 0.f};

  const int wr = w >> 1, wc = w & 1, lrow = l & 15, g = l >> 4;
  const int gs = g ^ ((l >> 1) & 3);
  const int NK = H_DIM / BK;  // 32

  gld16(gA0, &As[0][w * 512]);
  gld16(gA1, &As[0][2048 + w * 512]);
  gld16(gB0, &Bs[0][w * 512]);
  gld16(gB1, &Bs[0][2048 + w * 512]);

  for (int kt = 0; kt < NK; ++kt) {
    __syncthreads();
    if (kt + 1 < NK) {
      const int kb = (kt + 1) * 64;
      const int nb = (kt + 1) & 1;
      gld16(gA0 + kb, &As[nb][w * 512]);
      gld16(gA1 + kb, &As[nb][2048 + w * 512]);
      gld16(gB0 + kb, &Bs[nb][w * 512]);
      gld16(gB1 + kb, &Bs[nb][2048 + w * 512]);
    }
    const int cb = kt & 1;
    const s16x8* Ap = (const s16x8*)As[cb];
    const s16x8* Bp = (const s16x8*)Bs[cb];
    s16x8 av[4], bv[4];
#pragma unroll
    for (int m = 0; m < 4; ++m) av[m] = Ap[(wr * 64 + m * 16 + lrow) * 4 + gs];
#pragma unroll
    for (int n = 0; n < 4; ++n) bv[n] = Bp[(wc * 64 + n * 16 + lrow) * 4 + gs];
#pragma unroll
    for (int m = 0; m < 4; ++m)
#pragma unroll
      for (int n = 0; n < 4; ++n) mfma_bf16(av[m], bv[n], acc[m][n]);
  }

  const float* b1e = b1 + (size_t)e * I_DIM;
#pragma unroll
  for (int m = 0; m < 4; ++m) {
    const int rw0 = wr * 64 + m * 16 + g * 4;
#pragma unroll
    for (int n = 0; n < 4; ++n) {
      const int col = n0 + wc * 64 + n * 16 + lrow;
      const float bb = b1e[col];
      f32x4 v = acc[m][n];
#pragma unroll
      for (int j = 0; j < 4; ++j) {
        const int p = tsp + rw0 + j;
        float xv = v[j] + bb;
        float y = 0.7978845608028654f * (xv + 0.044715f * xv * xv * xv);
        float ey = __expf(2.f * y);
        float th = 1.f - 2.f / (ey + 1.f);
        float ge = 0.5f * xv * (1.f + th);
        hmid[(size_t)p * I_DIM + col] = f2bf(ge);
      }
    }
  }
}

// standalone gemm1 (fallback when no dual-wT buffer)
__global__ __launch_bounds__(256, 4) void gemm1_kernel(
    const unsigned short* __restrict__ xb, const unsigned short* __restrict__ w1t,
    const float* __restrict__ b1, unsigned short* __restrict__ hmid,
    const int* __restrict__ pairTok, const int* __restrict__ counts) {
  gemm1_body(blockIdx.x, xb, w1t, b1, hmid, pairTok, counts);
}

// ---------------- fused2: gemm1 [0,2304) || transpose(w2) [2304,10496) --------
__global__ __launch_bounds__(256, 3) void fused2_kernel(
    const unsigned short* __restrict__ xb, const unsigned short* __restrict__ w1t,
    const float* __restrict__ b1, unsigned short* __restrict__ hmid,
    const int* __restrict__ pairTok, const int* __restrict__ counts,
    const float* __restrict__ w2, unsigned short* __restrict__ wT2) {
  const int bid = blockIdx.x;
  if (bid < 2304) {
    gemm1_body(bid, xb, w1t, b1, hmid, pairTok, counts);
  } else {
    const int tbid = bid - 2304;
    const size_t es = (size_t)H_DIM * I_DIM;
    const int e = tbid >> 9, tb = tbid & 511;
    transpose_tile(w2 + es * e, wT2 + es * e, I_DIM, H_DIM, tb & 15, tb >> 4);
  }
}

// ---------------- grouped GEMM2: r10 counted-vmcnt 3-slot pipeline ------------
__global__ __launch_bounds__(256, 3) void gemm2_kernel(
    const unsigned short* __restrict__ hmid,
    const unsigned short* __restrict__ w2t, const float* __restrict__ b2,
    float* __restrict__ out, unsigned short* __restrict__ poA,
    unsigned short* __restrict__ poB, const int* __restrict__ pairTok,
    const float* __restrict__ pairW, const int* __restrict__ counts, int mode) {
  __shared__ char LDS[49152];  // A: 3x8KB @0, B: 3x8KB @24576
  const int bid = blockIdx.x;
  const int nchunk = (mode == 2) ? 288 : 144;
  const int lin = (bid & 7) * nchunk + (bid >> 3);
  const int kh = (mode == 2) ? (lin & 1) : 0;
  const int tx = (mode == 2) ? ((lin >> 1) & 7) : (lin & 7);
  const int ty = (mode == 2) ? (lin >> 4) : (lin >> 3);
  int tsp = 0;
  const int e = tile_map(counts, ty, &tsp);
  if (e < 0) return;
  const int n0 = tx * 128;
  const int tid = threadIdx.x, w = tid >> 6, l = tid & 63;
  const int rbase = w * 16 + (l >> 2);
  const int segp = (l & 3) ^ ((l >> 3) & 3);
  const size_t koff = (size_t)kh * 2048;
  const char* gA0 =
      (const char*)(hmid + (size_t)(tsp + rbase) * I_DIM) + segp * 16 + koff;
  const char* gA1 =
      (const char*)(hmid + (size_t)(tsp + rbase + 64) * I_DIM) + segp * 16 + koff;
  const unsigned short* wbase = w2t + (size_t)e * H_DIM * I_DIM;
  const char* gB0 =
      (const char*)(wbase + (size_t)(n0 + rbase) * I_DIM) + segp * 16 + koff;
  const char* gB1 =
      (const char*)(wbase + (size_t)(n0 + rbase + 64) * I_DIM) + segp * 16 + koff;

  f32x4 acc[4][4];
#pragma unroll
  for (int m = 0; m < 4; ++m)
#pragma unroll
    for (int n = 0; n < 4; ++n) acc[m][n] = f32x4{0.f, 0.f, 0.f, 0.f};

  const int wr = w >> 1, wc = w & 1, lrow = l & 15, g = l >> 4;
  const int gs = g ^ ((l >> 1) & 3);
  const int NK = (mode == 2) ? 32 : 64;

  char* dA = LDS + w * 1024;
  char* dB = LDS + 24576 + w * 1024;
  const unsigned ldsb = (unsigned)(uintptr_t)&LDS[0];
  const unsigned aRd = ldsb + (unsigned)((wr * 64 + lrow) * 64 + gs * 16);
  const unsigned bRd = ldsb + 24576u + (unsigned)((wc * 64 + lrow) * 64 + gs * 16);

  asm volatile("s_waitcnt vmcnt(0)" ::: "memory");
  gld16(gA0, dA);        gld16(gA1, dA + 4096);
  gld16(gB0, dB);        gld16(gB1, dB + 4096);
  gld16(gA0 + 64, dA + 8192);  gld16(gA1 + 64, dA + 8192 + 4096);
  gld16(gB0 + 64, dB + 8192);  gld16(gB1 + 64, dB + 8192 + 4096);

  int srd = 0, sst = 2;
  for (int t = 0; t < NK; ++t) {
    if (t + 1 < NK)
      asm volatile("s_waitcnt vmcnt(4)" ::: "memory");
    else
      asm volatile("s_waitcnt vmcnt(0)" ::: "memory");
    asm volatile("s_barrier" ::: "memory");
    const int tau = t + 2;
    if (tau < NK) {
      const size_t kb = (size_t)tau * 64;
      char* da = dA + sst * 8192;
      char* db = dB + sst * 8192;
      gld16(gA0 + kb, da);  gld16(gA1 + kb, da + 4096);
      gld16(gB0 + kb, db);  gld16(gB1 + kb, db + 4096);
    }
    const unsigned so = (unsigned)(srd * 8192);
    const unsigned aS = aRd + so, bS = bRd + so;
    s16x8 av[4], bv[4];
    DSR(bv[0], bS, 0);    DSR(bv[1], bS, 1024);
    DSR(bv[2], bS, 2048); DSR(bv[3], bS, 3072);
    DSR(av[0], aS, 0);    DSR(av[1], aS, 1024);
    DSR(av[2], aS, 2048); DSR(av[3], aS, 3072);
    asm volatile("s_waitcnt lgkmcnt(0)" ::: "memory");
    __builtin_amdgcn_sched_barrier(0);
    __builtin_amdgcn_s_setprio(1);
#pragma unroll
    for (int m = 0; m < 4; ++m)
#pragma unroll
      for (int n = 0; n < 4; ++n) mfma_bf16(av[m], bv[n], acc[m][n]);
    __builtin_amdgcn_s_setprio(0);
    srd = (srd == 2) ? 0 : srd + 1;
    sst = (sst == 2) ? 0 : sst + 1;
  }
  __builtin_amdgcn_sched_barrier(0);

  if (mode >= 1) {
    unsigned short* po = (kh == 0) ? poA : poB;
#pragma unroll
    for (int m = 0; m < 4; ++m) {
      const int rw0 = wr * 64 + m * 16 + g * 4;
#pragma unroll
      for (int n = 0; n < 4; ++n) {
        const int col = n0 + wc * 64 + n * 16 + lrow;
        f32x4 v = acc[m][n];
#pragma unroll
        for (int j = 0; j < 4; ++j)
          po[(size_t)(tsp + rw0 + j) * H_DIM + col] = f2bf(v[j]);
      }
    }
  } else {
    const float* b2e = b2 + (size_t)e * H_DIM;
#pragma unroll
    for (int m = 0; m < 4; ++m) {
      const int rw0 = wr * 64 + m * 16 + g * 4;
#pragma unroll
      for (int j = 0; j < 4; ++j) {
        const int p = tsp + rw0 + j;
        const int tok = pairTok[p];
        if (tok < 0) continue;
        const float pw = pairW[p];
        float* orow = out + (size_t)tok * H_DIM;
#pragma unroll
        for (int n = 0; n < 4; ++n) {
          const int col = n0 + wc * 64 + n * 16 + lrow;
          float val = (acc[m][n][j] + b2e[col]) * pw;
          atomicAdd(orow + col, val);
        }
      }
    }
  }
}

// ---------------- combine: out[t] = sum_k pw_k * (poA[+poB] + b2[e_k]) --------
__global__ __launch_bounds__(256) void combine_kernel(
    const unsigned short* __restrict__ poA, const unsigned short* __restrict__ poB,
    const int* __restrict__ pairPos, const int* __restrict__ topi,
    const float* __restrict__ topw, const float* __restrict__ b2,
    float* __restrict__ out, int nbuf) {
  const int t = blockIdx.x * 2 + (threadIdx.x >> 7);
  const int c0 = (threadIdx.x & 127) * 8;
  float o[8];
#pragma unroll
  for (int j = 0; j < 8; ++j) o[j] = 0.f;
#pragma unroll
  for (int k = 0; k < K_TOP; ++k) {
    const int e = topi[t * K_TOP + k];
    const float pw = topw[t * K_TOP + k];
    const int pos = pairPos[t * K_TOP + k];
    u16x8 va = *(const u16x8*)(poA + (size_t)pos * H_DIM + c0);
    u16x8 vb;
    if (nbuf == 2) vb = *(const u16x8*)(poB + (size_t)pos * H_DIM + c0);
    const float* b2r = b2 + (size_t)e * H_DIM + c0;
#pragma unroll
    for (int j = 0; j < 8; ++j) {
      float hv = __uint_as_float((unsigned)va[j] << 16);
      if (nbuf == 2) hv += __uint_as_float((unsigned)vb[j] << 16);
      o[j] += pw * (hv + b2r[j]);
    }
  }
  float* orow = out + (size_t)t * H_DIM + c0;
  *(f32x4*)orow = f32x4{o[0], o[1], o[2], o[3]};
  *(f32x4*)(orow + 4) = f32x4{o[4], o[5], o[6], o[7]};
}

// ------------------------------------------------------------------------------
extern "C" void kernel_launch(void* const* d_in, const int* in_sizes, int n_in,
                              void* d_out, int out_size, void* d_ws,
                              size_t ws_size, hipStream_t stream) {
  const float* x = (const float*)d_in[0];
  const float* rw = (const float*)d_in[1];
  const float* rb = (const float*)d_in[2];
  const float* w1 = (const float*)d_in[3];
  const float* b1 = (const float*)d_in[4];
  const float* w2 = (const float*)d_in[5];
  const float* b2 = (const float*)d_in[6];
  float* out = (float*)d_out;
  char* ws = (char*)d_ws;

  const size_t xbSz = (size_t)T_TOK * H_DIM * 2;          // 8.39 MB
  const size_t poSz = (size_t)PAD_PAIRS * H_DIM * 2;      // 37.75 MB
  const size_t wtSz = (size_t)E_NUM * H_DIM * I_DIM * 2;  // 67.11 MB
  const size_t hmSz = (size_t)PAD_PAIRS * I_DIM * 2;      // 75.50 MB
  const size_t smallSz = (size_t)T_TOK * K_TOP * 4 * 3
                         + (size_t)PAD_PAIRS * 4 * 2 + 128;
  const size_t needDualSplit = 2 * poSz + 2 * wtSz + hmSz + smallSz;
  const size_t needDual      = poSz + 2 * wtSz + hmSz + smallSz;
  const size_t needSplit     = 2 * poSz + wtSz + hmSz + smallSz;
  const size_t needPo        = poSz + wtSz + hmSz + smallSz;
  const size_t needMin       = xbSz + wtSz + hmSz + smallSz;
  int dual = 0, split = 0, po = 0;
  if (ws_size >= needDualSplit) { dual = 1; split = 1; po = 1; }
  else if (ws_size >= needDual) { dual = 1; po = 1; }
  else if (ws_size >= needSplit) { split = 1; po = 1; }
  else if (ws_size >= needPo) { po = 1; }
  else if (ws_size < needMin) return;  // diagnostic: output stays 0

  size_t off = 0;
  unsigned short* xb = (unsigned short*)(ws + off);
  unsigned short* poA = (unsigned short*)(ws + off);  // xb dead by gemm2
  off += po ? poSz : xbSz;
  unsigned short* poB = (unsigned short*)(ws + off);
  if (split) off += poSz;
  unsigned short* wT1 = (unsigned short*)(ws + off);
  off += wtSz;
  unsigned short* wT2 = wT1;
  if (dual) { wT2 = (unsigned short*)(ws + off); off += wtSz; }
  unsigned short* hmid = (unsigned short*)(ws + off);
  off += hmSz;
  int* topi = (int*)(ws + off);      off += (size_t)T_TOK * K_TOP * 4;
  float* topw = (float*)(ws + off);  off += (size_t)T_TOK * K_TOP * 4;
  int* pairPos = (int*)(ws + off);   off += (size_t)T_TOK * K_TOP * 4;
  int* pairTok = (int*)(ws + off);   off += (size_t)PAD_PAIRS * 4;
  float* pairW = (float*)(ws + off); off += (size_t)PAD_PAIRS * 4;
  int* counts = (int*)(ws + off);    off += 64;
  int* cursor = (int*)(ws + off);    off += 64;

  const int gmode = split ? 2 : (po ? 1 : 0);

  hipMemsetAsync(counts, 0, 128, stream);  // counts + cursor
  if (gmode == 0) hipMemsetAsync(out, 0, (size_t)T_TOK * H_DIM * 4, stream);

  // stage 1: router (blocks [0,256), dispatched first) || transpose(w1)
  fused1_kernel<<<256 + 8192, 256, 0, stream>>>(x, rw, rb, topi, topw, counts,
                                                xb, w1, wT1);
  scatter_kernel<<<T_TOK / 256, 256, 0, stream>>>(topi, topw, counts, cursor,
                                                  pairTok, pairW, pairPos);
  // stage 2: gemm1 || transpose(w2) when dual buffers available
  if (dual) {
    fused2_kernel<<<2304 + 8192, 256, 0, stream>>>(xb, wT1, b1, hmid, pairTok,
                                                   counts, w2, wT2);
  } else {
    gemm1_kernel<<<16 * MAX_TILES, 256, 0, stream>>>(xb, wT1, b1, hmid, pairTok,
                                                     counts);
    transpose_kernel<<<dim3(H_DIM / 64, I_DIM / 64, E_NUM), 256, 0, stream>>>(
        w2, wT2, I_DIM, H_DIM);
  }
  gemm2_kernel<<<(gmode == 2 ? 16 : 8) * MAX_TILES, 256, 0, stream>>>(
      hmid, wT2, b2, out, poA, poB, pairTok, pairW, counts, gmode);
  if (gmode >= 1)
    combine_kernel<<<T_TOK / 2, 256, 0, stream>>>(poA, poB, pairPos, topi, topw,
                                                  b2, out, gmode);
}

// Round 13
// 368.327 us; speedup vs baseline: 1.5621x; 1.0256x over previous
//
#include <hip/hip_runtime.h>

#define T_TOK 4096
#define H_DIM 1024
#define I_DIM 2048
#define E_NUM 16
#define K_TOP 4
#define BM 128
#define BK 32
#define MAX_TILES 144
#define PAD_PAIRS (MAX_TILES * BM)  // 18432

typedef __attribute__((ext_vector_type(8))) short s16x8;
typedef __attribute__((ext_vector_type(4))) float f32x4;
typedef __attribute__((ext_vector_type(4))) unsigned short u16x4;
typedef __attribute__((ext_vector_type(8))) unsigned short u16x8;

#define DSR(dst, addr, off) \
  asm volatile("ds_read_b128 %0, %1 offset:" #off : "=v"(dst) : "v"(addr))

__device__ __forceinline__ unsigned short f2bf(float f) {
  unsigned u = __float_as_uint(f);
  u += 0x7fffu + ((u >> 16) & 1u);  // round-to-nearest-even
  return (unsigned short)(u >> 16);
}

__device__ __forceinline__ void mfma_bf16(const s16x8& a, const s16x8& b, f32x4& c) {
  asm("v_mfma_f32_16x16x32_bf16 %0, %1, %2, %0" : "+v"(c) : "v"(a), "v"(b));
}

__device__ __forceinline__ void gld16(const void* g, void* l) {
  __builtin_amdgcn_global_load_lds(
      (const __attribute__((address_space(1))) unsigned int*)g,
      (__attribute__((address_space(3))) unsigned int*)l, 16, 0, 0);
}

__device__ __forceinline__ int tile_map(const int* counts, int ty, int* tsp) {
  int e = -1, acc = 0, base = 0;
#pragma unroll
  for (int ee = 0; ee < E_NUM; ++ee) {
    int tc = (counts[ee] + 127) >> 7;
    if (ty >= acc && ty < acc + tc) {
      e = ee;
      *tsp = base + ((ty - acc) << 7);
    }
    acc += tc;
    base += tc << 7;
  }
  return e;
}

// ---------------- transpose tile body (uses caller smem, 16640 B) -------------
__device__ __forceinline__ void transpose_tile(const float* __restrict__ src,
                                               unsigned short* __restrict__ dst,
                                               int R, int C, int tx, int ty,
                                               char* smem) {
  float (*tle)[65] = (float (*)[65])smem;  // 64*65*4 = 16640 B
  int r0 = ty * 64, c0 = tx * 64;
  int rr = threadIdx.x >> 4, cc = (threadIdx.x & 15) * 4;
#pragma unroll
  for (int i = 0; i < 4; ++i) {
    f32x4 v = *(const f32x4*)(src + (size_t)(r0 + rr + 16 * i) * C + c0 + cc);
    tle[rr + 16 * i][cc + 0] = v[0];
    tle[rr + 16 * i][cc + 1] = v[1];
    tle[rr + 16 * i][cc + 2] = v[2];
    tle[rr + 16 * i][cc + 3] = v[3];
  }
  __syncthreads();
#pragma unroll
  for (int i = 0; i < 4; ++i) {
    int oc = c0 + rr + 16 * i;
    u16x4 o;
    o[0] = f2bf(tle[cc + 0][rr + 16 * i]);
    o[1] = f2bf(tle[cc + 1][rr + 16 * i]);
    o[2] = f2bf(tle[cc + 2][rr + 16 * i]);
    o[3] = f2bf(tle[cc + 3][rr + 16 * i]);
    *(u16x4*)(dst + (size_t)oc * R + r0 + cc) = o;
  }
}

// ---------------- router device body (no LDS: rw read direct, L1-resident) ----
__device__ __forceinline__ void router_body(
    int rbid, const float* __restrict__ x, const float* __restrict__ rw,
    const float* __restrict__ rb, int* __restrict__ topi,
    float* __restrict__ topw, int* __restrict__ counts,
    unsigned short* __restrict__ xb) {
  const int tid = threadIdx.x;
  {  // fused x -> bf16 for this block's 16 token rows
    const size_t base = (size_t)rbid * 16 * H_DIM;
#pragma unroll
    for (int it = 0; it < 8; ++it) {
      size_t idx = base + ((size_t)(it * 256 + tid)) * 8;
      f32x4 a = *(const f32x4*)(x + idx);
      f32x4 b = *(const f32x4*)(x + idx + 4);
      u16x8 o;
      o[0] = f2bf(a[0]); o[1] = f2bf(a[1]); o[2] = f2bf(a[2]); o[3] = f2bf(a[3]);
      o[4] = f2bf(b[0]); o[5] = f2bf(b[1]); o[6] = f2bf(b[2]); o[7] = f2bf(b[3]);
      *(u16x8*)(xb + idx) = o;
    }
  }
  const int w = tid >> 6, l = tid & 63;
  const int e = l & 15, q = l >> 4;
  const float rbe = rb[e];
  const float* rq = rw + ((size_t)q * 256) * E_NUM + e;  // lane's expert column
#pragma unroll
  for (int i = 0; i < 4; ++i) {
    const int t = rbid * 16 + w * 4 + i;
    const float* xr = x + (size_t)t * H_DIM + (q << 8);
    float acc = 0.f;
#pragma unroll 8
    for (int hh = 0; hh < 256; hh += 4) {
      f32x4 xv = *(const f32x4*)(xr + hh);
      acc += xv[0] * rq[(hh + 0) * 16];
      acc += xv[1] * rq[(hh + 1) * 16];
      acc += xv[2] * rq[(hh + 2) * 16];
      acc += xv[3] * rq[(hh + 3) * 16];
    }
    acc += __shfl_xor(acc, 16);
    acc += __shfl_xor(acc, 32);
    float logit = acc + rbe;
    float m = logit;
    m = fmaxf(m, __shfl_xor(m, 1));
    m = fmaxf(m, __shfl_xor(m, 2));
    m = fmaxf(m, __shfl_xor(m, 4));
    m = fmaxf(m, __shfl_xor(m, 8));
    float ex = expf(logit - m);
    int rank = 0;
    const int b16 = l & 48;
#pragma unroll
    for (int j = 0; j < 16; ++j) {
      float vj = __shfl(ex, b16 + j);
      rank += (vj > ex) || (vj == ex && j < e);
    }
    float sel = (rank < K_TOP) ? ex : 0.f;
    float subs = sel;
    subs += __shfl_xor(subs, 1);
    subs += __shfl_xor(subs, 2);
    subs += __shfl_xor(subs, 4);
    subs += __shfl_xor(subs, 8);
    if (q == 0 && rank < K_TOP) {
      topi[t * K_TOP + rank] = e;
      topw[t * K_TOP + rank] = ex / subs;
      atomicAdd(&counts[e], 1);
    }
  }
}

// -------- fused1: router FIRST [0,256) || transpose(w1) [256,8448) ------------
__global__ __launch_bounds__(256) void fused1_kernel(
    const float* __restrict__ x, const float* __restrict__ rw,
    const float* __restrict__ rb, int* __restrict__ topi,
    float* __restrict__ topw, int* __restrict__ counts,
    unsigned short* __restrict__ xb, const float* __restrict__ w1,
    unsigned short* __restrict__ wT1) {
  __shared__ char smem[16640];
  const int bid = blockIdx.x;
  if (bid < 256) {
    router_body(bid, x, rw, rb, topi, topw, counts, xb);
  } else {
    const int tbid = bid - 256;
    const size_t es = (size_t)H_DIM * I_DIM;
    const int e = tbid >> 9, tb = tbid & 511;
    transpose_tile(w1 + es * e, wT1 + es * e, H_DIM, I_DIM, tb & 31, tb >> 5,
                   smem);
  }
}

// legacy standalone transpose (fallback path)
__global__ __launch_bounds__(256) void transpose_kernel(
    const float* __restrict__ src, unsigned short* __restrict__ dst, int R,
    int C) {
  __shared__ char smem[16640];
  size_t es = (size_t)R * C;
  transpose_tile(src + es * blockIdx.z, dst + es * blockIdx.z, R, C,
                 blockIdx.x, blockIdx.y, smem);
}

// ---------------- scatter + padding clear -------------------------------------
__global__ __launch_bounds__(256) void scatter_kernel(
    const int* __restrict__ topi, const float* __restrict__ topw,
    const int* __restrict__ counts, int* __restrict__ cursor,
    int* __restrict__ pairTok, float* __restrict__ pairW,
    int* __restrict__ pairPos) {
  int padBase[E_NUM];
  int base = 0;
#pragma unroll
  for (int ee = 0; ee < E_NUM; ++ee) {
    padBase[ee] = base;
    base += ((counts[ee] + 127) >> 7) << 7;
  }
  const int t = blockIdx.x * 256 + threadIdx.x;
#pragma unroll
  for (int k = 0; k < K_TOP; ++k) {
    int e = topi[t * K_TOP + k];
    int pos = atomicAdd(&cursor[e], 1);
    int idx = padBase[e] + pos;
    pairTok[idx] = t;
    pairW[idx] = topw[t * K_TOP + k];
    pairPos[t * K_TOP + k] = idx;
  }
#pragma unroll
  for (int ee = 0; ee < E_NUM; ++ee) {
    int c = counts[ee];
    int padded = ((c + 127) >> 7) << 7;
    int o = c + t;
    if (o < padded) pairTok[padBase[ee] + o] = -1;  // disjoint: race-free
  }
}

// ---------------- gemm1 device body (r9 2-phase; smem passed in, 32768 B) -----
__device__ __forceinline__ void gemm1_body(
    int bid, const unsigned short* __restrict__ xb,
    const unsigned short* __restrict__ w1t, const float* __restrict__ b1,
    unsigned short* __restrict__ hmid, const int* __restrict__ pairTok,
    const int* __restrict__ counts, char* smem) {
  const int lin = (bid & 7) * 288 + (bid >> 3);  // XCD chunk (2304 blocks)
  const int tx = lin & 15, ty = lin >> 4;
  int tsp = 0;
  const int e = tile_map(counts, ty, &tsp);
  if (e < 0) return;
  const int n0 = tx * 128;
  unsigned short* As0 = (unsigned short*)smem;            // 2 x 4096 u16 = 16KB
  unsigned short* Bs0 = (unsigned short*)(smem + 16384);  // 2 x 4096 u16 = 16KB
  const int tid = threadIdx.x, w = tid >> 6, l = tid & 63;
  const int rbase = w * 16 + (l >> 2);
  const int segp = (l & 3) ^ ((l >> 3) & 3);
  int tok0 = pairTok[tsp + rbase];
  if (tok0 < 0) tok0 = 0;
  int tok1 = pairTok[tsp + rbase + 64];
  if (tok1 < 0) tok1 = 0;
  const char* gA0 = (const char*)(xb + (size_t)tok0 * H_DIM) + segp * 16;
  const char* gA1 = (const char*)(xb + (size_t)tok1 * H_DIM) + segp * 16;
  const unsigned short* wbase = w1t + (size_t)e * I_DIM * H_DIM;
  const char* gB0 = (const char*)(wbase + (size_t)(n0 + rbase) * H_DIM) + segp * 16;
  const char* gB1 = (const char*)(wbase + (size_t)(n0 + rbase + 64) * H_DIM) + segp * 16;

  f32x4 acc[4][4];
#pragma unroll
  for (int m = 0; m < 4; ++m)
#pragma unroll
    for (int n = 0; n < 4; ++n) acc[m][n] = f32x4{0.f, 0.f, 0.f, 0.f};

  const int wr = w >> 1, wc = w & 1, lrow = l & 15, g = l >> 4;
  const int gs = g ^ ((l >> 1) & 3);
  const int NK = H_DIM / BK;  // 32

  gld16(gA0, As0 + w * 512);
  gld16(gA1, As0 + 2048 + w * 512);
  gld16(gB0, Bs0 + w * 512);
  gld16(gB1, Bs0 + 2048 + w * 512);

  for (int kt = 0; kt < NK; ++kt) {
    __syncthreads();
    if (kt + 1 < NK) {
      const int kb = (kt + 1) * 64;
      const int nb = (kt + 1) & 1;
      gld16(gA0 + kb, As0 + nb * 4096 + w * 512);
      gld16(gA1 + kb, As0 + nb * 4096 + 2048 + w * 512);
      gld16(gB0 + kb, Bs0 + nb * 4096 + w * 512);
      gld16(gB1 + kb, Bs0 + nb * 4096 + 2048 + w * 512);
    }
    const int cb = kt & 1;
    const s16x8* Ap = (const s16x8*)(As0 + cb * 4096);
    const s16x8* Bp = (const s16x8*)(Bs0 + cb * 4096);
    s16x8 av[4], bv[4];
#pragma unroll
    for (int m = 0; m < 4; ++m) av[m] = Ap[(wr * 64 + m * 16 + lrow) * 4 + gs];
#pragma unroll
    for (int n = 0; n < 4; ++n) bv[n] = Bp[(wc * 64 + n * 16 + lrow) * 4 + gs];
#pragma unroll
    for (int m = 0; m < 4; ++m)
#pragma unroll
      for (int n = 0; n < 4; ++n) mfma_bf16(av[m], bv[n], acc[m][n]);
  }

  const float* b1e = b1 + (size_t)e * I_DIM;
#pragma unroll
  for (int m = 0; m < 4; ++m) {
    const int rw0 = wr * 64 + m * 16 + g * 4;
#pragma unroll
    for (int n = 0; n < 4; ++n) {
      const int col = n0 + wc * 64 + n * 16 + lrow;
      const float bb = b1e[col];
      f32x4 v = acc[m][n];
#pragma unroll
      for (int j = 0; j < 4; ++j) {
        const int p = tsp + rw0 + j;
        float xv = v[j] + bb;
        float y = 0.7978845608028654f * (xv + 0.044715f * xv * xv * xv);
        float ey = __expf(2.f * y);
        float th = 1.f - 2.f / (ey + 1.f);
        float ge = 0.5f * xv * (1.f + th);
        hmid[(size_t)p * I_DIM + col] = f2bf(ge);
      }
    }
  }
}

// standalone gemm1 (fallback when no dual-wT buffer)
__global__ __launch_bounds__(256, 4) void gemm1_kernel(
    const unsigned short* __restrict__ xb, const unsigned short* __restrict__ w1t,
    const float* __restrict__ b1, unsigned short* __restrict__ hmid,
    const int* __restrict__ pairTok, const int* __restrict__ counts) {
  __shared__ char smem[32768];
  gemm1_body(blockIdx.x, xb, w1t, b1, hmid, pairTok, counts, smem);
}

// ---------------- fused2: gemm1 [0,2304) || transpose(w2) [2304,10496) --------
// smem UNION (32KB = max of the two bodies, not sum) -> 4 blocks/CU for the
// gemm1 blocks (r12's 49.7KB summed allocation capped occupancy at 3/CU,
// costing gemm1 exactly the 126->150us ratio).
__global__ __launch_bounds__(256, 4) void fused2_kernel(
    const unsigned short* __restrict__ xb, const unsigned short* __restrict__ w1t,
    const float* __restrict__ b1, unsigned short* __restrict__ hmid,
    const int* __restrict__ pairTok, const int* __restrict__ counts,
    const float* __restrict__ w2, unsigned short* __restrict__ wT2) {
  __shared__ char smem[32768];
  const int bid = blockIdx.x;
  if (bid < 2304) {
    gemm1_body(bid, xb, w1t, b1, hmid, pairTok, counts, smem);
  } else {
    const int tbid = bid - 2304;
    const size_t es = (size_t)H_DIM * I_DIM;
    const int e = tbid >> 9, tb = tbid & 511;
    transpose_tile(w2 + es * e, wT2 + es * e, I_DIM, H_DIM, tb & 15, tb >> 4,
                   smem);
  }
}

// ---------------- grouped GEMM2: r10 counted-vmcnt 3-slot pipeline ------------
__global__ __launch_bounds__(256, 3) void gemm2_kernel(
    const unsigned short* __restrict__ hmid,
    const unsigned short* __restrict__ w2t, const float* __restrict__ b2,
    float* __restrict__ out, unsigned short* __restrict__ poA,
    unsigned short* __restrict__ poB, const int* __restrict__ pairTok,
    const float* __restrict__ pairW, const int* __restrict__ counts, int mode) {
  __shared__ char LDS[49152];  // A: 3x8KB @0, B: 3x8KB @24576
  const int bid = blockIdx.x;
  const int nchunk = (mode == 2) ? 288 : 144;
  const int lin = (bid & 7) * nchunk + (bid >> 3);
  const int kh = (mode == 2) ? (lin & 1) : 0;
  const int tx = (mode == 2) ? ((lin >> 1) & 7) : (lin & 7);
  const int ty = (mode == 2) ? (lin >> 4) : (lin >> 3);
  int tsp = 0;
  const int e = tile_map(counts, ty, &tsp);
  if (e < 0) return;
  const int n0 = tx * 128;
  const int tid = threadIdx.x, w = tid >> 6, l = tid & 63;
  const int rbase = w * 16 + (l >> 2);
  const int segp = (l & 3) ^ ((l >> 3) & 3);
  const size_t koff = (size_t)kh * 2048;
  const char* gA0 =
      (const char*)(hmid + (size_t)(tsp + rbase) * I_DIM) + segp * 16 + koff;
  const char* gA1 =
      (const char*)(hmid + (size_t)(tsp + rbase + 64) * I_DIM) + segp * 16 + koff;
  const unsigned short* wbase = w2t + (size_t)e * H_DIM * I_DIM;
  const char* gB0 =
      (const char*)(wbase + (size_t)(n0 + rbase) * I_DIM) + segp * 16 + koff;
  const char* gB1 =
      (const char*)(wbase + (size_t)(n0 + rbase + 64) * I_DIM) + segp * 16 + koff;

  f32x4 acc[4][4];
#pragma unroll
  for (int m = 0; m < 4; ++m)
#pragma unroll
    for (int n = 0; n < 4; ++n) acc[m][n] = f32x4{0.f, 0.f, 0.f, 0.f};

  const int wr = w >> 1, wc = w & 1, lrow = l & 15, g = l >> 4;
  const int gs = g ^ ((l >> 1) & 3);
  const int NK = (mode == 2) ? 32 : 64;

  char* dA = LDS + w * 1024;
  char* dB = LDS + 24576 + w * 1024;
  const unsigned ldsb = (unsigned)(uintptr_t)&LDS[0];
  const unsigned aRd = ldsb + (unsigned)((wr * 64 + lrow) * 64 + gs * 16);
  const unsigned bRd = ldsb + 24576u + (unsigned)((wc * 64 + lrow) * 64 + gs * 16);

  asm volatile("s_waitcnt vmcnt(0)" ::: "memory");
  gld16(gA0, dA);        gld16(gA1, dA + 4096);
  gld16(gB0, dB);        gld16(gB1, dB + 4096);
  gld16(gA0 + 64, dA + 8192);  gld16(gA1 + 64, dA + 8192 + 4096);
  gld16(gB0 + 64, dB + 8192);  gld16(gB1 + 64, dB + 8192 + 4096);

  int srd = 0, sst = 2;
  for (int t = 0; t < NK; ++t) {
    if (t + 1 < NK)
      asm volatile("s_waitcnt vmcnt(4)" ::: "memory");
    else
      asm volatile("s_waitcnt vmcnt(0)" ::: "memory");
    asm volatile("s_barrier" ::: "memory");
    const int tau = t + 2;
    if (tau < NK) {
      const size_t kb = (size_t)tau * 64;
      char* da = dA + sst * 8192;
      char* db = dB + sst * 8192;
      gld16(gA0 + kb, da);  gld16(gA1 + kb, da + 4096);
      gld16(gB0 + kb, db);  gld16(gB1 + kb, db + 4096);
    }
    const unsigned so = (unsigned)(srd * 8192);
    const unsigned aS = aRd + so, bS = bRd + so;
    s16x8 av[4], bv[4];
    DSR(bv[0], bS, 0);    DSR(bv[1], bS, 1024);
    DSR(bv[2], bS, 2048); DSR(bv[3], bS, 3072);
    DSR(av[0], aS, 0);    DSR(av[1], aS, 1024);
    DSR(av[2], aS, 2048); DSR(av[3], aS, 3072);
    asm volatile("s_waitcnt lgkmcnt(0)" ::: "memory");
    __builtin_amdgcn_sched_barrier(0);
    __builtin_amdgcn_s_setprio(1);
#pragma unroll
    for (int m = 0; m < 4; ++m)
#pragma unroll
      for (int n = 0; n < 4; ++n) mfma_bf16(av[m], bv[n], acc[m][n]);
    __builtin_amdgcn_s_setprio(0);
    srd = (srd == 2) ? 0 : srd + 1;
    sst = (sst == 2) ? 0 : sst + 1;
  }
  __builtin_amdgcn_sched_barrier(0);

  if (mode >= 1) {
    unsigned short* po = (kh == 0) ? poA : poB;
#pragma unroll
    for (int m = 0; m < 4; ++m) {
      const int rw0 = wr * 64 + m * 16 + g * 4;
#pragma unroll
      for (int n = 0; n < 4; ++n) {
        const int col = n0 + wc * 64 + n * 16 + lrow;
        f32x4 v = acc[m][n];
#pragma unroll
        for (int j = 0; j < 4; ++j)
          po[(size_t)(tsp + rw0 + j) * H_DIM + col] = f2bf(v[j]);
      }
    }
  } else {
    const float* b2e = b2 + (size_t)e * H_DIM;
#pragma unroll
    for (int m = 0; m < 4; ++m) {
      const int rw0 = wr * 64 + m * 16 + g * 4;
#pragma unroll
      for (int j = 0; j < 4; ++j) {
        const int p = tsp + rw0 + j;
        const int tok = pairTok[p];
        if (tok < 0) continue;
        const float pw = pairW[p];
        float* orow = out + (size_t)tok * H_DIM;
#pragma unroll
        for (int n = 0; n < 4; ++n) {
          const int col = n0 + wc * 64 + n * 16 + lrow;
          float val = (acc[m][n][j] + b2e[col]) * pw;
          atomicAdd(orow + col, val);
        }
      }
    }
  }
}

// ---------------- combine: out[t] = sum_k pw_k * (poA[+poB] + b2[e_k]) --------
__global__ __launch_bounds__(256) void combine_kernel(
    const unsigned short* __restrict__ poA, const unsigned short* __restrict__ poB,
    const int* __restrict__ pairPos, const int* __restrict__ topi,
    const float* __restrict__ topw, const float* __restrict__ b2,
    float* __restrict__ out, int nbuf) {
  const int t = blockIdx.x * 2 + (threadIdx.x >> 7);
  const int c0 = (threadIdx.x & 127) * 8;
  float o[8];
#pragma unroll
  for (int j = 0; j < 8; ++j) o[j] = 0.f;
#pragma unroll
  for (int k = 0; k < K_TOP; ++k) {
    const int e = topi[t * K_TOP + k];
    const float pw = topw[t * K_TOP + k];
    const int pos = pairPos[t * K_TOP + k];
    u16x8 va = *(const u16x8*)(poA + (size_t)pos * H_DIM + c0);
    u16x8 vb;
    if (nbuf == 2) vb = *(const u16x8*)(poB + (size_t)pos * H_DIM + c0);
    const float* b2r = b2 + (size_t)e * H_DIM + c0;
#pragma unroll
    for (int j = 0; j < 8; ++j) {
      float hv = __uint_as_float((unsigned)va[j] << 16);
      if (nbuf == 2) hv += __uint_as_float((unsigned)vb[j] << 16);
      o[j] += pw * (hv + b2r[j]);
    }
  }
  float* orow = out + (size_t)t * H_DIM + c0;
  *(f32x4*)orow = f32x4{o[0], o[1], o[2], o[3]};
  *(f32x4*)(orow + 4) = f32x4{o[4], o[5], o[6], o[7]};
}

// ------------------------------------------------------------------------------
extern "C" void kernel_launch(void* const* d_in, const int* in_sizes, int n_in,
                              void* d_out, int out_size, void* d_ws,
                              size_t ws_size, hipStream_t stream) {
  const float* x = (const float*)d_in[0];
  const float* rw = (const float*)d_in[1];
  const float* rb = (const float*)d_in[2];
  const float* w1 = (const float*)d_in[3];
  const float* b1 = (const float*)d_in[4];
  const float* w2 = (const float*)d_in[5];
  const float* b2 = (const float*)d_in[6];
  float* out = (float*)d_out;
  char* ws = (char*)d_ws;

  const size_t xbSz = (size_t)T_TOK * H_DIM * 2;          // 8.39 MB
  const size_t poSz = (size_t)PAD_PAIRS * H_DIM * 2;      // 37.75 MB
  const size_t wtSz = (size_t)E_NUM * H_DIM * I_DIM * 2;  // 67.11 MB
  const size_t hmSz = (size_t)PAD_PAIRS * I_DIM * 2;      // 75.50 MB
  const size_t smallSz = (size_t)T_TOK * K_TOP * 4 * 3
                         + (size_t)PAD_PAIRS * 4 * 2 + 128;
  const size_t needDualSplit = 2 * poSz + 2 * wtSz + hmSz + smallSz;
  const size_t needDual      = poSz + 2 * wtSz + hmSz + smallSz;
  const size_t needSplit     = 2 * poSz + wtSz + hmSz + smallSz;
  const size_t needPo        = poSz + wtSz + hmSz + smallSz;
  const size_t needMin       = xbSz + wtSz + hmSz + smallSz;
  int dual = 0, split = 0, po = 0;
  if (ws_size >= needDualSplit) { dual = 1; split = 1; po = 1; }
  else if (ws_size >= needDual) { dual = 1; po = 1; }
  else if (ws_size >= needSplit) { split = 1; po = 1; }
  else if (ws_size >= needPo) { po = 1; }
  else if (ws_size < needMin) return;  // diagnostic: output stays 0

  size_t off = 0;
  unsigned short* xb = (unsigned short*)(ws + off);
  unsigned short* poA = (unsigned short*)(ws + off);  // xb dead by gemm2
  off += po ? poSz : xbSz;
  unsigned short* poB = (unsigned short*)(ws + off);
  if (split) off += poSz;
  unsigned short* wT1 = (unsigned short*)(ws + off);
  off += wtSz;
  unsigned short* wT2 = wT1;
  if (dual) { wT2 = (unsigned short*)(ws + off); off += wtSz; }
  unsigned short* hmid = (unsigned short*)(ws + off);
  off += hmSz;
  int* topi = (int*)(ws + off);      off += (size_t)T_TOK * K_TOP * 4;
  float* topw = (float*)(ws + off);  off += (size_t)T_TOK * K_TOP * 4;
  int* pairPos = (int*)(ws + off);   off += (size_t)T_TOK * K_TOP * 4;
  int* pairTok = (int*)(ws + off);   off += (size_t)PAD_PAIRS * 4;
  float* pairW = (float*)(ws + off); off += (size_t)PAD_PAIRS * 4;
  int* counts = (int*)(ws + off);    off += 64;
  int* cursor = (int*)(ws + off);    off += 64;

  const int gmode = split ? 2 : (po ? 1 : 0);

  hipMemsetAsync(counts, 0, 128, stream);  // counts + cursor
  if (gmode == 0) hipMemsetAsync(out, 0, (size_t)T_TOK * H_DIM * 4, stream);

  // stage 1: router (blocks [0,256), dispatched first) || transpose(w1)
  fused1_kernel<<<256 + 8192, 256, 0, stream>>>(x, rw, rb, topi, topw, counts,
                                                xb, w1, wT1);
  scatter_kernel<<<T_TOK / 256, 256, 0, stream>>>(topi, topw, counts, cursor,
                                                  pairTok, pairW, pairPos);
  // stage 2: gemm1 || transpose(w2) when dual buffers available
  if (dual) {
    fused2_kernel<<<2304 + 8192, 256, 0, stream>>>(xb, wT1, b1, hmid, pairTok,
                                                   counts, w2, wT2);
  } else {
    gemm1_kernel<<<16 * MAX_TILES, 256, 0, stream>>>(xb, wT1, b1, hmid, pairTok,
                                                     counts);
    transpose_kernel<<<dim3(H_DIM / 64, I_DIM / 64, E_NUM), 256, 0, stream>>>(
        w2, wT2, I_DIM, H_DIM);
  }
  gemm2_kernel<<<(gmode == 2 ? 16 : 8) * MAX_TILES, 256, 0, stream>>>(
      hmid, wT2, b2, out, poA, poB, pairTok, pairW, counts, gmode);
  if (gmode >= 1)
    combine_kernel<<<T_TOK / 2, 256, 0, stream>>>(poA, poB, pairPos, topi, topw,
                                                  b2, out, gmode);
}

// Round 14
// 363.924 us; speedup vs baseline: 1.5810x; 1.0121x over previous
//
#include <hip/hip_runtime.h>

#define T_TOK 4096
#define H_DIM 1024
#define I_DIM 2048
#define E_NUM 16
#define K_TOP 4
#define BM 128
#define BK 32
#define MAX_TILES 144
#define PAD_PAIRS (MAX_TILES * BM)  // 18432

typedef __attribute__((ext_vector_type(8))) short s16x8;
typedef __attribute__((ext_vector_type(4))) float f32x4;
typedef __attribute__((ext_vector_type(4))) unsigned short u16x4;
typedef __attribute__((ext_vector_type(8))) unsigned short u16x8;

#define DSR(dst, addr, off) \
  asm volatile("ds_read_b128 %0, %1 offset:" #off : "=v"(dst) : "v"(addr))

__device__ __forceinline__ unsigned short f2bf(float f) {
  unsigned u = __float_as_uint(f);
  u += 0x7fffu + ((u >> 16) & 1u);  // round-to-nearest-even
  return (unsigned short)(u >> 16);
}

__device__ __forceinline__ void mfma_bf16(const s16x8& a, const s16x8& b, f32x4& c) {
  asm("v_mfma_f32_16x16x32_bf16 %0, %1, %2, %0" : "+v"(c) : "v"(a), "v"(b));
}

__device__ __forceinline__ void gld16(const void* g, void* l) {
  __builtin_amdgcn_global_load_lds(
      (const __attribute__((address_space(1))) unsigned int*)g,
      (__attribute__((address_space(3))) unsigned int*)l, 16, 0, 0);
}

__device__ __forceinline__ int tile_map(const int* counts, int ty, int* tsp) {
  int e = -1, acc = 0, base = 0;
#pragma unroll
  for (int ee = 0; ee < E_NUM; ++ee) {
    int tc = (counts[ee] + 127) >> 7;
    if (ty >= acc && ty < acc + tc) {
      e = ee;
      *tsp = base + ((ty - acc) << 7);
    }
    acc += tc;
    base += tc << 7;
  }
  return e;
}

// ---------------- transpose tile body (caller smem; nontemporal weights) ------
// nt hints: weights are read-once/write-once — keep them from evicting the
// co-resident GEMM's L2 working set (r13: fused2 FETCH 187MB, 13us contention).
__device__ __forceinline__ void transpose_tile(const float* __restrict__ src,
                                               unsigned short* __restrict__ dst,
                                               int R, int C, int tx, int ty,
                                               char* smem) {
  float (*tle)[65] = (float (*)[65])smem;  // 64*65*4 = 16640 B
  int r0 = ty * 64, c0 = tx * 64;
  int rr = threadIdx.x >> 4, cc = (threadIdx.x & 15) * 4;
#pragma unroll
  for (int i = 0; i < 4; ++i) {
    f32x4 v = __builtin_nontemporal_load(
        (const f32x4*)(src + (size_t)(r0 + rr + 16 * i) * C + c0 + cc));
    tle[rr + 16 * i][cc + 0] = v[0];
    tle[rr + 16 * i][cc + 1] = v[1];
    tle[rr + 16 * i][cc + 2] = v[2];
    tle[rr + 16 * i][cc + 3] = v[3];
  }
  __syncthreads();
#pragma unroll
  for (int i = 0; i < 4; ++i) {
    int oc = c0 + rr + 16 * i;
    u16x4 o;
    o[0] = f2bf(tle[cc + 0][rr + 16 * i]);
    o[1] = f2bf(tle[cc + 1][rr + 16 * i]);
    o[2] = f2bf(tle[cc + 2][rr + 16 * i]);
    o[3] = f2bf(tle[cc + 3][rr + 16 * i]);
    __builtin_nontemporal_store(o, (u16x4*)(dst + (size_t)oc * R + r0 + cc));
  }
}

// two adjacent column-tiles per block: same src rows, 512B effective per-row
// span (r13: 64-tile bursts were 256B at 8KB row stride -> ~3.1 TB/s).
__device__ __forceinline__ void transpose_tile2(const float* __restrict__ src,
                                                unsigned short* __restrict__ dst,
                                                int R, int C, int txd, int ty,
                                                char* smem) {
  transpose_tile(src, dst, R, C, txd * 2, ty, smem);
  __syncthreads();
  transpose_tile(src, dst, R, C, txd * 2 + 1, ty, smem);
}

// ---------------- router device body (no LDS: rw read direct, L1-resident) ----
__device__ __forceinline__ void router_body(
    int rbid, const float* __restrict__ x, const float* __restrict__ rw,
    const float* __restrict__ rb, int* __restrict__ topi,
    float* __restrict__ topw, int* __restrict__ counts,
    unsigned short* __restrict__ xb) {
  const int tid = threadIdx.x;
  {  // fused x -> bf16 for this block's 16 token rows
    const size_t base = (size_t)rbid * 16 * H_DIM;
#pragma unroll
    for (int it = 0; it < 8; ++it) {
      size_t idx = base + ((size_t)(it * 256 + tid)) * 8;
      f32x4 a = *(const f32x4*)(x + idx);
      f32x4 b = *(const f32x4*)(x + idx + 4);
      u16x8 o;
      o[0] = f2bf(a[0]); o[1] = f2bf(a[1]); o[2] = f2bf(a[2]); o[3] = f2bf(a[3]);
      o[4] = f2bf(b[0]); o[5] = f2bf(b[1]); o[6] = f2bf(b[2]); o[7] = f2bf(b[3]);
      *(u16x8*)(xb + idx) = o;
    }
  }
  const int w = tid >> 6, l = tid & 63;
  const int e = l & 15, q = l >> 4;
  const float rbe = rb[e];
  const float* rq = rw + ((size_t)q * 256) * E_NUM + e;  // lane's expert column
#pragma unroll
  for (int i = 0; i < 4; ++i) {
    const int t = rbid * 16 + w * 4 + i;
    const float* xr = x + (size_t)t * H_DIM + (q << 8);
    float acc = 0.f;
#pragma unroll 8
    for (int hh = 0; hh < 256; hh += 4) {
      f32x4 xv = *(const f32x4*)(xr + hh);
      acc += xv[0] * rq[(hh + 0) * 16];
      acc += xv[1] * rq[(hh + 1) * 16];
      acc += xv[2] * rq[(hh + 2) * 16];
      acc += xv[3] * rq[(hh + 3) * 16];
    }
    acc += __shfl_xor(acc, 16);
    acc += __shfl_xor(acc, 32);
    float logit = acc + rbe;
    float m = logit;
    m = fmaxf(m, __shfl_xor(m, 1));
    m = fmaxf(m, __shfl_xor(m, 2));
    m = fmaxf(m, __shfl_xor(m, 4));
    m = fmaxf(m, __shfl_xor(m, 8));
    float ex = expf(logit - m);
    int rank = 0;
    const int b16 = l & 48;
#pragma unroll
    for (int j = 0; j < 16; ++j) {
      float vj = __shfl(ex, b16 + j);
      rank += (vj > ex) || (vj == ex && j < e);
    }
    float sel = (rank < K_TOP) ? ex : 0.f;
    float subs = sel;
    subs += __shfl_xor(subs, 1);
    subs += __shfl_xor(subs, 2);
    subs += __shfl_xor(subs, 4);
    subs += __shfl_xor(subs, 8);
    if (q == 0 && rank < K_TOP) {
      topi[t * K_TOP + rank] = e;
      topw[t * K_TOP + rank] = ex / subs;
      atomicAdd(&counts[e], 1);
    }
  }
}

// -------- fused1: router FIRST [0,256) || transpose(w1) x2 [256,4352) ---------
__global__ __launch_bounds__(256) void fused1_kernel(
    const float* __restrict__ x, const float* __restrict__ rw,
    const float* __restrict__ rb, int* __restrict__ topi,
    float* __restrict__ topw, int* __restrict__ counts,
    unsigned short* __restrict__ xb, const float* __restrict__ w1,
    unsigned short* __restrict__ wT1) {
  __shared__ char smem[16640];
  const int bid = blockIdx.x;
  if (bid < 256) {
    router_body(bid, x, rw, rb, topi, topw, counts, xb);
  } else {
    const int tbid = bid - 256;  // 0..4095: e = tbid>>8, 256 dbl-tiles/expert
    const size_t es = (size_t)H_DIM * I_DIM;
    const int e = tbid >> 8, tb = tbid & 255;
    // w1: R=1024 C=2048 -> txd 0..15 (128 cols), ty 0..15 (64 rows)
    transpose_tile2(w1 + es * e, wT1 + es * e, H_DIM, I_DIM, tb & 15, tb >> 4,
                    smem);
  }
}

// legacy standalone transpose (fallback path, single tile per block)
__global__ __launch_bounds__(256) void transpose_kernel(
    const float* __restrict__ src, unsigned short* __restrict__ dst, int R,
    int C) {
  __shared__ char smem[16640];
  size_t es = (size_t)R * C;
  transpose_tile(src + es * blockIdx.z, dst + es * blockIdx.z, R, C,
                 blockIdx.x, blockIdx.y, smem);
}

// ---------------- scatter + padding clear -------------------------------------
__global__ __launch_bounds__(256) void scatter_kernel(
    const int* __restrict__ topi, const float* __restrict__ topw,
    const int* __restrict__ counts, int* __restrict__ cursor,
    int* __restrict__ pairTok, float* __restrict__ pairW,
    int* __restrict__ pairPos) {
  int padBase[E_NUM];
  int base = 0;
#pragma unroll
  for (int ee = 0; ee < E_NUM; ++ee) {
    padBase[ee] = base;
    base += ((counts[ee] + 127) >> 7) << 7;
  }
  const int t = blockIdx.x * 256 + threadIdx.x;
#pragma unroll
  for (int k = 0; k < K_TOP; ++k) {
    int e = topi[t * K_TOP + k];
    int pos = atomicAdd(&cursor[e], 1);
    int idx = padBase[e] + pos;
    pairTok[idx] = t;
    pairW[idx] = topw[t * K_TOP + k];
    pairPos[t * K_TOP + k] = idx;
  }
#pragma unroll
  for (int ee = 0; ee < E_NUM; ++ee) {
    int c = counts[ee];
    int padded = ((c + 127) >> 7) << 7;
    int o = c + t;
    if (o < padded) pairTok[padBase[ee] + o] = -1;  // disjoint: race-free
  }
}

// ---------------- gemm1 device body (r9 2-phase; smem passed in, 32768 B) -----
__device__ __forceinline__ void gemm1_body(
    int bid, const unsigned short* __restrict__ xb,
    const unsigned short* __restrict__ w1t, const float* __restrict__ b1,
    unsigned short* __restrict__ hmid, const int* __restrict__ pairTok,
    const int* __restrict__ counts, char* smem) {
  const int lin = (bid & 7) * 288 + (bid >> 3);  // XCD chunk (2304 blocks)
  const int tx = lin & 15, ty = lin >> 4;
  int tsp = 0;
  const int e = tile_map(counts, ty, &tsp);
  if (e < 0) return;
  const int n0 = tx * 128;
  unsigned short* As0 = (unsigned short*)smem;            // 2 x 4096 u16 = 16KB
  unsigned short* Bs0 = (unsigned short*)(smem + 16384);  // 2 x 4096 u16 = 16KB
  const int tid = threadIdx.x, w = tid >> 6, l = tid & 63;
  const int rbase = w * 16 + (l >> 2);
  const int segp = (l & 3) ^ ((l >> 3) & 3);
  int tok0 = pairTok[tsp + rbase];
  if (tok0 < 0) tok0 = 0;
  int tok1 = pairTok[tsp + rbase + 64];
  if (tok1 < 0) tok1 = 0;
  const char* gA0 = (const char*)(xb + (size_t)tok0 * H_DIM) + segp * 16;
  const char* gA1 = (const char*)(xb + (size_t)tok1 * H_DIM) + segp * 16;
  const unsigned short* wbase = w1t + (size_t)e * I_DIM * H_DIM;
  const char* gB0 = (const char*)(wbase + (size_t)(n0 + rbase) * H_DIM) + segp * 16;
  const char* gB1 = (const char*)(wbase + (size_t)(n0 + rbase + 64) * H_DIM) + segp * 16;

  f32x4 acc[4][4];
#pragma unroll
  for (int m = 0; m < 4; ++m)
#pragma unroll
    for (int n = 0; n < 4; ++n) acc[m][n] = f32x4{0.f, 0.f, 0.f, 0.f};

  const int wr = w >> 1, wc = w & 1, lrow = l & 15, g = l >> 4;
  const int gs = g ^ ((l >> 1) & 3);
  const int NK = H_DIM / BK;  // 32

  gld16(gA0, As0 + w * 512);
  gld16(gA1, As0 + 2048 + w * 512);
  gld16(gB0, Bs0 + w * 512);
  gld16(gB1, Bs0 + 2048 + w * 512);

  for (int kt = 0; kt < NK; ++kt) {
    __syncthreads();
    if (kt + 1 < NK) {
      const int kb = (kt + 1) * 64;
      const int nb = (kt + 1) & 1;
      gld16(gA0 + kb, As0 + nb * 4096 + w * 512);
      gld16(gA1 + kb, As0 + nb * 4096 + 2048 + w * 512);
      gld16(gB0 + kb, Bs0 + nb * 4096 + w * 512);
      gld16(gB1 + kb, Bs0 + nb * 4096 + 2048 + w * 512);
    }
    const int cb = kt & 1;
    const s16x8* Ap = (const s16x8*)(As0 + cb * 4096);
    const s16x8* Bp = (const s16x8*)(Bs0 + cb * 4096);
    s16x8 av[4], bv[4];
#pragma unroll
    for (int m = 0; m < 4; ++m) av[m] = Ap[(wr * 64 + m * 16 + lrow) * 4 + gs];
#pragma unroll
    for (int n = 0; n < 4; ++n) bv[n] = Bp[(wc * 64 + n * 16 + lrow) * 4 + gs];
#pragma unroll
    for (int m = 0; m < 4; ++m)
#pragma unroll
      for (int n = 0; n < 4; ++n) mfma_bf16(av[m], bv[n], acc[m][n]);
  }

  const float* b1e = b1 + (size_t)e * I_DIM;
#pragma unroll
  for (int m = 0; m < 4; ++m) {
    const int rw0 = wr * 64 + m * 16 + g * 4;
#pragma unroll
    for (int n = 0; n < 4; ++n) {
      const int col = n0 + wc * 64 + n * 16 + lrow;
      const float bb = b1e[col];
      f32x4 v = acc[m][n];
#pragma unroll
      for (int j = 0; j < 4; ++j) {
        const int p = tsp + rw0 + j;
        float xv = v[j] + bb;
        float y = 0.7978845608028654f * (xv + 0.044715f * xv * xv * xv);
        float ey = __expf(2.f * y);
        float th = 1.f - 2.f / (ey + 1.f);
        float ge = 0.5f * xv * (1.f + th);
        hmid[(size_t)p * I_DIM + col] = f2bf(ge);
      }
    }
  }
}

// standalone gemm1 (fallback when no dual-wT buffer)
__global__ __launch_bounds__(256, 4) void gemm1_kernel(
    const unsigned short* __restrict__ xb, const unsigned short* __restrict__ w1t,
    const float* __restrict__ b1, unsigned short* __restrict__ hmid,
    const int* __restrict__ pairTok, const int* __restrict__ counts) {
  __shared__ char smem[32768];
  gemm1_body(blockIdx.x, xb, w1t, b1, hmid, pairTok, counts, smem);
}

// ---------------- fused2: gemm1 [0,2304) || transpose(w2) x2 [2304,6400) ------
// smem union (32KB = max, not sum) -> 4+ blocks/CU for gemm1 blocks (r13).
__global__ __launch_bounds__(256, 4) void fused2_kernel(
    const unsigned short* __restrict__ xb, const unsigned short* __restrict__ w1t,
    const float* __restrict__ b1, unsigned short* __restrict__ hmid,
    const int* __restrict__ pairTok, const int* __restrict__ counts,
    const float* __restrict__ w2, unsigned short* __restrict__ wT2) {
  __shared__ char smem[32768];
  const int bid = blockIdx.x;
  if (bid < 2304) {
    gemm1_body(bid, xb, w1t, b1, hmid, pairTok, counts, smem);
  } else {
    const int tbid = bid - 2304;  // 0..4095: e = tbid>>8, 256 dbl-tiles/expert
    const size_t es = (size_t)H_DIM * I_DIM;
    const int e = tbid >> 8, tb = tbid & 255;
    // w2: R=2048 C=1024 -> txd 0..7 (128 cols), ty 0..31 (64 rows)
    transpose_tile2(w2 + es * e, wT2 + es * e, I_DIM, H_DIM, tb & 7, tb >> 3,
                    smem);
  }
}

// ---------------- grouped GEMM2: r10 counted-vmcnt 3-slot pipeline ------------
__global__ __launch_bounds__(256, 3) void gemm2_kernel(
    const unsigned short* __restrict__ hmid,
    const unsigned short* __restrict__ w2t, const float* __restrict__ b2,
    float* __restrict__ out, unsigned short* __restrict__ poA,
    unsigned short* __restrict__ poB, const int* __restrict__ pairTok,
    const float* __restrict__ pairW, const int* __restrict__ counts, int mode) {
  __shared__ char LDS[49152];  // A: 3x8KB @0, B: 3x8KB @24576
  const int bid = blockIdx.x;
  const int nchunk = (mode == 2) ? 288 : 144;
  const int lin = (bid & 7) * nchunk + (bid >> 3);
  const int kh = (mode == 2) ? (lin & 1) : 0;
  const int tx = (mode == 2) ? ((lin >> 1) & 7) : (lin & 7);
  const int ty = (mode == 2) ? (lin >> 4) : (lin >> 3);
  int tsp = 0;
  const int e = tile_map(counts, ty, &tsp);
  if (e < 0) return;
  const int n0 = tx * 128;
  const int tid = threadIdx.x, w = tid >> 6, l = tid & 63;
  const int rbase = w * 16 + (l >> 2);
  const int segp = (l & 3) ^ ((l >> 3) & 3);
  const size_t koff = (size_t)kh * 2048;
  const char* gA0 =
      (const char*)(hmid + (size_t)(tsp + rbase) * I_DIM) + segp * 16 + koff;
  const char* gA1 =
      (const char*)(hmid + (size_t)(tsp + rbase + 64) * I_DIM) + segp * 16 + koff;
  const unsigned short* wbase = w2t + (size_t)e * H_DIM * I_DIM;
  const char* gB0 =
      (const char*)(wbase + (size_t)(n0 + rbase) * I_DIM) + segp * 16 + koff;
  const char* gB1 =
      (const char*)(wbase + (size_t)(n0 + rbase + 64) * I_DIM) + segp * 16 + koff;

  f32x4 acc[4][4];
#pragma unroll
  for (int m = 0; m < 4; ++m)
#pragma unroll
    for (int n = 0; n < 4; ++n) acc[m][n] = f32x4{0.f, 0.f, 0.f, 0.f};

  const int wr = w >> 1, wc = w & 1, lrow = l & 15, g = l >> 4;
  const int gs = g ^ ((l >> 1) & 3);
  const int NK = (mode == 2) ? 32 : 64;

  char* dA = LDS + w * 1024;
  char* dB = LDS + 24576 + w * 1024;
  const unsigned ldsb = (unsigned)(uintptr_t)&LDS[0];
  const unsigned aRd = ldsb + (unsigned)((wr * 64 + lrow) * 64 + gs * 16);
  const unsigned bRd = ldsb + 24576u + (unsigned)((wc * 64 + lrow) * 64 + gs * 16);

  asm volatile("s_waitcnt vmcnt(0)" ::: "memory");
  gld16(gA0, dA);        gld16(gA1, dA + 4096);
  gld16(gB0, dB);        gld16(gB1, dB + 4096);
  gld16(gA0 + 64, dA + 8192);  gld16(gA1 + 64, dA + 8192 + 4096);
  gld16(gB0 + 64, dB + 8192);  gld16(gB1 + 64, dB + 8192 + 4096);

  int srd = 0, sst = 2;
  for (int t = 0; t < NK; ++t) {
    if (t + 1 < NK)
      asm volatile("s_waitcnt vmcnt(4)" ::: "memory");
    else
      asm volatile("s_waitcnt vmcnt(0)" ::: "memory");
    asm volatile("s_barrier" ::: "memory");
    const int tau = t + 2;
    if (tau < NK) {
      const size_t kb = (size_t)tau * 64;
      char* da = dA + sst * 8192;
      char* db = dB + sst * 8192;
      gld16(gA0 + kb, da);  gld16(gA1 + kb, da + 4096);
      gld16(gB0 + kb, db);  gld16(gB1 + kb, db + 4096);
    }
    const unsigned so = (unsigned)(srd * 8192);
    const unsigned aS = aRd + so, bS = bRd + so;
    s16x8 av[4], bv[4];
    DSR(bv[0], bS, 0);    DSR(bv[1], bS, 1024);
    DSR(bv[2], bS, 2048); DSR(bv[3], bS, 3072);
    DSR(av[0], aS, 0);    DSR(av[1], aS, 1024);
    DSR(av[2], aS, 2048); DSR(av[3], aS, 3072);
    asm volatile("s_waitcnt lgkmcnt(0)" ::: "memory");
    __builtin_amdgcn_sched_barrier(0);
    __builtin_amdgcn_s_setprio(1);
#pragma unroll
    for (int m = 0; m < 4; ++m)
#pragma unroll
      for (int n = 0; n < 4; ++n) mfma_bf16(av[m], bv[n], acc[m][n]);
    __builtin_amdgcn_s_setprio(0);
    srd = (srd == 2) ? 0 : srd + 1;
    sst = (sst == 2) ? 0 : sst + 1;
  }
  __builtin_amdgcn_sched_barrier(0);

  if (mode >= 1) {
    unsigned short* po = (kh == 0) ? poA : poB;
#pragma unroll
    for (int m = 0; m < 4; ++m) {
      const int rw0 = wr * 64 + m * 16 + g * 4;
#pragma unroll
      for (int n = 0; n < 4; ++n) {
        const int col = n0 + wc * 64 + n * 16 + lrow;
        f32x4 v = acc[m][n];
#pragma unroll
        for (int j = 0; j < 4; ++j)
          po[(size_t)(tsp + rw0 + j) * H_DIM + col] = f2bf(v[j]);
      }
    }
  } else {
    const float* b2e = b2 + (size_t)e * H_DIM;
#pragma unroll
    for (int m = 0; m < 4; ++m) {
      const int rw0 = wr * 64 + m * 16 + g * 4;
#pragma unroll
      for (int j = 0; j < 4; ++j) {
        const int p = tsp + rw0 + j;
        const int tok = pairTok[p];
        if (tok < 0) continue;
        const float pw = pairW[p];
        float* orow = out + (size_t)tok * H_DIM;
#pragma unroll
        for (int n = 0; n < 4; ++n) {
          const int col = n0 + wc * 64 + n * 16 + lrow;
          float val = (acc[m][n][j] + b2e[col]) * pw;
          atomicAdd(orow + col, val);
        }
      }
    }
  }
}

// ---------------- combine: out[t] = sum_k pw_k * (poA[+poB] + b2[e_k]) --------
__global__ __launch_bounds__(256) void combine_kernel(
    const unsigned short* __restrict__ poA, const unsigned short* __restrict__ poB,
    const int* __restrict__ pairPos, const int* __restrict__ topi,
    const float* __restrict__ topw, const float* __restrict__ b2,
    float* __restrict__ out, int nbuf) {
  const int t = blockIdx.x * 2 + (threadIdx.x >> 7);
  const int c0 = (threadIdx.x & 127) * 8;
  float o[8];
#pragma unroll
  for (int j = 0; j < 8; ++j) o[j] = 0.f;
#pragma unroll
  for (int k = 0; k < K_TOP; ++k) {
    const int e = topi[t * K_TOP + k];
    const float pw = topw[t * K_TOP + k];
    const int pos = pairPos[t * K_TOP + k];
    u16x8 va = *(const u16x8*)(poA + (size_t)pos * H_DIM + c0);
    u16x8 vb;
    if (nbuf == 2) vb = *(const u16x8*)(poB + (size_t)pos * H_DIM + c0);
    const float* b2r = b2 + (size_t)e * H_DIM + c0;
#pragma unroll
    for (int j = 0; j < 8; ++j) {
      float hv = __uint_as_float((unsigned)va[j] << 16);
      if (nbuf == 2) hv += __uint_as_float((unsigned)vb[j] << 16);
      o[j] += pw * (hv + b2r[j]);
    }
  }
  float* orow = out + (size_t)t * H_DIM + c0;
  *(f32x4*)orow = f32x4{o[0], o[1], o[2], o[3]};
  *(f32x4*)(orow + 4) = f32x4{o[4], o[5], o[6], o[7]};
}

// ------------------------------------------------------------------------------
extern "C" void kernel_launch(void* const* d_in, const int* in_sizes, int n_in,
                              void* d_out, int out_size, void* d_ws,
                              size_t ws_size, hipStream_t stream) {
  const float* x = (const float*)d_in[0];
  const float* rw = (const float*)d_in[1];
  const float* rb = (const float*)d_in[2];
  const float* w1 = (const float*)d_in[3];
  const float* b1 = (const float*)d_in[4];
  const float* w2 = (const float*)d_in[5];
  const float* b2 = (const float*)d_in[6];
  float* out = (float*)d_out;
  char* ws = (char*)d_ws;

  const size_t xbSz = (size_t)T_TOK * H_DIM * 2;          // 8.39 MB
  const size_t poSz = (size_t)PAD_PAIRS * H_DIM * 2;      // 37.75 MB
  const size_t wtSz = (size_t)E_NUM * H_DIM * I_DIM * 2;  // 67.11 MB
  const size_t hmSz = (size_t)PAD_PAIRS * I_DIM * 2;      // 75.50 MB
  const size_t smallSz = (size_t)T_TOK * K_TOP * 4 * 3
                         + (size_t)PAD_PAIRS * 4 * 2 + 128;
  const size_t needDualSplit = 2 * poSz + 2 * wtSz + hmSz + smallSz;
  const size_t needDual      = poSz + 2 * wtSz + hmSz + smallSz;
  const size_t needSplit     = 2 * poSz + wtSz + hmSz + smallSz;
  const size_t needPo        = poSz + wtSz + hmSz + smallSz;
  const size_t needMin       = xbSz + wtSz + hmSz + smallSz;
  int dual = 0, split = 0, po = 0;
  if (ws_size >= needDualSplit) { dual = 1; split = 1; po = 1; }
  else if (ws_size >= needDual) { dual = 1; po = 1; }
  else if (ws_size >= needSplit) { split = 1; po = 1; }
  else if (ws_size >= needPo) { po = 1; }
  else if (ws_size < needMin) return;  // diagnostic: output stays 0

  size_t off = 0;
  unsigned short* xb = (unsigned short*)(ws + off);
  unsigned short* poA = (unsigned short*)(ws + off);  // xb dead by gemm2
  off += po ? poSz : xbSz;
  unsigned short* poB = (unsigned short*)(ws + off);
  if (split) off += poSz;
  unsigned short* wT1 = (unsigned short*)(ws + off);
  off += wtSz;
  unsigned short* wT2 = wT1;
  if (dual) { wT2 = (unsigned short*)(ws + off); off += wtSz; }
  unsigned short* hmid = (unsigned short*)(ws + off);
  off += hmSz;
  int* topi = (int*)(ws + off);      off += (size_t)T_TOK * K_TOP * 4;
  float* topw = (float*)(ws + off);  off += (size_t)T_TOK * K_TOP * 4;
  int* pairPos = (int*)(ws + off);   off += (size_t)T_TOK * K_TOP * 4;
  int* pairTok = (int*)(ws + off);   off += (size_t)PAD_PAIRS * 4;
  float* pairW = (float*)(ws + off); off += (size_t)PAD_PAIRS * 4;
  int* counts = (int*)(ws + off);    off += 64;
  int* cursor = (int*)(ws + off);    off += 64;

  const int gmode = split ? 2 : (po ? 1 : 0);

  hipMemsetAsync(counts, 0, 128, stream);  // counts + cursor
  if (gmode == 0) hipMemsetAsync(out, 0, (size_t)T_TOK * H_DIM * 4, stream);

  // stage 1: router (blocks [0,256), dispatched first) || transpose(w1) x2
  fused1_kernel<<<256 + 4096, 256, 0, stream>>>(x, rw, rb, topi, topw, counts,
                                                xb, w1, wT1);
  scatter_kernel<<<T_TOK / 256, 256, 0, stream>>>(topi, topw, counts, cursor,
                                                  pairTok, pairW, pairPos);
  // stage 2: gemm1 || transpose(w2) x2 when dual buffers available
  if (dual) {
    fused2_kernel<<<2304 + 4096, 256, 0, stream>>>(xb, wT1, b1, hmid, pairTok,
                                                   counts, w2, wT2);
  } else {
    gemm1_kernel<<<16 * MAX_TILES, 256, 0, stream>>>(xb, wT1, b1, hmid, pairTok,
                                                     counts);
    transpose_kernel<<<dim3(H_DIM / 64, I_DIM / 64, E_NUM), 256, 0, stream>>>(
        w2, wT2, I_DIM, H_DIM);
  }
  gemm2_kernel<<<(gmode == 2 ? 16 : 8) * MAX_TILES, 256, 0, stream>>>(
      hmid, wT2, b2, out, poA, poB, pairTok, pairW, counts, gmode);
  if (gmode >= 1)
    combine_kernel<<<T_TOK / 2, 256, 0, stream>>>(poA, poB, pairPos, topi, topw,
                                                  b2, out, gmode);
}